// Round 1
// baseline (665.051 us; speedup 1.0000x reference)
//
#include <hip/hip_runtime.h>
#include <hip/hip_bf16.h>

typedef __bf16 bf16x8 __attribute__((ext_vector_type(8)));
typedef float f32x4 __attribute__((ext_vector_type(4)));

__device__ __forceinline__ f32x4 mfma16(bf16x8 a, bf16x8 b, f32x4 c) {
  return __builtin_amdgcn_mfma_f32_16x16x32_bf16(a, b, c, 0, 0, 0);
}

__device__ __forceinline__ bf16x8 cvt8(const float* f) {
  bf16x8 r;
#pragma unroll
  for (int i = 0; i < 8; ++i) r[i] = (__bf16)f[i];
  return r;
}

// ---- block reduction helpers (blockDim.x == 256 assumed, 4 waves) ----
__device__ __forceinline__ void blockRed2(float& a, float& b, float* red) {
#pragma unroll
  for (int off = 1; off < 64; off <<= 1) {
    a += __shfl_xor(a, off, 64);
    b += __shfl_xor(b, off, 64);
  }
  const int w = threadIdx.x >> 6;
  if ((threadIdx.x & 63) == 0) { red[w] = a; red[4 + w] = b; }
  __syncthreads();
  a = red[0] + red[1] + red[2] + red[3];
  b = red[4] + red[5] + red[6] + red[7];
  __syncthreads();
}

__device__ __forceinline__ float blockMax(float v, float* red) {
#pragma unroll
  for (int off = 1; off < 64; off <<= 1) v = fmaxf(v, __shfl_xor(v, off, 64));
  const int w = threadIdx.x >> 6;
  if ((threadIdx.x & 63) == 0) red[w] = v;
  __syncthreads();
  v = fmaxf(fmaxf(red[0], red[1]), fmaxf(red[2], red[3]));
  __syncthreads();
  return v;
}

__device__ __forceinline__ float blockSum(float v, float* red) {
#pragma unroll
  for (int off = 1; off < 64; off <<= 1) v += __shfl_xor(v, off, 64);
  const int w = threadIdx.x >> 6;
  if ((threadIdx.x & 63) == 0) red[w] = v;
  __syncthreads();
  v = red[0] + red[1] + red[2] + red[3];
  __syncthreads();
  return v;
}

// =====================================================================
// Stage A: img_feat partials = images_flat(512x37632) @ W_img(37632x512)
// split-K=24, tile 128x128, 4 waves each 64x64, fp32->bf16 staging.
// =====================================================================
#define IMG_K 37632
#define SPLITK 24
#define STEPS_PER 49  // 1176 k-steps of 32 / 24

__global__ __launch_bounds__(256) void img_gemm_kernel(
    const float* __restrict__ A, const float* __restrict__ B,
    float* __restrict__ partials) {
  __shared__ __bf16 As[128 * 40];
  __shared__ __bf16 Bs[128 * 40];
  const int t = threadIdx.x;
  const int lane = t & 63;
  const int w = t >> 6;
  const int wm = (w >> 1) * 64, wn = (w & 1) * 64;
  const int m0 = blockIdx.y * 128, n0 = blockIdx.x * 128;
  const int step0 = blockIdx.z * STEPS_PER;

  f32x4 acc[4][4];
#pragma unroll
  for (int i = 0; i < 4; ++i)
#pragma unroll
    for (int j = 0; j < 4; ++j) acc[i][j] = f32x4{0.f, 0.f, 0.f, 0.f};

  const int ar = t >> 1, ak = (t & 1) * 16;
  const int bn = t & 127, bk = (t >> 7) * 16;
  const int fr = lane & 15, fk = (lane >> 4) * 8;

  for (int s = 0; s < STEPS_PER; ++s) {
    const int k0 = (step0 + s) * 32;
    {  // stage A (row-major, 16 f32/thread)
      const float* src = A + (size_t)(m0 + ar) * IMG_K + k0 + ak;
      float tmp[16];
#pragma unroll
      for (int i = 0; i < 4; ++i) {
        f32x4 v = *reinterpret_cast<const f32x4*>(src + i * 4);
        tmp[i * 4 + 0] = v[0]; tmp[i * 4 + 1] = v[1];
        tmp[i * 4 + 2] = v[2]; tmp[i * 4 + 3] = v[3];
      }
      *reinterpret_cast<bf16x8*>(&As[ar * 40 + ak]) = cvt8(tmp);
      *reinterpret_cast<bf16x8*>(&As[ar * 40 + ak + 8]) = cvt8(tmp + 8);
    }
    {  // stage B transposed: column loads (coalesced across lanes)
      float tmp[16];
#pragma unroll
      for (int j = 0; j < 16; ++j)
        tmp[j] = B[(size_t)(k0 + bk + j) * 512 + n0 + bn];
      *reinterpret_cast<bf16x8*>(&Bs[bn * 40 + bk]) = cvt8(tmp);
      *reinterpret_cast<bf16x8*>(&Bs[bn * 40 + bk + 8]) = cvt8(tmp + 8);
    }
    __syncthreads();
    bf16x8 af[4], bfr[4];
#pragma unroll
    for (int i = 0; i < 4; ++i) {
      af[i] = *reinterpret_cast<const bf16x8*>(&As[(wm + i * 16 + fr) * 40 + fk]);
      bfr[i] = *reinterpret_cast<const bf16x8*>(&Bs[(wn + i * 16 + fr) * 40 + fk]);
    }
#pragma unroll
    for (int i = 0; i < 4; ++i)
#pragma unroll
      for (int j = 0; j < 4; ++j) acc[i][j] = mfma16(af[i], bfr[j], acc[i][j]);
    __syncthreads();
  }

  float* P = partials + (size_t)blockIdx.z * (512 * 512);
  const int rq = (lane >> 4) * 4;
#pragma unroll
  for (int i = 0; i < 4; ++i)
#pragma unroll
    for (int j = 0; j < 4; ++j)
#pragma unroll
      for (int r = 0; r < 4; ++r)
        P[(size_t)(m0 + wm + i * 16 + rq + r) * 512 + (n0 + wn + j * 16 + fr)] =
            acc[i][j][r];
}

// low[idx] = kp_feat(already there) + b_img + sum_z partials[z][idx]
__global__ __launch_bounds__(256) void reduce_add_kernel(
    const float* __restrict__ partials, const float* __restrict__ b_img,
    float* __restrict__ low) {
  const int idx = blockIdx.x * 256 + threadIdx.x;
  float acc = low[idx] + b_img[idx & 511];
#pragma unroll
  for (int z = 0; z < SPLITK; ++z) acc += partials[(size_t)z * 262144 + idx];
  low[idx] = acc;
}

// =====================================================================
// kp_feat = LN(relu(keypoints @ W_kp + b_kp)); one block per row (512)
// writes into `low` (img_feat added later by reduce_add_kernel)
// =====================================================================
__global__ __launch_bounds__(256) void kp_kernel(
    const float* __restrict__ kp, const float* __restrict__ W,
    const float* __restrict__ bias, const float* __restrict__ g,
    const float* __restrict__ bt, float* __restrict__ low) {
  __shared__ float rowv[242];
  __shared__ float red[8];
  const int t = threadIdx.x;
  const size_t roff = (size_t)blockIdx.x * 242;
  if (t < 242) rowv[t] = kp[roff + t];
  __syncthreads();
  const int d0 = t, d1 = t + 256;
  float p0 = bias[d0], p1 = bias[d1];
  for (int kk = 0; kk < 242; ++kk) {
    const float x = rowv[kk];
    p0 = fmaf(x, W[kk * 512 + d0], p0);
    p1 = fmaf(x, W[kk * 512 + d1], p1);
  }
  p0 = fmaxf(p0, 0.f);
  p1 = fmaxf(p1, 0.f);
  float s = p0 + p1, sq = p0 * p0 + p1 * p1;
  blockRed2(s, sq, red);
  const float m = s * (1.f / 512.f);
  const float var = sq * (1.f / 512.f) - m * m;
  const float rs = rsqrtf(var + 1e-5f);
  const size_t off = (size_t)blockIdx.x * 512;
  low[off + d0] = (p0 - m) * rs * g[d0] + bt[d0];
  low[off + d1] = (p1 - m) * rs * g[d1] + bt[d1];
}

// =====================================================================
// pooled = pool_mean(LN(qgrids @ W_qp + b_qp)); 2 pooled rows / block.
// Templated on stride S so accumulators stay in registers (rule #20).
// =====================================================================
template <int S>
__device__ __forceinline__ void pool_core(
    const float* __restrict__ qg_b, const float* __restrict__ W,
    const float* __restrict__ bias, const float* __restrict__ g,
    const float* __restrict__ bt, float* __restrict__ pooled_b, int L,
    int new_len, int j0, float (*rows)[242], float* red) {
  constexpr int NR = 2 * S;
  const int t = threadIdx.x;
  const int base = j0 * S;
  for (int rr = 0; rr < NR; ++rr) {
    const int row = base + rr;
    if (t < 242) rows[rr][t] = (row < L) ? qg_b[(size_t)row * 242 + t] : 0.f;
  }
  __syncthreads();
  const int d0 = t, d1 = t + 256;
  float p0[NR], p1[NR];
  const float b0 = bias[d0], b1 = bias[d1];
#pragma unroll
  for (int rr = 0; rr < NR; ++rr) { p0[rr] = b0; p1[rr] = b1; }
  for (int kk = 0; kk < 242; ++kk) {
    const float w0 = W[kk * 512 + d0], w1 = W[kk * 512 + d1];
#pragma unroll
    for (int rr = 0; rr < NR; ++rr) {
      const float x = rows[rr][kk];
      p0[rr] = fmaf(x, w0, p0[rr]);
      p1[rr] = fmaf(x, w1, p1[rr]);
    }
  }
  const float g0 = g[d0], g1 = g[d1], t0 = bt[d0], t1 = bt[d1];
  float acc0[2] = {0.f, 0.f}, acc1[2] = {0.f, 0.f};
#pragma unroll
  for (int rr = 0; rr < NR; ++rr) {
    float s = p0[rr] + p1[rr], sq = p0[rr] * p0[rr] + p1[rr] * p1[rr];
    blockRed2(s, sq, red);
    const float m = s * (1.f / 512.f);
    const float var = sq * (1.f / 512.f) - m * m;
    const float rs = rsqrtf(var + 1e-5f);
    if (base + rr < L) {  // rows past L contribute zero (still divided by S)
      acc0[rr / S] += (p0[rr] - m) * rs * g0 + t0;
      acc1[rr / S] += (p1[rr] - m) * rs * g1 + t1;
    }
  }
  const float inv = 1.f / (float)S;
#pragma unroll
  for (int g2 = 0; g2 < 2; ++g2) {
    const int j = j0 + g2;
    const bool ok = j < new_len;
    pooled_b[(size_t)j * 512 + d0] = ok ? acc0[g2] * inv : 0.f;
    pooled_b[(size_t)j * 512 + d1] = ok ? acc1[g2] * inv : 0.f;
  }
}

__global__ __launch_bounds__(256) void pool_kernel(
    const float* __restrict__ qgrids, const int* __restrict__ lens,
    const float* __restrict__ W, const float* __restrict__ bias,
    const float* __restrict__ g, const float* __restrict__ bt,
    float* __restrict__ pooled) {
  __shared__ float rows[16][242];
  __shared__ float red[8];
  const int b = blockIdx.x >> 8;
  const int j0 = (blockIdx.x & 255) * 2;
  const int L = lens[b];
  int s = (L + 511) >> 9;
  if (s < 1) s = 1;
  const int new_len = (L + s - 1) / s;
  const float* qg_b = qgrids + (size_t)b * 4096 * 242;
  float* pooled_b = pooled + (size_t)b * 512 * 512;
  switch (s) {
    case 1: pool_core<1>(qg_b, W, bias, g, bt, pooled_b, L, new_len, j0, rows, red); break;
    case 2: pool_core<2>(qg_b, W, bias, g, bt, pooled_b, L, new_len, j0, rows, red); break;
    case 3: pool_core<3>(qg_b, W, bias, g, bt, pooled_b, L, new_len, j0, rows, red); break;
    case 4: pool_core<4>(qg_b, W, bias, g, bt, pooled_b, L, new_len, j0, rows, red); break;
    case 5: pool_core<5>(qg_b, W, bias, g, bt, pooled_b, L, new_len, j0, rows, red); break;
    case 6: pool_core<6>(qg_b, W, bias, g, bt, pooled_b, L, new_len, j0, rows, red); break;
    case 7: pool_core<7>(qg_b, W, bias, g, bt, pooled_b, L, new_len, j0, rows, red); break;
    default: pool_core<8>(qg_b, W, bias, g, bt, pooled_b, L, new_len, j0, rows, red); break;
  }
}

// =====================================================================
// Generic bf16-MFMA GEMM: C[M,N] = A[M,K]@B[K,N] (+bias if flags&1,
// += existing C if flags&2). M%64==0, K%32==0; N arbitrary (guarded).
// =====================================================================
__global__ __launch_bounds__(256) void gemm_kernel(
    const float* __restrict__ A, const float* __restrict__ B,
    const float* __restrict__ bias, float* __restrict__ C, int M, int N,
    int K, int flags) {
  __shared__ __bf16 As[64 * 40];
  __shared__ __bf16 Bs[64 * 40];
  const int t = threadIdx.x, lane = t & 63, w = t >> 6;
  const int m0 = blockIdx.y * 64, n0 = blockIdx.x * 64;
  f32x4 acc[4];
#pragma unroll
  for (int j = 0; j < 4; ++j) acc[j] = f32x4{0.f, 0.f, 0.f, 0.f};
  const int ar = t >> 2, ak = (t & 3) * 8;
  const int bn = t & 63, bk = (t >> 6) * 8;
  const int fr = lane & 15, fk = (lane >> 4) * 8;
  const int col = n0 + bn;
  const bool colok = col < N;
  const int nst = K >> 5;
  for (int s = 0; s < nst; ++s) {
    const int k0 = s * 32;
    {
      const float* src = A + (size_t)(m0 + ar) * K + k0 + ak;
      f32x4 v0 = *reinterpret_cast<const f32x4*>(src);
      f32x4 v1 = *reinterpret_cast<const f32x4*>(src + 4);
      float tmp[8] = {v0[0], v0[1], v0[2], v0[3], v1[0], v1[1], v1[2], v1[3]};
      *reinterpret_cast<bf16x8*>(&As[ar * 40 + ak]) = cvt8(tmp);
    }
    {
      float tmp[8];
#pragma unroll
      for (int j = 0; j < 8; ++j)
        tmp[j] = colok ? B[(size_t)(k0 + bk + j) * N + col] : 0.f;
      *reinterpret_cast<bf16x8*>(&Bs[bn * 40 + bk]) = cvt8(tmp);
    }
    __syncthreads();
    bf16x8 a = *reinterpret_cast<const bf16x8*>(&As[(w * 16 + fr) * 40 + fk]);
#pragma unroll
    for (int j = 0; j < 4; ++j) {
      bf16x8 b = *reinterpret_cast<const bf16x8*>(&Bs[(j * 16 + fr) * 40 + fk]);
      acc[j] = mfma16(a, b, acc[j]);
    }
    __syncthreads();
  }
  const int rq = (lane >> 4) * 4;
#pragma unroll
  for (int j = 0; j < 4; ++j) {
    const int c = n0 + j * 16 + fr;
    if (c < N) {
#pragma unroll
      for (int r = 0; r < 4; ++r) {
        const size_t idx = (size_t)(m0 + w * 16 + rq + r) * N + c;
        float v = acc[j][r];
        if (flags & 1) v += bias[c];
        if (flags & 2) v += C[idx];
        C[idx] = v;
      }
    }
  }
}

// =====================================================================
// Fused attention: one block per (b, q-row). scores+mask+softmax+PV.
// =====================================================================
__global__ __launch_bounds__(256) void attn_kernel(
    const float* __restrict__ q, const float* __restrict__ k,
    const float* __restrict__ v, const int* __restrict__ lens,
    float* __restrict__ ctx) {
  __shared__ float qrow[512];
  __shared__ float p[512];
  __shared__ float pv[256];
  __shared__ float red[8];
  const int t = threadIdx.x;
  const int b = blockIdx.x >> 6, qt = blockIdx.x & 63;
  const int L = lens[b];
  int sdiv = (L + 511) >> 9;
  if (sdiv < 1) sdiv = 1;
  const int new_len = (L + sdiv - 1) / sdiv;
  const size_t qoff = ((size_t)b * 64 + qt) * 512;
  qrow[t] = q[qoff + t];
  qrow[t + 256] = q[qoff + t + 256];
  __syncthreads();
  const float* kb_base = k + (size_t)b * 512 * 512;
  const float* vb_base = v + (size_t)b * 512 * 512;
  for (int h = 0; h < 8; ++h) {
    const float* qh = qrow + h * 64;
    const float* kb = kb_base + h * 64;
    float a0 = 0.f, a1 = 0.f;
#pragma unroll
    for (int d = 0; d < 64; d += 4) {
      f32x4 qv = *reinterpret_cast<const f32x4*>(&qh[d]);
      f32x4 k0 = *reinterpret_cast<const f32x4*>(&kb[(size_t)t * 512 + d]);
      f32x4 k1 = *reinterpret_cast<const f32x4*>(&kb[(size_t)(t + 256) * 512 + d]);
      a0 = fmaf(qv[0], k0[0], fmaf(qv[1], k0[1], fmaf(qv[2], k0[2], fmaf(qv[3], k0[3], a0))));
      a1 = fmaf(qv[0], k1[0], fmaf(qv[1], k1[1], fmaf(qv[2], k1[2], fmaf(qv[3], k1[3], a1))));
    }
    a0 *= 0.125f;
    a1 *= 0.125f;
    const bool ok0 = t < new_len, ok1 = (t + 256) < new_len;
    const float mx = blockMax(fmaxf(ok0 ? a0 : -3.0e38f, ok1 ? a1 : -3.0e38f), red);
    const float e0 = ok0 ? expf(a0 - mx) : 0.f;
    const float e1 = ok1 ? expf(a1 - mx) : 0.f;
    const float sum = blockSum(e0 + e1, red);
    const float inv = 1.f / sum;
    p[t] = e0 * inv;
    p[t + 256] = e1 * inv;
    __syncthreads();
    const int d = t & 63, c = t >> 6;
    const float* vb = vb_base + h * 64 + d;
    float a = 0.f;
    const int kv0 = c * 128;
#pragma unroll 4
    for (int kv = kv0; kv < kv0 + 128; ++kv) a = fmaf(p[kv], vb[(size_t)kv * 512], a);
    pv[t] = a;
    __syncthreads();
    if (t < 64) {
      const float r2 = pv[t] + pv[64 + t] + pv[128 + t] + pv[192 + t];
      ctx[qoff + h * 64 + t] = r2;
    }
    __syncthreads();
  }
}

// LayerNorm over rows of 512 (for ctx @ Wo + bo)
__global__ __launch_bounds__(256) void ln_kernel(const float* __restrict__ x,
                                                 const float* __restrict__ g,
                                                 const float* __restrict__ bt,
                                                 float* __restrict__ y) {
  __shared__ float red[8];
  const int t = threadIdx.x;
  const size_t off = (size_t)blockIdx.x * 512;
  const float a = x[off + t], b2 = x[off + t + 256];
  float s = a + b2, sq = a * a + b2 * b2;
  blockRed2(s, sq, red);
  const float m = s * (1.f / 512.f);
  const float var = sq * (1.f / 512.f) - m * m;
  const float rs = rsqrtf(var + 1e-5f);
  y[off + t] = (a - m) * rs * g[t] + bt[t];
  y[off + t + 256] = (b2 - m) * rs * g[t + 256] + bt[t + 256];
}

// =====================================================================
extern "C" void kernel_launch(void* const* d_in, const int* in_sizes, int n_in,
                              void* d_out, int out_size, void* d_ws,
                              size_t ws_size, hipStream_t stream) {
  const float* images = (const float*)d_in[0];
  const float* qgrids = (const float*)d_in[1];
  const float* keypoints = (const float*)d_in[2];
  const int* qlens = (const int*)d_in[3];
  const float* W_img = (const float*)d_in[4];
  const float* b_img = (const float*)d_in[5];
  const float* W_kp = (const float*)d_in[6];
  const float* b_kp = (const float*)d_in[7];
  const float* g_kp = (const float*)d_in[8];
  const float* bt_kp = (const float*)d_in[9];
  const float* W_qp = (const float*)d_in[10];
  const float* b_qp = (const float*)d_in[11];
  const float* g_qln = (const float*)d_in[12];
  const float* bt_qln = (const float*)d_in[13];
  const float* Wq = (const float*)d_in[14];
  const float* bq = (const float*)d_in[15];
  const float* Wk = (const float*)d_in[16];
  const float* bk = (const float*)d_in[17];
  const float* Wv = (const float*)d_in[18];
  const float* bv = (const float*)d_in[19];
  const float* Wo = (const float*)d_in[20];
  const float* bo = (const float*)d_in[21];
  const float* g_attn = (const float*)d_in[22];
  const float* bt_attn = (const float*)d_in[23];
  const float* W_ctc = (const float*)d_in[24];
  const float* b_ctc = (const float*)d_in[25];
  float* out = (float*)d_out;

  const size_t MB = 1u << 20;
  if (ws_size < 29 * MB) return;  // need 29 MB of scratch
  char* ws = (char*)d_ws;
  float* low = (float*)(ws);            // 1 MB  (512x512)
  float* qbuf = (float*)(ws + 1 * MB);  // 1 MB
  float* ctxo = (float*)(ws + 2 * MB);  // 1 MB
  float* ctxln = (float*)(ws + 3 * MB); // 1 MB
  float* pooled = (float*)(ws + 4 * MB);    // 8 MB (8x512x512)
  float* partials = (float*)(ws + 12 * MB); // 24 MB (24x512x512)
  float* kbuf = partials;                   // reuse after reduce (8 MB)
  float* vbuf = (float*)(ws + 20 * MB);     // 8 MB
  float* ctx = (float*)(ws + 28 * MB);      // 1 MB

  // 1) img GEMM partials (split-K=24)
  img_gemm_kernel<<<dim3(4, 4, SPLITK), 256, 0, stream>>>(images, W_img, partials);
  // 2) kp_feat -> low
  kp_kernel<<<512, 256, 0, stream>>>(keypoints, W_kp, b_kp, g_kp, bt_kp, low);
  // 3) low += b_img + sum(partials)
  reduce_add_kernel<<<1024, 256, 0, stream>>>(partials, b_img, low);
  // 4) pooled qgrid tokens (proj + LN + ragged mean-pool)
  pool_kernel<<<2048, 256, 0, stream>>>(qgrids, qlens, W_qp, b_qp, g_qln, bt_qln, pooled);
  // 5) k, v from pooled (partials region is dead now)
  gemm_kernel<<<dim3(8, 64), 256, 0, stream>>>(pooled, Wk, bk, kbuf, 4096, 512, 512, 1);
  gemm_kernel<<<dim3(8, 64), 256, 0, stream>>>(pooled, Wv, bv, vbuf, 4096, 512, 512, 1);
  // 6) q from low
  gemm_kernel<<<dim3(8, 8), 256, 0, stream>>>(low, Wq, bq, qbuf, 512, 512, 512, 1);
  // 7) fused attention
  attn_kernel<<<512, 256, 0, stream>>>(qbuf, kbuf, vbuf, qlens, ctx);
  // 8) ctx @ Wo + bo, then LN
  gemm_kernel<<<dim3(8, 8), 256, 0, stream>>>(ctx, Wo, bo, ctxo, 512, 512, 512, 1);
  ln_kernel<<<512, 256, 0, stream>>>(ctxo, g_attn, bt_attn, ctxln);
  // 9) out = low @ W_ctc[:512] + b_ctc ; out += ctxln @ W_ctc[512:]
  gemm_kernel<<<dim3(21, 8), 256, 0, stream>>>(low, W_ctc, b_ctc, out, 512, 1296, 512, 1);
  gemm_kernel<<<dim3(21, 8), 256, 0, stream>>>(ctxln, W_ctc + (size_t)512 * 1296, nullptr, out, 512, 1296, 512, 2);
}

// Round 2
// 526.284 us; speedup vs baseline: 1.2637x; 1.2637x over previous
//
#include <hip/hip_runtime.h>
#include <hip/hip_bf16.h>

typedef __bf16 bf16x8 __attribute__((ext_vector_type(8)));
typedef __bf16 bf16x4 __attribute__((ext_vector_type(4)));
typedef float f32x4 __attribute__((ext_vector_type(4)));

__device__ __forceinline__ f32x4 mfma16(bf16x8 a, bf16x8 b, f32x4 c) {
  return __builtin_amdgcn_mfma_f32_16x16x32_bf16(a, b, c, 0, 0, 0);
}

__device__ __forceinline__ bf16x8 cvt8(const float* f) {
  bf16x8 r;
#pragma unroll
  for (int i = 0; i < 8; ++i) r[i] = (__bf16)f[i];
  return r;
}

__device__ __forceinline__ bf16x4 cvt4(f32x4 v) {
  bf16x4 r;
#pragma unroll
  for (int i = 0; i < 4; ++i) r[i] = (__bf16)v[i];
  return r;
}

// ---- block reduction helpers (blockDim.x == 256 assumed, 4 waves) ----
__device__ __forceinline__ void blockRed2(float& a, float& b, float* red) {
#pragma unroll
  for (int off = 1; off < 64; off <<= 1) {
    a += __shfl_xor(a, off, 64);
    b += __shfl_xor(b, off, 64);
  }
  const int w = threadIdx.x >> 6;
  if ((threadIdx.x & 63) == 0) { red[w] = a; red[4 + w] = b; }
  __syncthreads();
  a = red[0] + red[1] + red[2] + red[3];
  b = red[4] + red[5] + red[6] + red[7];
  __syncthreads();
}

// =====================================================================
// Stage A: img_feat partials = images_flat(512x37632) @ W_img(37632x512)
// split-K=24, tile 128x128, 4 waves each 64x64, fp32->bf16 staging.
// =====================================================================
#define IMG_K 37632
#define SPLITK 24
#define STEPS_PER 49  // 1176 k-steps of 32 / 24

__global__ __launch_bounds__(256) void img_gemm_kernel(
    const float* __restrict__ A, const float* __restrict__ B,
    float* __restrict__ partials) {
  __shared__ __bf16 As[128 * 40];
  __shared__ __bf16 Bs[128 * 40];
  const int t = threadIdx.x;
  const int lane = t & 63;
  const int w = t >> 6;
  const int wm = (w >> 1) * 64, wn = (w & 1) * 64;
  const int m0 = blockIdx.y * 128, n0 = blockIdx.x * 128;
  const int step0 = blockIdx.z * STEPS_PER;

  f32x4 acc[4][4];
#pragma unroll
  for (int i = 0; i < 4; ++i)
#pragma unroll
    for (int j = 0; j < 4; ++j) acc[i][j] = f32x4{0.f, 0.f, 0.f, 0.f};

  const int ar = t >> 1, ak = (t & 1) * 16;
  const int bn = t & 127, bk = (t >> 7) * 16;
  const int fr = lane & 15, fk = (lane >> 4) * 8;

  for (int s = 0; s < STEPS_PER; ++s) {
    const int k0 = (step0 + s) * 32;
    {  // stage A (row-major, 16 f32/thread)
      const float* src = A + (size_t)(m0 + ar) * IMG_K + k0 + ak;
      float tmp[16];
#pragma unroll
      for (int i = 0; i < 4; ++i) {
        f32x4 v = *reinterpret_cast<const f32x4*>(src + i * 4);
        tmp[i * 4 + 0] = v[0]; tmp[i * 4 + 1] = v[1];
        tmp[i * 4 + 2] = v[2]; tmp[i * 4 + 3] = v[3];
      }
      *reinterpret_cast<bf16x8*>(&As[ar * 40 + ak]) = cvt8(tmp);
      *reinterpret_cast<bf16x8*>(&As[ar * 40 + ak + 8]) = cvt8(tmp + 8);
    }
    {  // stage B transposed: column loads (coalesced across lanes)
      float tmp[16];
#pragma unroll
      for (int j = 0; j < 16; ++j)
        tmp[j] = B[(size_t)(k0 + bk + j) * 512 + n0 + bn];
      *reinterpret_cast<bf16x8*>(&Bs[bn * 40 + bk]) = cvt8(tmp);
      *reinterpret_cast<bf16x8*>(&Bs[bn * 40 + bk + 8]) = cvt8(tmp + 8);
    }
    __syncthreads();
    bf16x8 af[4], bfr[4];
#pragma unroll
    for (int i = 0; i < 4; ++i) {
      af[i] = *reinterpret_cast<const bf16x8*>(&As[(wm + i * 16 + fr) * 40 + fk]);
      bfr[i] = *reinterpret_cast<const bf16x8*>(&Bs[(wn + i * 16 + fr) * 40 + fk]);
    }
#pragma unroll
    for (int i = 0; i < 4; ++i)
#pragma unroll
      for (int j = 0; j < 4; ++j) acc[i][j] = mfma16(af[i], bfr[j], acc[i][j]);
    __syncthreads();
  }

  float* P = partials + (size_t)blockIdx.z * (512 * 512);
  const int rq = (lane >> 4) * 4;
#pragma unroll
  for (int i = 0; i < 4; ++i)
#pragma unroll
    for (int j = 0; j < 4; ++j)
#pragma unroll
      for (int r = 0; r < 4; ++r)
        P[(size_t)(m0 + wm + i * 16 + rq + r) * 512 + (n0 + wn + j * 16 + fr)] =
            acc[i][j][r];
}

// low[idx] = kp_feat(already there) + b_img + sum_z partials[z][idx]
__global__ __launch_bounds__(256) void reduce_add_kernel(
    const float* __restrict__ partials, const float* __restrict__ b_img,
    float* __restrict__ low) {
  const int idx = blockIdx.x * 256 + threadIdx.x;
  float acc = low[idx] + b_img[idx & 511];
#pragma unroll
  for (int z = 0; z < SPLITK; ++z) acc += partials[(size_t)z * 262144 + idx];
  low[idx] = acc;
}

// =====================================================================
// kp_feat = LN(relu(keypoints @ W_kp + b_kp)); one block per row (512)
// =====================================================================
__global__ __launch_bounds__(256) void kp_kernel(
    const float* __restrict__ kp, const float* __restrict__ W,
    const float* __restrict__ bias, const float* __restrict__ g,
    const float* __restrict__ bt, float* __restrict__ low) {
  __shared__ float rowv[242];
  __shared__ float red[8];
  const int t = threadIdx.x;
  const size_t roff = (size_t)blockIdx.x * 242;
  if (t < 242) rowv[t] = kp[roff + t];
  __syncthreads();
  const int d0 = t, d1 = t + 256;
  float p0 = bias[d0], p1 = bias[d1];
  for (int kk = 0; kk < 242; ++kk) {
    const float x = rowv[kk];
    p0 = fmaf(x, W[kk * 512 + d0], p0);
    p1 = fmaf(x, W[kk * 512 + d1], p1);
  }
  p0 = fmaxf(p0, 0.f);
  p1 = fmaxf(p1, 0.f);
  float s = p0 + p1, sq = p0 * p0 + p1 * p1;
  blockRed2(s, sq, red);
  const float m = s * (1.f / 512.f);
  const float var = sq * (1.f / 512.f) - m * m;
  const float rs = rsqrtf(var + 1e-5f);
  const size_t off = (size_t)blockIdx.x * 512;
  low[off + d0] = (p0 - m) * rs * g[d0] + bt[d0];
  low[off + d1] = (p1 - m) * rs * g[d1] + bt[d1];
}

// =====================================================================
// pooled = pool_mean(LN(qgrids @ W_qp + b_qp)); 2 pooled rows / block.
// =====================================================================
template <int S>
__device__ __forceinline__ void pool_core(
    const float* __restrict__ qg_b, const float* __restrict__ W,
    const float* __restrict__ bias, const float* __restrict__ g,
    const float* __restrict__ bt, float* __restrict__ pooled_b, int L,
    int new_len, int j0, float (*rows)[242], float* red) {
  constexpr int NR = 2 * S;
  const int t = threadIdx.x;
  const int base = j0 * S;
  for (int rr = 0; rr < NR; ++rr) {
    const int row = base + rr;
    if (t < 242) rows[rr][t] = (row < L) ? qg_b[(size_t)row * 242 + t] : 0.f;
  }
  __syncthreads();
  const int d0 = t, d1 = t + 256;
  float p0[NR], p1[NR];
  const float b0 = bias[d0], b1 = bias[d1];
#pragma unroll
  for (int rr = 0; rr < NR; ++rr) { p0[rr] = b0; p1[rr] = b1; }
  for (int kk = 0; kk < 242; ++kk) {
    const float w0 = W[kk * 512 + d0], w1 = W[kk * 512 + d1];
#pragma unroll
    for (int rr = 0; rr < NR; ++rr) {
      const float x = rows[rr][kk];
      p0[rr] = fmaf(x, w0, p0[rr]);
      p1[rr] = fmaf(x, w1, p1[rr]);
    }
  }
  const float g0 = g[d0], g1 = g[d1], t0 = bt[d0], t1 = bt[d1];
  float acc0[2] = {0.f, 0.f}, acc1[2] = {0.f, 0.f};
#pragma unroll
  for (int rr = 0; rr < NR; ++rr) {
    float s = p0[rr] + p1[rr], sq = p0[rr] * p0[rr] + p1[rr] * p1[rr];
    blockRed2(s, sq, red);
    const float m = s * (1.f / 512.f);
    const float var = sq * (1.f / 512.f) - m * m;
    const float rs = rsqrtf(var + 1e-5f);
    if (base + rr < L) {
      acc0[rr / S] += (p0[rr] - m) * rs * g0 + t0;
      acc1[rr / S] += (p1[rr] - m) * rs * g1 + t1;
    }
  }
  const float inv = 1.f / (float)S;
#pragma unroll
  for (int g2 = 0; g2 < 2; ++g2) {
    const int j = j0 + g2;
    const bool ok = j < new_len;
    pooled_b[(size_t)j * 512 + d0] = ok ? acc0[g2] * inv : 0.f;
    pooled_b[(size_t)j * 512 + d1] = ok ? acc1[g2] * inv : 0.f;
  }
}

__global__ __launch_bounds__(256) void pool_kernel(
    const float* __restrict__ qgrids, const int* __restrict__ lens,
    const float* __restrict__ W, const float* __restrict__ bias,
    const float* __restrict__ g, const float* __restrict__ bt,
    float* __restrict__ pooled) {
  __shared__ float rows[16][242];
  __shared__ float red[8];
  const int b = blockIdx.x >> 8;
  const int j0 = (blockIdx.x & 255) * 2;
  const int L = lens[b];
  int s = (L + 511) >> 9;
  if (s < 1) s = 1;
  const int new_len = (L + s - 1) / s;
  const float* qg_b = qgrids + (size_t)b * 4096 * 242;
  float* pooled_b = pooled + (size_t)b * 512 * 512;
  switch (s) {
    case 1: pool_core<1>(qg_b, W, bias, g, bt, pooled_b, L, new_len, j0, rows, red); break;
    case 2: pool_core<2>(qg_b, W, bias, g, bt, pooled_b, L, new_len, j0, rows, red); break;
    case 3: pool_core<3>(qg_b, W, bias, g, bt, pooled_b, L, new_len, j0, rows, red); break;
    case 4: pool_core<4>(qg_b, W, bias, g, bt, pooled_b, L, new_len, j0, rows, red); break;
    case 5: pool_core<5>(qg_b, W, bias, g, bt, pooled_b, L, new_len, j0, rows, red); break;
    case 6: pool_core<6>(qg_b, W, bias, g, bt, pooled_b, L, new_len, j0, rows, red); break;
    case 7: pool_core<7>(qg_b, W, bias, g, bt, pooled_b, L, new_len, j0, rows, red); break;
    default: pool_core<8>(qg_b, W, bias, g, bt, pooled_b, L, new_len, j0, rows, red); break;
  }
}

// =====================================================================
// Generic bf16-MFMA GEMM: C[M,N] = A[M,K]@B[K,N] (+bias if flags&1,
// += existing C if flags&2). M%64==0, K%32==0; N arbitrary (guarded).
// =====================================================================
__global__ __launch_bounds__(256) void gemm_kernel(
    const float* __restrict__ A, const float* __restrict__ B,
    const float* __restrict__ bias, float* __restrict__ C, int M, int N,
    int K, int flags) {
  __shared__ __bf16 As[64 * 40];
  __shared__ __bf16 Bs[64 * 40];
  const int t = threadIdx.x, lane = t & 63, w = t >> 6;
  const int m0 = blockIdx.y * 64, n0 = blockIdx.x * 64;
  f32x4 acc[4];
#pragma unroll
  for (int j = 0; j < 4; ++j) acc[j] = f32x4{0.f, 0.f, 0.f, 0.f};
  const int ar = t >> 2, ak = (t & 3) * 8;
  const int bn = t & 63, bk = (t >> 6) * 8;
  const int fr = lane & 15, fk = (lane >> 4) * 8;
  const int col = n0 + bn;
  const bool colok = col < N;
  const int nst = K >> 5;
  for (int s = 0; s < nst; ++s) {
    const int k0 = s * 32;
    {
      const float* src = A + (size_t)(m0 + ar) * K + k0 + ak;
      f32x4 v0 = *reinterpret_cast<const f32x4*>(src);
      f32x4 v1 = *reinterpret_cast<const f32x4*>(src + 4);
      float tmp[8] = {v0[0], v0[1], v0[2], v0[3], v1[0], v1[1], v1[2], v1[3]};
      *reinterpret_cast<bf16x8*>(&As[ar * 40 + ak]) = cvt8(tmp);
    }
    {
      float tmp[8];
#pragma unroll
      for (int j = 0; j < 8; ++j)
        tmp[j] = colok ? B[(size_t)(k0 + bk + j) * N + col] : 0.f;
      *reinterpret_cast<bf16x8*>(&Bs[bn * 40 + bk]) = cvt8(tmp);
    }
    __syncthreads();
    bf16x8 a = *reinterpret_cast<const bf16x8*>(&As[(w * 16 + fr) * 40 + fk]);
#pragma unroll
    for (int j = 0; j < 4; ++j) {
      bf16x8 b = *reinterpret_cast<const bf16x8*>(&Bs[(j * 16 + fr) * 40 + fk]);
      acc[j] = mfma16(a, b, acc[j]);
    }
    __syncthreads();
  }
  const int rq = (lane >> 4) * 4;
#pragma unroll
  for (int j = 0; j < 4; ++j) {
    const int c = n0 + j * 16 + fr;
    if (c < N) {
#pragma unroll
      for (int r = 0; r < 4; ++r) {
        const size_t idx = (size_t)(m0 + w * 16 + rq + r) * N + c;
        float v = acc[j][r];
        if (flags & 1) v += bias[c];
        if (flags & 2) v += C[idx];
        C[idx] = v;
      }
    }
  }
}

// =====================================================================
// Attention stage 1: P = softmax(mask(Q_h @ K_h^T / 8)) as bf16.
// One block per (b,h). M=64 q rows (wave w owns rows w*16..w*16+15),
// N=512 kv, K=64 d (2 MFMA k-steps). K_h is (kv,d) row-major = exactly
// the (N,K) k-inner layout the B-fragment wants -> coalesced row copies.
// =====================================================================
__global__ __launch_bounds__(256) void attn_scores_kernel(
    const float* __restrict__ q, const float* __restrict__ k,
    const int* __restrict__ lens, __bf16* __restrict__ P) {
  __shared__ __bf16 Qs[64 * 72];
  __shared__ __bf16 Bs[512 * 40];
  const int t = threadIdx.x, lane = t & 63, w = t >> 6;
  const int bh = blockIdx.x, b = bh >> 3, h = bh & 7;
  const int L = lens[b];
  const int sdiv = (L + 511) >> 9;  // L >= 512 so sdiv >= 1
  const int new_len = (L + sdiv - 1) / sdiv;
  const size_t qbase = (size_t)b * 64 * 512 + h * 64;
  const size_t kbase = (size_t)b * 512 * 512 + h * 64;
  // stage Q (64x64) once, bf16, row stride 72
#pragma unroll
  for (int rep = 0; rep < 4; ++rep) {
    const int gidx = rep * 256 + t;
    const int row = gidx >> 4, c = (gidx & 15) * 4;
    f32x4 v = *reinterpret_cast<const f32x4*>(&q[qbase + (size_t)row * 512 + c]);
    *reinterpret_cast<bf16x4*>(&Qs[row * 72 + c]) = cvt4(v);
  }
  f32x4 acc[32];
#pragma unroll
  for (int nt = 0; nt < 32; ++nt) acc[nt] = f32x4{0.f, 0.f, 0.f, 0.f};
  const int fr = lane & 15, fkq = (lane >> 4) * 8;
  for (int ks = 0; ks < 2; ++ks) {
    const int k0 = ks * 32;
    // stage K rows: 512 x 32 f32 -> bf16, coalesced 128B row segments
#pragma unroll
    for (int rep = 0; rep < 16; ++rep) {
      const int gidx = rep * 256 + t;
      const int row = gidx >> 3, c = (gidx & 7) * 4;
      f32x4 v =
          *reinterpret_cast<const f32x4*>(&k[kbase + (size_t)row * 512 + k0 + c]);
      *reinterpret_cast<bf16x4*>(&Bs[row * 40 + c]) = cvt4(v);
    }
    __syncthreads();
    const bf16x8 af =
        *reinterpret_cast<const bf16x8*>(&Qs[(w * 16 + fr) * 72 + k0 + fkq]);
#pragma unroll
    for (int nt = 0; nt < 32; ++nt) {
      bf16x8 bf = *reinterpret_cast<const bf16x8*>(&Bs[(nt * 16 + fr) * 40 + fkq]);
      acc[nt] = mfma16(af, bf, acc[nt]);
    }
    __syncthreads();
  }
  // fused masked softmax, wave-local (each wave owns 16 complete rows).
  // D-layout: value acc[nt][r] is (row = w*16 + (lane>>4)*4 + r, col = nt*16+fr)
  const float scale = 0.125f;
  const size_t pb = (size_t)bh * 64 * 512;
#pragma unroll
  for (int r = 0; r < 4; ++r) {
    float mx = -3.0e38f;
#pragma unroll
    for (int nt = 0; nt < 32; ++nt) {
      const int col = nt * 16 + fr;
      const float sv = acc[nt][r] * scale;
      if (col < new_len) mx = fmaxf(mx, sv);
    }
#pragma unroll
    for (int off = 1; off < 16; off <<= 1) mx = fmaxf(mx, __shfl_xor(mx, off, 64));
    float sum = 0.f;
#pragma unroll
    for (int nt = 0; nt < 32; ++nt) {
      const int col = nt * 16 + fr;
      const float e = (col < new_len) ? __expf(acc[nt][r] * scale - mx) : 0.f;
      acc[nt][r] = e;
      sum += e;
    }
#pragma unroll
    for (int off = 1; off < 16; off <<= 1) sum += __shfl_xor(sum, off, 64);
    const float inv = 1.f / sum;
    const int row = w * 16 + ((lane >> 4) << 2) + r;
    __bf16* dst = P + pb + (size_t)row * 512 + fr;
#pragma unroll
    for (int nt = 0; nt < 32; ++nt) dst[nt * 16] = (__bf16)(acc[nt][r] * inv);
  }
}

// =====================================================================
// Attention stage 2: ctx = P_h(64x512 bf16) @ V_h(512x64). V is (K,N)
// row-major -> standard gemm-style B column-gather staging (coalesced).
// =====================================================================
__global__ __launch_bounds__(256) void attn_pv_kernel(
    const __bf16* __restrict__ P, const float* __restrict__ v,
    float* __restrict__ ctx) {
  __shared__ __bf16 As[64 * 40];
  __shared__ __bf16 Bs[64 * 40];
  const int t = threadIdx.x, lane = t & 63, w = t >> 6;
  const int bh = blockIdx.x, b = bh >> 3, h = bh & 7;
  const size_t pbase = (size_t)bh * 64 * 512;
  const size_t vbase = (size_t)b * 512 * 512 + h * 64;
  f32x4 acc[4];
#pragma unroll
  for (int j = 0; j < 4; ++j) acc[j] = f32x4{0.f, 0.f, 0.f, 0.f};
  const int fr = lane & 15, fk = (lane >> 4) * 8;
  const int arow = t >> 2, ac = (t & 3) * 8;
  const int bn = t & 63, bk = (t >> 6) * 8;
  for (int s = 0; s < 16; ++s) {
    const int k0 = s * 32;
    *reinterpret_cast<bf16x8*>(&As[arow * 40 + ac]) =
        *reinterpret_cast<const bf16x8*>(&P[pbase + (size_t)arow * 512 + k0 + ac]);
    {
      float tmp[8];
#pragma unroll
      for (int j = 0; j < 8; ++j)
        tmp[j] = v[vbase + (size_t)(k0 + bk + j) * 512 + bn];
      *reinterpret_cast<bf16x8*>(&Bs[bn * 40 + bk]) = cvt8(tmp);
    }
    __syncthreads();
    const bf16x8 a = *reinterpret_cast<const bf16x8*>(&As[(w * 16 + fr) * 40 + fk]);
#pragma unroll
    for (int j = 0; j < 4; ++j) {
      bf16x8 bfrag = *reinterpret_cast<const bf16x8*>(&Bs[(j * 16 + fr) * 40 + fk]);
      acc[j] = mfma16(a, bfrag, acc[j]);
    }
    __syncthreads();
  }
  const int rq = (lane >> 4) * 4;
  const size_t cbase = (size_t)b * 64 * 512 + h * 64;
#pragma unroll
  for (int j = 0; j < 4; ++j)
#pragma unroll
    for (int r = 0; r < 4; ++r)
      ctx[cbase + (size_t)(w * 16 + rq + r) * 512 + j * 16 + fr] = acc[j][r];
}

// LayerNorm over rows of 512 (for ctx @ Wo + bo)
__global__ __launch_bounds__(256) void ln_kernel(const float* __restrict__ x,
                                                 const float* __restrict__ g,
                                                 const float* __restrict__ bt,
                                                 float* __restrict__ y) {
  __shared__ float red[8];
  const int t = threadIdx.x;
  const size_t off = (size_t)blockIdx.x * 512;
  const float a = x[off + t], b2 = x[off + t + 256];
  float s = a + b2, sq = a * a + b2 * b2;
  blockRed2(s, sq, red);
  const float m = s * (1.f / 512.f);
  const float var = sq * (1.f / 512.f) - m * m;
  const float rs = rsqrtf(var + 1e-5f);
  y[off + t] = (a - m) * rs * g[t] + bt[t];
  y[off + t + 256] = (b2 - m) * rs * g[t + 256] + bt[t + 256];
}

// =====================================================================
extern "C" void kernel_launch(void* const* d_in, const int* in_sizes, int n_in,
                              void* d_out, int out_size, void* d_ws,
                              size_t ws_size, hipStream_t stream) {
  const float* images = (const float*)d_in[0];
  const float* qgrids = (const float*)d_in[1];
  const float* keypoints = (const float*)d_in[2];
  const int* qlens = (const int*)d_in[3];
  const float* W_img = (const float*)d_in[4];
  const float* b_img = (const float*)d_in[5];
  const float* W_kp = (const float*)d_in[6];
  const float* b_kp = (const float*)d_in[7];
  const float* g_kp = (const float*)d_in[8];
  const float* bt_kp = (const float*)d_in[9];
  const float* W_qp = (const float*)d_in[10];
  const float* b_qp = (const float*)d_in[11];
  const float* g_qln = (const float*)d_in[12];
  const float* bt_qln = (const float*)d_in[13];
  const float* Wq = (const float*)d_in[14];
  const float* bq = (const float*)d_in[15];
  const float* Wk = (const float*)d_in[16];
  const float* bk = (const float*)d_in[17];
  const float* Wv = (const float*)d_in[18];
  const float* bv = (const float*)d_in[19];
  const float* Wo = (const float*)d_in[20];
  const float* bo = (const float*)d_in[21];
  const float* g_attn = (const float*)d_in[22];
  const float* bt_attn = (const float*)d_in[23];
  const float* W_ctc = (const float*)d_in[24];
  const float* b_ctc = (const float*)d_in[25];
  float* out = (float*)d_out;

  const size_t MB = 1u << 20;
  if (ws_size < 29 * MB) return;  // need 29 MB of scratch
  char* ws = (char*)d_ws;
  float* low = (float*)(ws);            // 1 MB  (512x512)
  float* qbuf = (float*)(ws + 1 * MB);  // 1 MB
  __bf16* pbuf = (__bf16*)(ws + 2 * MB);  // 512 KB (P, bf16) -- dead before ctxo
  float* ctxo = (float*)(ws + 2 * MB);    // 1 MB (reuses pbuf region, sequential)
  float* ctxln = (float*)(ws + 3 * MB); // 1 MB
  float* pooled = (float*)(ws + 4 * MB);    // 8 MB (8x512x512)
  float* partials = (float*)(ws + 12 * MB); // 24 MB (24x512x512)
  float* kbuf = partials;                   // reuse after reduce (8 MB)
  float* vbuf = (float*)(ws + 20 * MB);     // 8 MB
  float* ctx = (float*)(ws + 28 * MB);      // 1 MB

  // 1) img GEMM partials (split-K=24)
  img_gemm_kernel<<<dim3(4, 4, SPLITK), 256, 0, stream>>>(images, W_img, partials);
  // 2) kp_feat -> low
  kp_kernel<<<512, 256, 0, stream>>>(keypoints, W_kp, b_kp, g_kp, bt_kp, low);
  // 3) low += b_img + sum(partials)
  reduce_add_kernel<<<1024, 256, 0, stream>>>(partials, b_img, low);
  // 4) pooled qgrid tokens (proj + LN + ragged mean-pool)
  pool_kernel<<<2048, 256, 0, stream>>>(qgrids, qlens, W_qp, b_qp, g_qln, bt_qln, pooled);
  // 5) k, v from pooled (partials region is dead now)
  gemm_kernel<<<dim3(8, 64), 256, 0, stream>>>(pooled, Wk, bk, kbuf, 4096, 512, 512, 1);
  gemm_kernel<<<dim3(8, 64), 256, 0, stream>>>(pooled, Wv, bv, vbuf, 4096, 512, 512, 1);
  // 6) q from low
  gemm_kernel<<<dim3(8, 8), 256, 0, stream>>>(low, Wq, bq, qbuf, 512, 512, 512, 1);
  // 7) fused attention: batched MFMA scores+softmax, then MFMA PV
  attn_scores_kernel<<<64, 256, 0, stream>>>(qbuf, kbuf, qlens, pbuf);
  attn_pv_kernel<<<64, 256, 0, stream>>>(pbuf, vbuf, ctx);
  // 8) ctx @ Wo + bo, then LN
  gemm_kernel<<<dim3(8, 8), 256, 0, stream>>>(ctx, Wo, bo, ctxo, 512, 512, 512, 1);
  ln_kernel<<<512, 256, 0, stream>>>(ctxo, g_attn, bt_attn, ctxln);
  // 9) out = low @ W_ctc[:512] + b_ctc ; out += ctxln @ W_ctc[512:]
  gemm_kernel<<<dim3(21, 8), 256, 0, stream>>>(low, W_ctc, b_ctc, out, 512, 1296, 512, 1);
  gemm_kernel<<<dim3(21, 8), 256, 0, stream>>>(ctxln, W_ctc + (size_t)512 * 1296, nullptr, out, 512, 1296, 512, 2);
}

// Round 3
// 470.280 us; speedup vs baseline: 1.4142x; 1.1191x over previous
//
#include <hip/hip_runtime.h>
#include <hip/hip_bf16.h>

typedef __bf16 bf16x8 __attribute__((ext_vector_type(8)));
typedef __bf16 bf16x4 __attribute__((ext_vector_type(4)));
typedef float f32x4 __attribute__((ext_vector_type(4)));
typedef float f32x2 __attribute__((ext_vector_type(2)));

__device__ __forceinline__ f32x4 mfma16(bf16x8 a, bf16x8 b, f32x4 c) {
  return __builtin_amdgcn_mfma_f32_16x16x32_bf16(a, b, c, 0, 0, 0);
}

__device__ __forceinline__ bf16x8 cvt8(const float* f) {
  bf16x8 r;
#pragma unroll
  for (int i = 0; i < 8; ++i) r[i] = (__bf16)f[i];
  return r;
}

__device__ __forceinline__ bf16x4 cvt4(f32x4 v) {
  bf16x4 r;
#pragma unroll
  for (int i = 0; i < 4; ++i) r[i] = (__bf16)v[i];
  return r;
}

// ---- block reduction helpers (blockDim.x == 256 assumed, 4 waves) ----
__device__ __forceinline__ void blockRed2(float& a, float& b, float* red) {
#pragma unroll
  for (int off = 1; off < 64; off <<= 1) {
    a += __shfl_xor(a, off, 64);
    b += __shfl_xor(b, off, 64);
  }
  const int w = threadIdx.x >> 6;
  if ((threadIdx.x & 63) == 0) { red[w] = a; red[4 + w] = b; }
  __syncthreads();
  a = red[0] + red[1] + red[2] + red[3];
  b = red[4] + red[5] + red[6] + red[7];
  __syncthreads();
}

// =====================================================================
// Stage A: img_feat partials = images_flat(512x37632) @ W_img(37632x512)
// split-K=24, tile 128x128, 4 waves each 64x64, fp32->bf16 staging.
// =====================================================================
#define IMG_K 37632
#define SPLITK 24
#define STEPS_PER 49  // 1176 k-steps of 32 / 24

__global__ __launch_bounds__(256) void img_gemm_kernel(
    const float* __restrict__ A, const float* __restrict__ B,
    float* __restrict__ partials) {
  __shared__ __bf16 As[128 * 40];
  __shared__ __bf16 Bs[128 * 40];
  const int t = threadIdx.x;
  const int lane = t & 63;
  const int w = t >> 6;
  const int wm = (w >> 1) * 64, wn = (w & 1) * 64;
  const int m0 = blockIdx.y * 128, n0 = blockIdx.x * 128;
  const int step0 = blockIdx.z * STEPS_PER;

  f32x4 acc[4][4];
#pragma unroll
  for (int i = 0; i < 4; ++i)
#pragma unroll
    for (int j = 0; j < 4; ++j) acc[i][j] = f32x4{0.f, 0.f, 0.f, 0.f};

  const int ar = t >> 1, ak = (t & 1) * 16;
  const int bn = t & 127, bk = (t >> 7) * 16;
  const int fr = lane & 15, fk = (lane >> 4) * 8;

  for (int s = 0; s < STEPS_PER; ++s) {
    const int k0 = (step0 + s) * 32;
    {  // stage A (row-major, 16 f32/thread)
      const float* src = A + (size_t)(m0 + ar) * IMG_K + k0 + ak;
      float tmp[16];
#pragma unroll
      for (int i = 0; i < 4; ++i) {
        f32x4 v = *reinterpret_cast<const f32x4*>(src + i * 4);
        tmp[i * 4 + 0] = v[0]; tmp[i * 4 + 1] = v[1];
        tmp[i * 4 + 2] = v[2]; tmp[i * 4 + 3] = v[3];
      }
      *reinterpret_cast<bf16x8*>(&As[ar * 40 + ak]) = cvt8(tmp);
      *reinterpret_cast<bf16x8*>(&As[ar * 40 + ak + 8]) = cvt8(tmp + 8);
    }
    {  // stage B transposed: column loads (coalesced across lanes)
      float tmp[16];
#pragma unroll
      for (int j = 0; j < 16; ++j)
        tmp[j] = B[(size_t)(k0 + bk + j) * 512 + n0 + bn];
      *reinterpret_cast<bf16x8*>(&Bs[bn * 40 + bk]) = cvt8(tmp);
      *reinterpret_cast<bf16x8*>(&Bs[bn * 40 + bk + 8]) = cvt8(tmp + 8);
    }
    __syncthreads();
    bf16x8 af[4], bfr[4];
#pragma unroll
    for (int i = 0; i < 4; ++i) {
      af[i] = *reinterpret_cast<const bf16x8*>(&As[(wm + i * 16 + fr) * 40 + fk]);
      bfr[i] = *reinterpret_cast<const bf16x8*>(&Bs[(wn + i * 16 + fr) * 40 + fk]);
    }
#pragma unroll
    for (int i = 0; i < 4; ++i)
#pragma unroll
      for (int j = 0; j < 4; ++j) acc[i][j] = mfma16(af[i], bfr[j], acc[i][j]);
    __syncthreads();
  }

  float* P = partials + (size_t)blockIdx.z * (512 * 512);
  const int rq = (lane >> 4) * 4;
#pragma unroll
  for (int i = 0; i < 4; ++i)
#pragma unroll
    for (int j = 0; j < 4; ++j)
#pragma unroll
      for (int r = 0; r < 4; ++r)
        P[(size_t)(m0 + wm + i * 16 + rq + r) * 512 + (n0 + wn + j * 16 + fr)] =
            acc[i][j][r];
}

// low[idx] = kp_feat(already there) + b_img + sum_z partials[z][idx]
__global__ __launch_bounds__(256) void reduce_add_kernel(
    const float* __restrict__ partials, const float* __restrict__ b_img,
    float* __restrict__ low) {
  const int idx = blockIdx.x * 256 + threadIdx.x;
  float acc = low[idx] + b_img[idx & 511];
#pragma unroll
  for (int z = 0; z < SPLITK; ++z) acc += partials[(size_t)z * 262144 + idx];
  low[idx] = acc;
}

// =====================================================================
// kp_feat = LN(relu(keypoints @ W_kp + b_kp)); one block per row (512)
// =====================================================================
__global__ __launch_bounds__(256) void kp_kernel(
    const float* __restrict__ kp, const float* __restrict__ W,
    const float* __restrict__ bias, const float* __restrict__ g,
    const float* __restrict__ bt, float* __restrict__ low) {
  __shared__ float rowv[242];
  __shared__ float red[8];
  const int t = threadIdx.x;
  const size_t roff = (size_t)blockIdx.x * 242;
  if (t < 242) rowv[t] = kp[roff + t];
  __syncthreads();
  const int d0 = t, d1 = t + 256;
  float p0 = bias[d0], p1 = bias[d1];
  for (int kk = 0; kk < 242; ++kk) {
    const float x = rowv[kk];
    p0 = fmaf(x, W[kk * 512 + d0], p0);
    p1 = fmaf(x, W[kk * 512 + d1], p1);
  }
  p0 = fmaxf(p0, 0.f);
  p1 = fmaxf(p1, 0.f);
  float s = p0 + p1, sq = p0 * p0 + p1 * p1;
  blockRed2(s, sq, red);
  const float m = s * (1.f / 512.f);
  const float var = sq * (1.f / 512.f) - m * m;
  const float rs = rsqrtf(var + 1e-5f);
  const size_t off = (size_t)blockIdx.x * 512;
  low[off + d0] = (p0 - m) * rs * g[d0] + bt[d0];
  low[off + d1] = (p1 - m) * rs * g[d1] + bt[d1];
}

// =====================================================================
// W_qp transpose+convert: Wt[col][k] bf16, k padded 242 -> 256 (zeros).
// Enables direct global B-fragment loads in pool_mfma_kernel.
// =====================================================================
__global__ __launch_bounds__(256) void wqp_transpose_kernel(
    const float* __restrict__ W, __bf16* __restrict__ Wt) {
  const int c = blockIdx.x;   // 512 output columns
  const int t = threadIdx.x;  // 256 k slots
  Wt[(size_t)c * 256 + t] = (t < 242) ? (__bf16)W[(size_t)t * 512 + c] : (__bf16)0.f;
}

// =====================================================================
// Fused MFMA pooling: pooled = pool_mean(LN(qgrids @ W_qp + b_qp)).
// One block per (batch, 16 pooled rows). 512 threads = 8 waves, each
// wave owns 64 output cols (4 MFMA n-tiles). For each window offset
// i < S: project 16 source rows (stride S apart) via MFMA (K=242->256),
// LN them (16-lane shfl + cross-wave LDS), accumulate into pool regs.
// B-fragments load straight from global Wt (L2-resident, no LDS).
// =====================================================================
__global__ __launch_bounds__(512) void pool_mfma_kernel(
    const float* __restrict__ qgrids, const int* __restrict__ lens,
    const __bf16* __restrict__ Wt, const float* __restrict__ bias,
    const float* __restrict__ g, const float* __restrict__ bt,
    float* __restrict__ pooled) {
  __shared__ float red[8][16][2];
  const int t = threadIdx.x, lane = t & 63, w = t >> 6;
  const int b = blockIdx.x >> 5;          // 8 batches
  const int j0 = (blockIdx.x & 31) * 16;  // pooled-row block
  const int L = lens[b];
  int S = (L + 511) >> 9;
  if (S < 1) S = 1;
  const int new_len = (L + S - 1) / S;
  const float* qg_b = qgrids + (size_t)b * 4096 * 242;
  float* pooled_b = pooled + (size_t)b * 512 * 512;

  const int fr = lane & 15;    // A row / B col within tile
  const int fq = lane >> 4;    // quad (k-offset group, D-row group)
  const int fkq = fq * 8;
  const int colbase = w * 64;  // wave's column base (4 tiles of 16)

  float biasv[4], gv[4], btv[4];
#pragma unroll
  for (int nt = 0; nt < 4; ++nt) {
    const int col = colbase + nt * 16 + fr;
    biasv[nt] = bias[col];
    gv[nt] = g[col];
    btv[nt] = bt[col];
  }

  f32x4 pool[4];
#pragma unroll
  for (int nt = 0; nt < 4; ++nt) pool[nt] = f32x4{0.f, 0.f, 0.f, 0.f};

  for (int i = 0; i < S; ++i) {
    const int arow = (j0 + fr) * S + i;  // < 4096 always (j<=511, S<=8)
    const float* asrc = qg_b + (size_t)arow * 242;
    f32x4 acc[4];
#pragma unroll
    for (int nt = 0; nt < 4; ++nt) acc[nt] = f32x4{0.f, 0.f, 0.f, 0.f};
#pragma unroll
    for (int ks = 0; ks < 8; ++ks) {
      bf16x8 af;
      if (ks < 7) {
        // rows are 8B-aligned (242 floats) -> f32x2 loads
        float tmp[8];
#pragma unroll
        for (int p2 = 0; p2 < 4; ++p2) {
          f32x2 v = *reinterpret_cast<const f32x2*>(asrc + ks * 32 + fkq + p2 * 2);
          tmp[p2 * 2] = v[0];
          tmp[p2 * 2 + 1] = v[1];
        }
        af = cvt8(tmp);
      } else {  // last k-step: k in [224,256) -> guard k < 242
        float tmp[8];
#pragma unroll
        for (int jj = 0; jj < 8; ++jj) {
          const int kk = 224 + fkq + jj;
          tmp[jj] = (kk < 242) ? asrc[kk] : 0.f;
        }
        af = cvt8(tmp);
      }
      const __bf16* wt = Wt + ks * 32 + fkq;
#pragma unroll
      for (int nt = 0; nt < 4; ++nt) {
        bf16x8 bfv = *reinterpret_cast<const bf16x8*>(
            wt + (size_t)(colbase + nt * 16 + fr) * 256);
        acc[nt] = mfma16(af, bfv, acc[nt]);
      }
    }
    // + bias, LN stats. acc[nt][r]: row p = fq*4+r, col = colbase+nt*16+fr
    float s[4] = {0.f, 0.f, 0.f, 0.f}, sq[4] = {0.f, 0.f, 0.f, 0.f};
#pragma unroll
    for (int nt = 0; nt < 4; ++nt) {
#pragma unroll
      for (int r = 0; r < 4; ++r) {
        const float v = acc[nt][r] + biasv[nt];
        acc[nt][r] = v;
        s[r] += v;
        sq[r] += v * v;
      }
    }
#pragma unroll
    for (int off = 1; off < 16; off <<= 1) {
#pragma unroll
      for (int r = 0; r < 4; ++r) {
        s[r] += __shfl_xor(s[r], off, 64);
        sq[r] += __shfl_xor(sq[r], off, 64);
      }
    }
    if (fr == 0) {
#pragma unroll
      for (int r = 0; r < 4; ++r) {
        red[w][fq * 4 + r][0] = s[r];
        red[w][fq * 4 + r][1] = sq[r];
      }
    }
    __syncthreads();
    float mean[4], rsig[4];
#pragma unroll
    for (int r = 0; r < 4; ++r) {
      const int p = fq * 4 + r;
      float ss = 0.f, qq = 0.f;
#pragma unroll
      for (int ww = 0; ww < 8; ++ww) {
        ss += red[ww][p][0];
        qq += red[ww][p][1];
      }
      const float m = ss * (1.f / 512.f);
      mean[r] = m;
      rsig[r] = rsqrtf(qq * (1.f / 512.f) - m * m + 1e-5f);
    }
    __syncthreads();  // red reused next iteration
#pragma unroll
    for (int r = 0; r < 4; ++r) {
      const int srow = (j0 + fq * 4 + r) * S + i;
      const bool ok = srow < L;
#pragma unroll
      for (int nt = 0; nt < 4; ++nt) {
        const float nv = (acc[nt][r] - mean[r]) * rsig[r] * gv[nt] + btv[nt];
        pool[nt][r] += ok ? nv : 0.f;
      }
    }
  }
  const float inv = 1.f / (float)S;
#pragma unroll
  for (int r = 0; r < 4; ++r) {
    const int j = j0 + fq * 4 + r;
    const bool ok = j < new_len;
#pragma unroll
    for (int nt = 0; nt < 4; ++nt)
      pooled_b[(size_t)j * 512 + colbase + nt * 16 + fr] =
          ok ? pool[nt][r] * inv : 0.f;
  }
}

// =====================================================================
// Generic bf16-MFMA GEMM: C[M,N] = A[M,K]@B[K,N] (+bias if flags&1,
// += existing C if flags&2). M%64==0, K%32==0; N arbitrary (guarded).
// =====================================================================
__global__ __launch_bounds__(256) void gemm_kernel(
    const float* __restrict__ A, const float* __restrict__ B,
    const float* __restrict__ bias, float* __restrict__ C, int M, int N,
    int K, int flags) {
  __shared__ __bf16 As[64 * 40];
  __shared__ __bf16 Bs[64 * 40];
  const int t = threadIdx.x, lane = t & 63, w = t >> 6;
  const int m0 = blockIdx.y * 64, n0 = blockIdx.x * 64;
  f32x4 acc[4];
#pragma unroll
  for (int j = 0; j < 4; ++j) acc[j] = f32x4{0.f, 0.f, 0.f, 0.f};
  const int ar = t >> 2, ak = (t & 3) * 8;
  const int bn = t & 63, bk = (t >> 6) * 8;
  const int fr = lane & 15, fk = (lane >> 4) * 8;
  const int col = n0 + bn;
  const bool colok = col < N;
  const int nst = K >> 5;
  for (int s = 0; s < nst; ++s) {
    const int k0 = s * 32;
    {
      const float* src = A + (size_t)(m0 + ar) * K + k0 + ak;
      f32x4 v0 = *reinterpret_cast<const f32x4*>(src);
      f32x4 v1 = *reinterpret_cast<const f32x4*>(src + 4);
      float tmp[8] = {v0[0], v0[1], v0[2], v0[3], v1[0], v1[1], v1[2], v1[3]};
      *reinterpret_cast<bf16x8*>(&As[ar * 40 + ak]) = cvt8(tmp);
    }
    {
      float tmp[8];
#pragma unroll
      for (int j = 0; j < 8; ++j)
        tmp[j] = colok ? B[(size_t)(k0 + bk + j) * N + col] : 0.f;
      *reinterpret_cast<bf16x8*>(&Bs[bn * 40 + bk]) = cvt8(tmp);
    }
    __syncthreads();
    bf16x8 a = *reinterpret_cast<const bf16x8*>(&As[(w * 16 + fr) * 40 + fk]);
#pragma unroll
    for (int j = 0; j < 4; ++j) {
      bf16x8 b = *reinterpret_cast<const bf16x8*>(&Bs[(j * 16 + fr) * 40 + fk]);
      acc[j] = mfma16(a, b, acc[j]);
    }
    __syncthreads();
  }
  const int rq = (lane >> 4) * 4;
#pragma unroll
  for (int j = 0; j < 4; ++j) {
    const int c = n0 + j * 16 + fr;
    if (c < N) {
#pragma unroll
      for (int r = 0; r < 4; ++r) {
        const size_t idx = (size_t)(m0 + w * 16 + rq + r) * N + c;
        float v = acc[j][r];
        if (flags & 1) v += bias[c];
        if (flags & 2) v += C[idx];
        C[idx] = v;
      }
    }
  }
}

// =====================================================================
// Attention stage 1: P = softmax(mask(Q_h @ K_h^T / 8)) as bf16.
// =====================================================================
__global__ __launch_bounds__(256) void attn_scores_kernel(
    const float* __restrict__ q, const float* __restrict__ k,
    const int* __restrict__ lens, __bf16* __restrict__ P) {
  __shared__ __bf16 Qs[64 * 72];
  __shared__ __bf16 Bs[512 * 40];
  const int t = threadIdx.x, lane = t & 63, w = t >> 6;
  const int bh = blockIdx.x, b = bh >> 3, h = bh & 7;
  const int L = lens[b];
  const int sdiv = (L + 511) >> 9;
  const int new_len = (L + sdiv - 1) / sdiv;
  const size_t qbase = (size_t)b * 64 * 512 + h * 64;
  const size_t kbase = (size_t)b * 512 * 512 + h * 64;
#pragma unroll
  for (int rep = 0; rep < 4; ++rep) {
    const int gidx = rep * 256 + t;
    const int row = gidx >> 4, c = (gidx & 15) * 4;
    f32x4 v = *reinterpret_cast<const f32x4*>(&q[qbase + (size_t)row * 512 + c]);
    *reinterpret_cast<bf16x4*>(&Qs[row * 72 + c]) = cvt4(v);
  }
  f32x4 acc[32];
#pragma unroll
  for (int nt = 0; nt < 32; ++nt) acc[nt] = f32x4{0.f, 0.f, 0.f, 0.f};
  const int fr = lane & 15, fkq = (lane >> 4) * 8;
  for (int ks = 0; ks < 2; ++ks) {
    const int k0 = ks * 32;
#pragma unroll
    for (int rep = 0; rep < 16; ++rep) {
      const int gidx = rep * 256 + t;
      const int row = gidx >> 3, c = (gidx & 7) * 4;
      f32x4 v =
          *reinterpret_cast<const f32x4*>(&k[kbase + (size_t)row * 512 + k0 + c]);
      *reinterpret_cast<bf16x4*>(&Bs[row * 40 + c]) = cvt4(v);
    }
    __syncthreads();
    const bf16x8 af =
        *reinterpret_cast<const bf16x8*>(&Qs[(w * 16 + fr) * 72 + k0 + fkq]);
#pragma unroll
    for (int nt = 0; nt < 32; ++nt) {
      bf16x8 bf = *reinterpret_cast<const bf16x8*>(&Bs[(nt * 16 + fr) * 40 + fkq]);
      acc[nt] = mfma16(af, bf, acc[nt]);
    }
    __syncthreads();
  }
  const float scale = 0.125f;
  const size_t pb = (size_t)bh * 64 * 512;
#pragma unroll
  for (int r = 0; r < 4; ++r) {
    float mx = -3.0e38f;
#pragma unroll
    for (int nt = 0; nt < 32; ++nt) {
      const int col = nt * 16 + fr;
      const float sv = acc[nt][r] * scale;
      if (col < new_len) mx = fmaxf(mx, sv);
    }
#pragma unroll
    for (int off = 1; off < 16; off <<= 1) mx = fmaxf(mx, __shfl_xor(mx, off, 64));
    float sum = 0.f;
#pragma unroll
    for (int nt = 0; nt < 32; ++nt) {
      const int col = nt * 16 + fr;
      const float e = (col < new_len) ? __expf(acc[nt][r] * scale - mx) : 0.f;
      acc[nt][r] = e;
      sum += e;
    }
#pragma unroll
    for (int off = 1; off < 16; off <<= 1) sum += __shfl_xor(sum, off, 64);
    const float inv = 1.f / sum;
    const int row = w * 16 + ((lane >> 4) << 2) + r;
    __bf16* dst = P + pb + (size_t)row * 512 + fr;
#pragma unroll
    for (int nt = 0; nt < 32; ++nt) dst[nt * 16] = (__bf16)(acc[nt][r] * inv);
  }
}

// =====================================================================
// Attention stage 2: ctx = P_h(64x512 bf16) @ V_h(512x64).
// =====================================================================
__global__ __launch_bounds__(256) void attn_pv_kernel(
    const __bf16* __restrict__ P, const float* __restrict__ v,
    float* __restrict__ ctx) {
  __shared__ __bf16 As[64 * 40];
  __shared__ __bf16 Bs[64 * 40];
  const int t = threadIdx.x, lane = t & 63, w = t >> 6;
  const int bh = blockIdx.x, b = bh >> 3, h = bh & 7;
  const size_t pbase = (size_t)bh * 64 * 512;
  const size_t vbase = (size_t)b * 512 * 512 + h * 64;
  f32x4 acc[4];
#pragma unroll
  for (int j = 0; j < 4; ++j) acc[j] = f32x4{0.f, 0.f, 0.f, 0.f};
  const int fr = lane & 15, fk = (lane >> 4) * 8;
  const int arow = t >> 2, ac = (t & 3) * 8;
  const int bn = t & 63, bk = (t >> 6) * 8;
  for (int s = 0; s < 16; ++s) {
    const int k0 = s * 32;
    *reinterpret_cast<bf16x8*>(&As[arow * 40 + ac]) =
        *reinterpret_cast<const bf16x8*>(&P[pbase + (size_t)arow * 512 + k0 + ac]);
    {
      float tmp[8];
#pragma unroll
      for (int j = 0; j < 8; ++j)
        tmp[j] = v[vbase + (size_t)(k0 + bk + j) * 512 + bn];
      *reinterpret_cast<bf16x8*>(&Bs[bn * 40 + bk]) = cvt8(tmp);
    }
    __syncthreads();
    const bf16x8 a = *reinterpret_cast<const bf16x8*>(&As[(w * 16 + fr) * 40 + fk]);
#pragma unroll
    for (int j = 0; j < 4; ++j) {
      bf16x8 bfrag = *reinterpret_cast<const bf16x8*>(&Bs[(j * 16 + fr) * 40 + fk]);
      acc[j] = mfma16(a, bfrag, acc[j]);
    }
    __syncthreads();
  }
  const int rq = (lane >> 4) * 4;
  const size_t cbase = (size_t)b * 64 * 512 + h * 64;
#pragma unroll
  for (int j = 0; j < 4; ++j)
#pragma unroll
    for (int r = 0; r < 4; ++r)
      ctx[cbase + (size_t)(w * 16 + rq + r) * 512 + j * 16 + fr] = acc[j][r];
}

// LayerNorm over rows of 512 (for ctx @ Wo + bo)
__global__ __launch_bounds__(256) void ln_kernel(const float* __restrict__ x,
                                                 const float* __restrict__ g,
                                                 const float* __restrict__ bt,
                                                 float* __restrict__ y) {
  __shared__ float red[8];
  const int t = threadIdx.x;
  const size_t off = (size_t)blockIdx.x * 512;
  const float a = x[off + t], b2 = x[off + t + 256];
  float s = a + b2, sq = a * a + b2 * b2;
  blockRed2(s, sq, red);
  const float m = s * (1.f / 512.f);
  const float var = sq * (1.f / 512.f) - m * m;
  const float rs = rsqrtf(var + 1e-5f);
  y[off + t] = (a - m) * rs * g[t] + bt[t];
  y[off + t + 256] = (b2 - m) * rs * g[t + 256] + bt[t + 256];
}

// =====================================================================
extern "C" void kernel_launch(void* const* d_in, const int* in_sizes, int n_in,
                              void* d_out, int out_size, void* d_ws,
                              size_t ws_size, hipStream_t stream) {
  const float* images = (const float*)d_in[0];
  const float* qgrids = (const float*)d_in[1];
  const float* keypoints = (const float*)d_in[2];
  const int* qlens = (const int*)d_in[3];
  const float* W_img = (const float*)d_in[4];
  const float* b_img = (const float*)d_in[5];
  const float* W_kp = (const float*)d_in[6];
  const float* b_kp = (const float*)d_in[7];
  const float* g_kp = (const float*)d_in[8];
  const float* bt_kp = (const float*)d_in[9];
  const float* W_qp = (const float*)d_in[10];
  const float* b_qp = (const float*)d_in[11];
  const float* g_qln = (const float*)d_in[12];
  const float* bt_qln = (const float*)d_in[13];
  const float* Wq = (const float*)d_in[14];
  const float* bq = (const float*)d_in[15];
  const float* Wk = (const float*)d_in[16];
  const float* bk = (const float*)d_in[17];
  const float* Wv = (const float*)d_in[18];
  const float* bv = (const float*)d_in[19];
  const float* Wo = (const float*)d_in[20];
  const float* bo = (const float*)d_in[21];
  const float* g_attn = (const float*)d_in[22];
  const float* bt_attn = (const float*)d_in[23];
  const float* W_ctc = (const float*)d_in[24];
  const float* b_ctc = (const float*)d_in[25];
  float* out = (float*)d_out;

  const size_t MB = 1u << 20;
  if (ws_size < 29 * MB) return;  // need 29 MB of scratch
  char* ws = (char*)d_ws;
  float* low = (float*)(ws);              // 1 MB  (512x512)
  float* qbuf = (float*)(ws + 1 * MB);    // 1 MB
  __bf16* wtq = (__bf16*)(ws + 2 * MB);   // 256 KB Wt (dead before pbuf)
  __bf16* pbuf = (__bf16*)(ws + 2 * MB);  // 512 KB (P, bf16) -- dead before ctxo
  float* ctxo = (float*)(ws + 2 * MB);    // 1 MB (reuses pbuf region, sequential)
  float* ctxln = (float*)(ws + 3 * MB);   // 1 MB
  float* pooled = (float*)(ws + 4 * MB);     // 8 MB (8x512x512)
  float* partials = (float*)(ws + 12 * MB);  // 24 MB (24x512x512)
  float* kbuf = partials;                    // reuse after reduce (8 MB)
  float* vbuf = (float*)(ws + 20 * MB);      // 8 MB
  float* ctx = (float*)(ws + 28 * MB);       // 1 MB

  // 0) Wt = transpose(W_qp) in bf16, K padded to 256
  wqp_transpose_kernel<<<512, 256, 0, stream>>>(W_qp, wtq);
  // 1) img GEMM partials (split-K=24)
  img_gemm_kernel<<<dim3(4, 4, SPLITK), 256, 0, stream>>>(images, W_img, partials);
  // 2) kp_feat -> low
  kp_kernel<<<512, 256, 0, stream>>>(keypoints, W_kp, b_kp, g_kp, bt_kp, low);
  // 3) low += b_img + sum(partials)
  reduce_add_kernel<<<1024, 256, 0, stream>>>(partials, b_img, low);
  // 4) pooled qgrid tokens (MFMA proj + LN + ragged mean-pool)
  pool_mfma_kernel<<<256, 512, 0, stream>>>(qgrids, qlens, wtq, b_qp, g_qln,
                                            bt_qln, pooled);
  // 5) k, v from pooled (partials region is dead now)
  gemm_kernel<<<dim3(8, 64), 256, 0, stream>>>(pooled, Wk, bk, kbuf, 4096, 512, 512, 1);
  gemm_kernel<<<dim3(8, 64), 256, 0, stream>>>(pooled, Wv, bv, vbuf, 4096, 512, 512, 1);
  // 6) q from low
  gemm_kernel<<<dim3(8, 8), 256, 0, stream>>>(low, Wq, bq, qbuf, 512, 512, 512, 1);
  // 7) fused attention: batched MFMA scores+softmax, then MFMA PV
  attn_scores_kernel<<<64, 256, 0, stream>>>(qbuf, kbuf, qlens, pbuf);
  attn_pv_kernel<<<64, 256, 0, stream>>>(pbuf, vbuf, ctx);
  // 8) ctx @ Wo + bo, then LN
  gemm_kernel<<<dim3(8, 8), 256, 0, stream>>>(ctx, Wo, bo, ctxo, 512, 512, 512, 1);
  ln_kernel<<<512, 256, 0, stream>>>(ctxo, g_attn, bt_attn, ctxln);
  // 9) out = low @ W_ctc[:512] + b_ctc ; out += ctxln @ W_ctc[512:]
  gemm_kernel<<<dim3(21, 8), 256, 0, stream>>>(low, W_ctc, b_ctc, out, 512, 1296, 512, 1);
  gemm_kernel<<<dim3(21, 8), 256, 0, stream>>>(ctxln, W_ctc + (size_t)512 * 1296, nullptr, out, 512, 1296, 512, 2);
}

// Round 4
// 385.031 us; speedup vs baseline: 1.7273x; 1.2214x over previous
//
#include <hip/hip_runtime.h>
#include <hip/hip_bf16.h>

typedef __bf16 bf16x8 __attribute__((ext_vector_type(8)));
typedef __bf16 bf16x4 __attribute__((ext_vector_type(4)));
typedef float f32x4 __attribute__((ext_vector_type(4)));
typedef float f32x2 __attribute__((ext_vector_type(2)));

__device__ __forceinline__ f32x4 mfma16(bf16x8 a, bf16x8 b, f32x4 c) {
  return __builtin_amdgcn_mfma_f32_16x16x32_bf16(a, b, c, 0, 0, 0);
}

__device__ __forceinline__ bf16x8 cvt8(const float* f) {
  bf16x8 r;
#pragma unroll
  for (int i = 0; i < 8; ++i) r[i] = (__bf16)f[i];
  return r;
}

__device__ __forceinline__ bf16x4 cvt4(f32x4 v) {
  bf16x4 r;
#pragma unroll
  for (int i = 0; i < 4; ++i) r[i] = (__bf16)v[i];
  return r;
}

// ---- block reduction helpers (blockDim.x == 256 assumed, 4 waves) ----
__device__ __forceinline__ void blockRed2(float& a, float& b, float* red) {
#pragma unroll
  for (int off = 1; off < 64; off <<= 1) {
    a += __shfl_xor(a, off, 64);
    b += __shfl_xor(b, off, 64);
  }
  const int w = threadIdx.x >> 6;
  if ((threadIdx.x & 63) == 0) { red[w] = a; red[4 + w] = b; }
  __syncthreads();
  a = red[0] + red[1] + red[2] + red[3];
  b = red[4] + red[5] + red[6] + red[7];
  __syncthreads();
}

// =====================================================================
// Stage A: img_feat partials = images_flat(512x37632) @ W_img(37632x512)
// split-K=24, tile 128x128, 512 threads = 8 waves (wave tile 64x32),
// double-buffered LDS, reg-staged async pipeline (1 barrier / K-step).
// =====================================================================
#define IMG_K 37632
#define SPLITK 24
#define STEPS_PER 49  // 1176 k-steps of 32 / 24

__global__ __launch_bounds__(512) void img_gemm_kernel(
    const float* __restrict__ A, const float* __restrict__ B,
    float* __restrict__ partials) {
  __shared__ __bf16 As[2][128 * 40];
  __shared__ __bf16 Bs[2][128 * 40];
  const int t = threadIdx.x;
  const int lane = t & 63;
  const int w = t >> 6;
  const int wr = (w >> 2) * 64;  // wave row base: 0 / 64
  const int wc = (w & 3) * 32;   // wave col base: 0/32/64/96
  const int m0 = blockIdx.y * 128, n0 = blockIdx.x * 128;
  const int step0 = blockIdx.z * STEPS_PER;

  f32x4 acc[4][2];
#pragma unroll
  for (int i = 0; i < 4; ++i)
#pragma unroll
    for (int j = 0; j < 2; ++j) acc[i][j] = f32x4{0.f, 0.f, 0.f, 0.f};

  // staging map: A row = t>>2 (128 rows), 8 k-floats; B col = t&127, 8 k's
  const int ar = t >> 2, ak = (t & 3) * 8;
  const int bn = t & 127, bk = (t >> 7) * 8;
  const int fr = lane & 15, fk = (lane >> 4) * 8;

  float atm[8], btm[8];
#define IMG_LOAD(K0)                                                        \
  do {                                                                      \
    const float* asrc = A + (size_t)(m0 + ar) * IMG_K + (K0) + ak;          \
    f32x4 v0 = *reinterpret_cast<const f32x4*>(asrc);                       \
    f32x4 v1 = *reinterpret_cast<const f32x4*>(asrc + 4);                   \
    atm[0] = v0[0]; atm[1] = v0[1]; atm[2] = v0[2]; atm[3] = v0[3];         \
    atm[4] = v1[0]; atm[5] = v1[1]; atm[6] = v1[2]; atm[7] = v1[3];         \
    const float* bsrc = B + (size_t)((K0) + bk) * 512 + n0 + bn;            \
    _Pragma("unroll") for (int j = 0; j < 8; ++j) btm[j] =                  \
        bsrc[(size_t)j * 512];                                              \
  } while (0)
#define IMG_WRITE(BUF)                                                      \
  do {                                                                      \
    *reinterpret_cast<bf16x8*>(&As[BUF][ar * 40 + ak]) = cvt8(atm);         \
    *reinterpret_cast<bf16x8*>(&Bs[BUF][bn * 40 + bk]) = cvt8(btm);         \
  } while (0)

  IMG_LOAD(step0 * 32);
  IMG_WRITE(0);
  __syncthreads();

  for (int s = 0; s < STEPS_PER; ++s) {
    const int cur = s & 1;
    const bool more = (s + 1) < STEPS_PER;
    if (more) IMG_LOAD((step0 + s + 1) * 32);  // issue early (hides under MFMA)
    bf16x8 af[4], bfr[2];
#pragma unroll
    for (int i = 0; i < 4; ++i)
      af[i] =
          *reinterpret_cast<const bf16x8*>(&As[cur][(wr + i * 16 + fr) * 40 + fk]);
#pragma unroll
    for (int j = 0; j < 2; ++j)
      bfr[j] =
          *reinterpret_cast<const bf16x8*>(&Bs[cur][(wc + j * 16 + fr) * 40 + fk]);
#pragma unroll
    for (int i = 0; i < 4; ++i)
#pragma unroll
      for (int j = 0; j < 2; ++j) acc[i][j] = mfma16(af[i], bfr[j], acc[i][j]);
    if (more) IMG_WRITE(cur ^ 1);  // write-late into the other buffer
    __syncthreads();
  }
#undef IMG_LOAD
#undef IMG_WRITE

  float* P = partials + (size_t)blockIdx.z * (512 * 512);
  const int rq = (lane >> 4) * 4;
#pragma unroll
  for (int i = 0; i < 4; ++i)
#pragma unroll
    for (int j = 0; j < 2; ++j)
#pragma unroll
      for (int r = 0; r < 4; ++r)
        P[(size_t)(m0 + wr + i * 16 + rq + r) * 512 + (n0 + wc + j * 16 + fr)] =
            acc[i][j][r];
}

// low[idx] = kp_feat(already there) + b_img + sum_z partials[z][idx]
__global__ __launch_bounds__(256) void reduce_add_kernel(
    const float* __restrict__ partials, const float* __restrict__ b_img,
    float* __restrict__ low) {
  const int idx = blockIdx.x * 256 + threadIdx.x;
  float acc = low[idx] + b_img[idx & 511];
#pragma unroll
  for (int z = 0; z < SPLITK; ++z) acc += partials[(size_t)z * 262144 + idx];
  low[idx] = acc;
}

// =====================================================================
// kp_feat = LN(relu(keypoints @ W_kp + b_kp)); one block per row (512)
// =====================================================================
__global__ __launch_bounds__(256) void kp_kernel(
    const float* __restrict__ kp, const float* __restrict__ W,
    const float* __restrict__ bias, const float* __restrict__ g,
    const float* __restrict__ bt, float* __restrict__ low) {
  __shared__ float rowv[242];
  __shared__ float red[8];
  const int t = threadIdx.x;
  const size_t roff = (size_t)blockIdx.x * 242;
  if (t < 242) rowv[t] = kp[roff + t];
  __syncthreads();
  const int d0 = t, d1 = t + 256;
  float p0 = bias[d0], p1 = bias[d1];
  for (int kk = 0; kk < 242; ++kk) {
    const float x = rowv[kk];
    p0 = fmaf(x, W[kk * 512 + d0], p0);
    p1 = fmaf(x, W[kk * 512 + d1], p1);
  }
  p0 = fmaxf(p0, 0.f);
  p1 = fmaxf(p1, 0.f);
  float s = p0 + p1, sq = p0 * p0 + p1 * p1;
  blockRed2(s, sq, red);
  const float m = s * (1.f / 512.f);
  const float var = sq * (1.f / 512.f) - m * m;
  const float rs = rsqrtf(var + 1e-5f);
  const size_t off = (size_t)blockIdx.x * 512;
  low[off + d0] = (p0 - m) * rs * g[d0] + bt[d0];
  low[off + d1] = (p1 - m) * rs * g[d1] + bt[d1];
}

// =====================================================================
// W_qp transpose+convert: Wt[col][k] bf16, k padded 242 -> 256 (zeros).
// =====================================================================
__global__ __launch_bounds__(256) void wqp_transpose_kernel(
    const float* __restrict__ W, __bf16* __restrict__ Wt) {
  const int c = blockIdx.x;   // 512 output columns
  const int t = threadIdx.x;  // 256 k slots
  Wt[(size_t)c * 256 + t] = (t < 242) ? (__bf16)W[(size_t)t * 512 + c] : (__bf16)0.f;
}

// =====================================================================
// Fused MFMA pooling: pooled = pool_mean(LN(qgrids @ W_qp + b_qp)).
// =====================================================================
__global__ __launch_bounds__(512) void pool_mfma_kernel(
    const float* __restrict__ qgrids, const int* __restrict__ lens,
    const __bf16* __restrict__ Wt, const float* __restrict__ bias,
    const float* __restrict__ g, const float* __restrict__ bt,
    float* __restrict__ pooled) {
  __shared__ float red[8][16][2];
  const int t = threadIdx.x, lane = t & 63, w = t >> 6;
  const int b = blockIdx.x >> 5;          // 8 batches
  const int j0 = (blockIdx.x & 31) * 16;  // pooled-row block
  const int L = lens[b];
  int S = (L + 511) >> 9;
  if (S < 1) S = 1;
  const int new_len = (L + S - 1) / S;
  const float* qg_b = qgrids + (size_t)b * 4096 * 242;
  float* pooled_b = pooled + (size_t)b * 512 * 512;

  const int fr = lane & 15;    // A row / B col within tile
  const int fq = lane >> 4;    // quad (k-offset group, D-row group)
  const int fkq = fq * 8;
  const int colbase = w * 64;  // wave's column base (4 tiles of 16)

  float biasv[4], gv[4], btv[4];
#pragma unroll
  for (int nt = 0; nt < 4; ++nt) {
    const int col = colbase + nt * 16 + fr;
    biasv[nt] = bias[col];
    gv[nt] = g[col];
    btv[nt] = bt[col];
  }

  f32x4 pool[4];
#pragma unroll
  for (int nt = 0; nt < 4; ++nt) pool[nt] = f32x4{0.f, 0.f, 0.f, 0.f};

  for (int i = 0; i < S; ++i) {
    const int arow = (j0 + fr) * S + i;
    const float* asrc = qg_b + (size_t)arow * 242;
    f32x4 acc[4];
#pragma unroll
    for (int nt = 0; nt < 4; ++nt) acc[nt] = f32x4{0.f, 0.f, 0.f, 0.f};
#pragma unroll
    for (int ks = 0; ks < 8; ++ks) {
      bf16x8 af;
      if (ks < 7) {
        float tmp[8];
#pragma unroll
        for (int p2 = 0; p2 < 4; ++p2) {
          f32x2 v = *reinterpret_cast<const f32x2*>(asrc + ks * 32 + fkq + p2 * 2);
          tmp[p2 * 2] = v[0];
          tmp[p2 * 2 + 1] = v[1];
        }
        af = cvt8(tmp);
      } else {
        float tmp[8];
#pragma unroll
        for (int jj = 0; jj < 8; ++jj) {
          const int kk = 224 + fkq + jj;
          tmp[jj] = (kk < 242) ? asrc[kk] : 0.f;
        }
        af = cvt8(tmp);
      }
      const __bf16* wt = Wt + ks * 32 + fkq;
#pragma unroll
      for (int nt = 0; nt < 4; ++nt) {
        bf16x8 bfv = *reinterpret_cast<const bf16x8*>(
            wt + (size_t)(colbase + nt * 16 + fr) * 256);
        acc[nt] = mfma16(af, bfv, acc[nt]);
      }
    }
    float s[4] = {0.f, 0.f, 0.f, 0.f}, sq[4] = {0.f, 0.f, 0.f, 0.f};
#pragma unroll
    for (int nt = 0; nt < 4; ++nt) {
#pragma unroll
      for (int r = 0; r < 4; ++r) {
        const float v = acc[nt][r] + biasv[nt];
        acc[nt][r] = v;
        s[r] += v;
        sq[r] += v * v;
      }
    }
#pragma unroll
    for (int off = 1; off < 16; off <<= 1) {
#pragma unroll
      for (int r = 0; r < 4; ++r) {
        s[r] += __shfl_xor(s[r], off, 64);
        sq[r] += __shfl_xor(sq[r], off, 64);
      }
    }
    if (fr == 0) {
#pragma unroll
      for (int r = 0; r < 4; ++r) {
        red[w][fq * 4 + r][0] = s[r];
        red[w][fq * 4 + r][1] = sq[r];
      }
    }
    __syncthreads();
    float mean[4], rsig[4];
#pragma unroll
    for (int r = 0; r < 4; ++r) {
      const int p = fq * 4 + r;
      float ss = 0.f, qq = 0.f;
#pragma unroll
      for (int ww = 0; ww < 8; ++ww) {
        ss += red[ww][p][0];
        qq += red[ww][p][1];
      }
      const float m = ss * (1.f / 512.f);
      mean[r] = m;
      rsig[r] = rsqrtf(qq * (1.f / 512.f) - m * m + 1e-5f);
    }
    __syncthreads();
#pragma unroll
    for (int r = 0; r < 4; ++r) {
      const int srow = (j0 + fq * 4 + r) * S + i;
      const bool ok = srow < L;
#pragma unroll
      for (int nt = 0; nt < 4; ++nt) {
        const float nv = (acc[nt][r] - mean[r]) * rsig[r] * gv[nt] + btv[nt];
        pool[nt][r] += ok ? nv : 0.f;
      }
    }
  }
  const float inv = 1.f / (float)S;
#pragma unroll
  for (int r = 0; r < 4; ++r) {
    const int j = j0 + fq * 4 + r;
    const bool ok = j < new_len;
#pragma unroll
    for (int nt = 0; nt < 4; ++nt)
      pooled_b[(size_t)j * 512 + colbase + nt * 16 + fr] =
          ok ? pool[nt][r] * inv : 0.f;
  }
}

// =====================================================================
// Generic bf16-MFMA GEMM: C[M,N] = A[M,K]@B[K,N] (+bias if flags&1,
// += existing C if flags&2). M%64==0, K%32==0; N arbitrary (guarded).
// =====================================================================
__global__ __launch_bounds__(256) void gemm_kernel(
    const float* __restrict__ A, const float* __restrict__ B,
    const float* __restrict__ bias, float* __restrict__ C, int M, int N,
    int K, int flags) {
  __shared__ __bf16 As[64 * 40];
  __shared__ __bf16 Bs[64 * 40];
  const int t = threadIdx.x, lane = t & 63, w = t >> 6;
  const int m0 = blockIdx.y * 64, n0 = blockIdx.x * 64;
  f32x4 acc[4];
#pragma unroll
  for (int j = 0; j < 4; ++j) acc[j] = f32x4{0.f, 0.f, 0.f, 0.f};
  const int ar = t >> 2, ak = (t & 3) * 8;
  const int bn = t & 63, bk = (t >> 6) * 8;
  const int fr = lane & 15, fk = (lane >> 4) * 8;
  const int col = n0 + bn;
  const bool colok = col < N;
  const int nst = K >> 5;
  for (int s = 0; s < nst; ++s) {
    const int k0 = s * 32;
    {
      const float* src = A + (size_t)(m0 + ar) * K + k0 + ak;
      f32x4 v0 = *reinterpret_cast<const f32x4*>(src);
      f32x4 v1 = *reinterpret_cast<const f32x4*>(src + 4);
      float tmp[8] = {v0[0], v0[1], v0[2], v0[3], v1[0], v1[1], v1[2], v1[3]};
      *reinterpret_cast<bf16x8*>(&As[ar * 40 + ak]) = cvt8(tmp);
    }
    {
      float tmp[8];
#pragma unroll
      for (int j = 0; j < 8; ++j)
        tmp[j] = colok ? B[(size_t)(k0 + bk + j) * N + col] : 0.f;
      *reinterpret_cast<bf16x8*>(&Bs[bn * 40 + bk]) = cvt8(tmp);
    }
    __syncthreads();
    bf16x8 a = *reinterpret_cast<const bf16x8*>(&As[(w * 16 + fr) * 40 + fk]);
#pragma unroll
    for (int j = 0; j < 4; ++j) {
      bf16x8 b = *reinterpret_cast<const bf16x8*>(&Bs[(j * 16 + fr) * 40 + fk]);
      acc[j] = mfma16(a, b, acc[j]);
    }
    __syncthreads();
  }
  const int rq = (lane >> 4) * 4;
#pragma unroll
  for (int j = 0; j < 4; ++j) {
    const int c = n0 + j * 16 + fr;
    if (c < N) {
#pragma unroll
      for (int r = 0; r < 4; ++r) {
        const size_t idx = (size_t)(m0 + w * 16 + rq + r) * N + c;
        float v = acc[j][r];
        if (flags & 1) v += bias[c];
        if (flags & 2) v += C[idx];
        C[idx] = v;
      }
    }
  }
}

// =====================================================================
// Fused K+V GEMM: blockIdx.z picks (Wk,bk,kout) vs (Wv,bv,vout).
// M=4096, N=512, K=512 (no guards). Same body as gemm_kernel.
// =====================================================================
__global__ __launch_bounds__(256) void kv_gemm_kernel(
    const float* __restrict__ A, const float* __restrict__ Wk,
    const float* __restrict__ bk, const float* __restrict__ Wv,
    const float* __restrict__ bv, float* __restrict__ kout,
    float* __restrict__ vout) {
  __shared__ __bf16 As[64 * 40];
  __shared__ __bf16 Bs[64 * 40];
  const float* B = blockIdx.z ? Wv : Wk;
  const float* bias = blockIdx.z ? bv : bk;
  float* C = blockIdx.z ? vout : kout;
  const int t = threadIdx.x, lane = t & 63, w = t >> 6;
  const int m0 = blockIdx.y * 64, n0 = blockIdx.x * 64;
  f32x4 acc[4];
#pragma unroll
  for (int j = 0; j < 4; ++j) acc[j] = f32x4{0.f, 0.f, 0.f, 0.f};
  const int ar = t >> 2, ak = (t & 3) * 8;
  const int bn = t & 63, bk2 = (t >> 6) * 8;
  const int fr = lane & 15, fk = (lane >> 4) * 8;
  const int col = n0 + bn;
  for (int s = 0; s < 16; ++s) {
    const int k0 = s * 32;
    {
      const float* src = A + (size_t)(m0 + ar) * 512 + k0 + ak;
      f32x4 v0 = *reinterpret_cast<const f32x4*>(src);
      f32x4 v1 = *reinterpret_cast<const f32x4*>(src + 4);
      float tmp[8] = {v0[0], v0[1], v0[2], v0[3], v1[0], v1[1], v1[2], v1[3]};
      *reinterpret_cast<bf16x8*>(&As[ar * 40 + ak]) = cvt8(tmp);
    }
    {
      float tmp[8];
#pragma unroll
      for (int j = 0; j < 8; ++j)
        tmp[j] = B[(size_t)(k0 + bk2 + j) * 512 + col];
      *reinterpret_cast<bf16x8*>(&Bs[bn * 40 + bk2]) = cvt8(tmp);
    }
    __syncthreads();
    bf16x8 a = *reinterpret_cast<const bf16x8*>(&As[(w * 16 + fr) * 40 + fk]);
#pragma unroll
    for (int j = 0; j < 4; ++j) {
      bf16x8 b2 = *reinterpret_cast<const bf16x8*>(&Bs[(j * 16 + fr) * 40 + fk]);
      acc[j] = mfma16(a, b2, acc[j]);
    }
    __syncthreads();
  }
  const int rq = (lane >> 4) * 4;
#pragma unroll
  for (int j = 0; j < 4; ++j) {
    const int c = n0 + j * 16 + fr;
#pragma unroll
    for (int r = 0; r < 4; ++r)
      C[(size_t)(m0 + w * 16 + rq + r) * 512 + c] = acc[j][r] + bias[c];
  }
}

// =====================================================================
// Fused CTC head: C[512,1296] = A1@B1 + A2@B2 + bias (K=512 each).
// =====================================================================
__global__ __launch_bounds__(256) void ctc_gemm_kernel(
    const float* __restrict__ A1, const float* __restrict__ A2,
    const float* __restrict__ B1, const float* __restrict__ B2,
    const float* __restrict__ bias, float* __restrict__ C) {
  __shared__ __bf16 As[64 * 40];
  __shared__ __bf16 Bs[64 * 40];
  const int N = 1296;
  const int t = threadIdx.x, lane = t & 63, w = t >> 6;
  const int m0 = blockIdx.y * 64, n0 = blockIdx.x * 64;
  f32x4 acc[4];
#pragma unroll
  for (int j = 0; j < 4; ++j) acc[j] = f32x4{0.f, 0.f, 0.f, 0.f};
  const int ar = t >> 2, ak = (t & 3) * 8;
  const int bn = t & 63, bk = (t >> 6) * 8;
  const int fr = lane & 15, fk = (lane >> 4) * 8;
  const int col = n0 + bn;
  const bool colok = col < N;
  for (int s = 0; s < 32; ++s) {
    const float* Ap = (s < 16) ? A1 : A2;
    const float* Bp = (s < 16) ? B1 : B2;
    const int k0 = (s & 15) * 32;
    {
      const float* src = Ap + (size_t)(m0 + ar) * 512 + k0 + ak;
      f32x4 v0 = *reinterpret_cast<const f32x4*>(src);
      f32x4 v1 = *reinterpret_cast<const f32x4*>(src + 4);
      float tmp[8] = {v0[0], v0[1], v0[2], v0[3], v1[0], v1[1], v1[2], v1[3]};
      *reinterpret_cast<bf16x8*>(&As[ar * 40 + ak]) = cvt8(tmp);
    }
    {
      float tmp[8];
#pragma unroll
      for (int j = 0; j < 8; ++j)
        tmp[j] = colok ? Bp[(size_t)(k0 + bk + j) * N + col] : 0.f;
      *reinterpret_cast<bf16x8*>(&Bs[bn * 40 + bk]) = cvt8(tmp);
    }
    __syncthreads();
    bf16x8 a = *reinterpret_cast<const bf16x8*>(&As[(w * 16 + fr) * 40 + fk]);
#pragma unroll
    for (int j = 0; j < 4; ++j) {
      bf16x8 b = *reinterpret_cast<const bf16x8*>(&Bs[(j * 16 + fr) * 40 + fk]);
      acc[j] = mfma16(a, b, acc[j]);
    }
    __syncthreads();
  }
  const int rq = (lane >> 4) * 4;
#pragma unroll
  for (int j = 0; j < 4; ++j) {
    const int c = n0 + j * 16 + fr;
    if (c < N) {
#pragma unroll
      for (int r = 0; r < 4; ++r)
        C[(size_t)(m0 + w * 16 + rq + r) * N + c] = acc[j][r] + bias[c];
    }
  }
}

// =====================================================================
// Attention stage 1: P = softmax(mask(Q_h @ K_h^T / 8)) as bf16.
// =====================================================================
__global__ __launch_bounds__(256) void attn_scores_kernel(
    const float* __restrict__ q, const float* __restrict__ k,
    const int* __restrict__ lens, __bf16* __restrict__ P) {
  __shared__ __bf16 Qs[64 * 72];
  __shared__ __bf16 Bs[512 * 40];
  const int t = threadIdx.x, lane = t & 63, w = t >> 6;
  const int bh = blockIdx.x, b = bh >> 3, h = bh & 7;
  const int L = lens[b];
  const int sdiv = (L + 511) >> 9;
  const int new_len = (L + sdiv - 1) / sdiv;
  const size_t qbase = (size_t)b * 64 * 512 + h * 64;
  const size_t kbase = (size_t)b * 512 * 512 + h * 64;
#pragma unroll
  for (int rep = 0; rep < 4; ++rep) {
    const int gidx = rep * 256 + t;
    const int row = gidx >> 4, c = (gidx & 15) * 4;
    f32x4 v = *reinterpret_cast<const f32x4*>(&q[qbase + (size_t)row * 512 + c]);
    *reinterpret_cast<bf16x4*>(&Qs[row * 72 + c]) = cvt4(v);
  }
  f32x4 acc[32];
#pragma unroll
  for (int nt = 0; nt < 32; ++nt) acc[nt] = f32x4{0.f, 0.f, 0.f, 0.f};
  const int fr = lane & 15, fkq = (lane >> 4) * 8;
  for (int ks = 0; ks < 2; ++ks) {
    const int k0 = ks * 32;
#pragma unroll
    for (int rep = 0; rep < 16; ++rep) {
      const int gidx = rep * 256 + t;
      const int row = gidx >> 3, c = (gidx & 7) * 4;
      f32x4 v =
          *reinterpret_cast<const f32x4*>(&k[kbase + (size_t)row * 512 + k0 + c]);
      *reinterpret_cast<bf16x4*>(&Bs[row * 40 + c]) = cvt4(v);
    }
    __syncthreads();
    const bf16x8 af =
        *reinterpret_cast<const bf16x8*>(&Qs[(w * 16 + fr) * 72 + k0 + fkq]);
#pragma unroll
    for (int nt = 0; nt < 32; ++nt) {
      bf16x8 bf = *reinterpret_cast<const bf16x8*>(&Bs[(nt * 16 + fr) * 40 + fkq]);
      acc[nt] = mfma16(af, bf, acc[nt]);
    }
    __syncthreads();
  }
  const float scale = 0.125f;
  const size_t pb = (size_t)bh * 64 * 512;
#pragma unroll
  for (int r = 0; r < 4; ++r) {
    float mx = -3.0e38f;
#pragma unroll
    for (int nt = 0; nt < 32; ++nt) {
      const int col = nt * 16 + fr;
      const float sv = acc[nt][r] * scale;
      if (col < new_len) mx = fmaxf(mx, sv);
    }
#pragma unroll
    for (int off = 1; off < 16; off <<= 1) mx = fmaxf(mx, __shfl_xor(mx, off, 64));
    float sum = 0.f;
#pragma unroll
    for (int nt = 0; nt < 32; ++nt) {
      const int col = nt * 16 + fr;
      const float e = (col < new_len) ? __expf(acc[nt][r] * scale - mx) : 0.f;
      acc[nt][r] = e;
      sum += e;
    }
#pragma unroll
    for (int off = 1; off < 16; off <<= 1) sum += __shfl_xor(sum, off, 64);
    const float inv = 1.f / sum;
    const int row = w * 16 + ((lane >> 4) << 2) + r;
    __bf16* dst = P + pb + (size_t)row * 512 + fr;
#pragma unroll
    for (int nt = 0; nt < 32; ++nt) dst[nt * 16] = (__bf16)(acc[nt][r] * inv);
  }
}

// =====================================================================
// Attention stage 2: ctx = P_h(64x512 bf16) @ V_h(512x64).
// =====================================================================
__global__ __launch_bounds__(256) void attn_pv_kernel(
    const __bf16* __restrict__ P, const float* __restrict__ v,
    float* __restrict__ ctx) {
  __shared__ __bf16 As[64 * 40];
  __shared__ __bf16 Bs[64 * 40];
  const int t = threadIdx.x, lane = t & 63, w = t >> 6;
  const int bh = blockIdx.x, b = bh >> 3, h = bh & 7;
  const size_t pbase = (size_t)bh * 64 * 512;
  const size_t vbase = (size_t)b * 512 * 512 + h * 64;
  f32x4 acc[4];
#pragma unroll
  for (int j = 0; j < 4; ++j) acc[j] = f32x4{0.f, 0.f, 0.f, 0.f};
  const int fr = lane & 15, fk = (lane >> 4) * 8;
  const int arow = t >> 2, ac = (t & 3) * 8;
  const int bn = t & 63, bk = (t >> 6) * 8;
  for (int s = 0; s < 16; ++s) {
    const int k0 = s * 32;
    *reinterpret_cast<bf16x8*>(&As[arow * 40 + ac]) =
        *reinterpret_cast<const bf16x8*>(&P[pbase + (size_t)arow * 512 + k0 + ac]);
    {
      float tmp[8];
#pragma unroll
      for (int j = 0; j < 8; ++j)
        tmp[j] = v[vbase + (size_t)(k0 + bk + j) * 512 + bn];
      *reinterpret_cast<bf16x8*>(&Bs[bn * 40 + bk]) = cvt8(tmp);
    }
    __syncthreads();
    const bf16x8 a = *reinterpret_cast<const bf16x8*>(&As[(w * 16 + fr) * 40 + fk]);
#pragma unroll
    for (int j = 0; j < 4; ++j) {
      bf16x8 bfrag = *reinterpret_cast<const bf16x8*>(&Bs[(j * 16 + fr) * 40 + fk]);
      acc[j] = mfma16(a, bfrag, acc[j]);
    }
    __syncthreads();
  }
  const int rq = (lane >> 4) * 4;
  const size_t cbase = (size_t)b * 64 * 512 + h * 64;
#pragma unroll
  for (int j = 0; j < 4; ++j)
#pragma unroll
    for (int r = 0; r < 4; ++r)
      ctx[cbase + (size_t)(w * 16 + rq + r) * 512 + j * 16 + fr] = acc[j][r];
}

// LayerNorm over rows of 512 (for ctx @ Wo + bo)
__global__ __launch_bounds__(256) void ln_kernel(const float* __restrict__ x,
                                                 const float* __restrict__ g,
                                                 const float* __restrict__ bt,
                                                 float* __restrict__ y) {
  __shared__ float red[8];
  const int t = threadIdx.x;
  const size_t off = (size_t)blockIdx.x * 512;
  const float a = x[off + t], b2 = x[off + t + 256];
  float s = a + b2, sq = a * a + b2 * b2;
  blockRed2(s, sq, red);
  const float m = s * (1.f / 512.f);
  const float var = sq * (1.f / 512.f) - m * m;
  const float rs = rsqrtf(var + 1e-5f);
  y[off + t] = (a - m) * rs * g[t] + bt[t];
  y[off + t + 256] = (b2 - m) * rs * g[t + 256] + bt[t + 256];
}

// =====================================================================
extern "C" void kernel_launch(void* const* d_in, const int* in_sizes, int n_in,
                              void* d_out, int out_size, void* d_ws,
                              size_t ws_size, hipStream_t stream) {
  const float* images = (const float*)d_in[0];
  const float* qgrids = (const float*)d_in[1];
  const float* keypoints = (const float*)d_in[2];
  const int* qlens = (const int*)d_in[3];
  const float* W_img = (const float*)d_in[4];
  const float* b_img = (const float*)d_in[5];
  const float* W_kp = (const float*)d_in[6];
  const float* b_kp = (const float*)d_in[7];
  const float* g_kp = (const float*)d_in[8];
  const float* bt_kp = (const float*)d_in[9];
  const float* W_qp = (const float*)d_in[10];
  const float* b_qp = (const float*)d_in[11];
  const float* g_qln = (const float*)d_in[12];
  const float* bt_qln = (const float*)d_in[13];
  const float* Wq = (const float*)d_in[14];
  const float* bq = (const float*)d_in[15];
  const float* Wk = (const float*)d_in[16];
  const float* bk = (const float*)d_in[17];
  const float* Wv = (const float*)d_in[18];
  const float* bv = (const float*)d_in[19];
  const float* Wo = (const float*)d_in[20];
  const float* bo = (const float*)d_in[21];
  const float* g_attn = (const float*)d_in[22];
  const float* bt_attn = (const float*)d_in[23];
  const float* W_ctc = (const float*)d_in[24];
  const float* b_ctc = (const float*)d_in[25];
  float* out = (float*)d_out;

  const size_t MB = 1u << 20;
  if (ws_size < 29 * MB) return;  // need 29 MB of scratch
  char* ws = (char*)d_ws;
  float* low = (float*)(ws);              // 1 MB  (512x512)
  float* qbuf = (float*)(ws + 1 * MB);    // 1 MB
  __bf16* wtq = (__bf16*)(ws + 2 * MB);   // 256 KB Wt (dead before pbuf)
  __bf16* pbuf = (__bf16*)(ws + 2 * MB);  // 512 KB (P, bf16) -- dead before ctxo
  float* ctxo = (float*)(ws + 2 * MB);    // 1 MB (reuses pbuf region, sequential)
  float* ctxln = (float*)(ws + 3 * MB);   // 1 MB
  float* pooled = (float*)(ws + 4 * MB);     // 8 MB (8x512x512)
  float* partials = (float*)(ws + 12 * MB);  // 24 MB (24x512x512)
  float* kbuf = partials;                    // reuse after reduce (8 MB)
  float* vbuf = (float*)(ws + 20 * MB);      // 8 MB
  float* ctx = (float*)(ws + 28 * MB);       // 1 MB

  // 0) Wt = transpose(W_qp) in bf16, K padded to 256
  wqp_transpose_kernel<<<512, 256, 0, stream>>>(W_qp, wtq);
  // 1) img GEMM partials (split-K=24, dbuf pipeline)
  img_gemm_kernel<<<dim3(4, 4, SPLITK), 512, 0, stream>>>(images, W_img, partials);
  // 2) kp_feat -> low
  kp_kernel<<<512, 256, 0, stream>>>(keypoints, W_kp, b_kp, g_kp, bt_kp, low);
  // 3) low += b_img + sum(partials)
  reduce_add_kernel<<<1024, 256, 0, stream>>>(partials, b_img, low);
  // 4) pooled qgrid tokens (MFMA proj + LN + ragged mean-pool)
  pool_mfma_kernel<<<256, 512, 0, stream>>>(qgrids, qlens, wtq, b_qp, g_qln,
                                            bt_qln, pooled);
  // 5) k + v from pooled, fused launch (partials region is dead now)
  kv_gemm_kernel<<<dim3(8, 64, 2), 256, 0, stream>>>(pooled, Wk, bk, Wv, bv,
                                                     kbuf, vbuf);
  // 6) q from low
  gemm_kernel<<<dim3(8, 8), 256, 0, stream>>>(low, Wq, bq, qbuf, 512, 512, 512, 1);
  // 7) fused attention: batched MFMA scores+softmax, then MFMA PV
  attn_scores_kernel<<<64, 256, 0, stream>>>(qbuf, kbuf, qlens, pbuf);
  attn_pv_kernel<<<64, 256, 0, stream>>>(pbuf, vbuf, ctx);
  // 8) ctx @ Wo + bo, then LN
  gemm_kernel<<<dim3(8, 8), 256, 0, stream>>>(ctx, Wo, bo, ctxo, 512, 512, 512, 1);
  ln_kernel<<<512, 256, 0, stream>>>(ctxo, g_attn, bt_attn, ctxln);
  // 9) out = low @ W_ctc[:512] + ctxln @ W_ctc[512:] + b_ctc (single pass)
  ctc_gemm_kernel<<<dim3(21, 8), 256, 0, stream>>>(
      low, ctxln, W_ctc, W_ctc + (size_t)512 * 1296, b_ctc, out);
}

// Round 6
// 351.830 us; speedup vs baseline: 1.8903x; 1.0944x over previous
//
#include <hip/hip_runtime.h>
#include <hip/hip_bf16.h>

typedef __bf16 bf16x8 __attribute__((ext_vector_type(8)));
typedef __bf16 bf16x4 __attribute__((ext_vector_type(4)));
typedef float f32x4 __attribute__((ext_vector_type(4)));
typedef float f32x2 __attribute__((ext_vector_type(2)));

__device__ __forceinline__ f32x4 mfma16(bf16x8 a, bf16x8 b, f32x4 c) {
  return __builtin_amdgcn_mfma_f32_16x16x32_bf16(a, b, c, 0, 0, 0);
}

__device__ __forceinline__ bf16x8 cvt8(const float* f) {
  bf16x8 r;
#pragma unroll
  for (int i = 0; i < 8; ++i) r[i] = (__bf16)f[i];
  return r;
}

__device__ __forceinline__ bf16x4 cvt4(f32x4 v) {
  bf16x4 r;
#pragma unroll
  for (int i = 0; i < 4; ++i) r[i] = (__bf16)v[i];
  return r;
}

// ---- block reduction helpers (blockDim.x == 256 assumed, 4 waves) ----
__device__ __forceinline__ void blockRed2(float& a, float& b, float* red) {
#pragma unroll
  for (int off = 1; off < 64; off <<= 1) {
    a += __shfl_xor(a, off, 64);
    b += __shfl_xor(b, off, 64);
  }
  const int w = threadIdx.x >> 6;
  if ((threadIdx.x & 63) == 0) { red[w] = a; red[4 + w] = b; }
  __syncthreads();
  a = red[0] + red[1] + red[2] + red[3];
  b = red[4] + red[5] + red[6] + red[7];
  __syncthreads();
}

// =====================================================================
// Stage A: img_feat partials = images_flat(512x37632) @ W_img(37632x512)
// split-K=24, tile 128x128, 512 threads = 8 waves (wave tile 64x32),
// double-buffered LDS, reg-staged async pipeline (1 barrier / K-step).
// =====================================================================
#define IMG_K 37632
#define SPLITK 24
#define STEPS_PER 49  // 1176 k-steps of 32 / 24

__global__ __launch_bounds__(512) void img_gemm_kernel(
    const float* __restrict__ A, const float* __restrict__ B,
    float* __restrict__ partials) {
  __shared__ __bf16 As[2][128 * 40];
  __shared__ __bf16 Bs[2][128 * 40];
  const int t = threadIdx.x;
  const int lane = t & 63;
  const int w = t >> 6;
  const int wr = (w >> 2) * 64;  // wave row base: 0 / 64
  const int wc = (w & 3) * 32;   // wave col base: 0/32/64/96
  const int m0 = blockIdx.y * 128, n0 = blockIdx.x * 128;
  const int step0 = blockIdx.z * STEPS_PER;

  f32x4 acc[4][2];
#pragma unroll
  for (int i = 0; i < 4; ++i)
#pragma unroll
    for (int j = 0; j < 2; ++j) acc[i][j] = f32x4{0.f, 0.f, 0.f, 0.f};

  const int ar = t >> 2, ak = (t & 3) * 8;
  const int bn = t & 127, bk = (t >> 7) * 8;
  const int fr = lane & 15, fk = (lane >> 4) * 8;

  float atm[8], btm[8];
#define IMG_LOAD(K0)                                                        \
  do {                                                                      \
    const float* asrc = A + (size_t)(m0 + ar) * IMG_K + (K0) + ak;          \
    f32x4 v0 = *reinterpret_cast<const f32x4*>(asrc);                       \
    f32x4 v1 = *reinterpret_cast<const f32x4*>(asrc + 4);                   \
    atm[0] = v0[0]; atm[1] = v0[1]; atm[2] = v0[2]; atm[3] = v0[3];         \
    atm[4] = v1[0]; atm[5] = v1[1]; atm[6] = v1[2]; atm[7] = v1[3];         \
    const float* bsrc = B + (size_t)((K0) + bk) * 512 + n0 + bn;            \
    _Pragma("unroll") for (int j = 0; j < 8; ++j) btm[j] =                  \
        bsrc[(size_t)j * 512];                                              \
  } while (0)
#define IMG_WRITE(BUF)                                                      \
  do {                                                                      \
    *reinterpret_cast<bf16x8*>(&As[BUF][ar * 40 + ak]) = cvt8(atm);         \
    *reinterpret_cast<bf16x8*>(&Bs[BUF][bn * 40 + bk]) = cvt8(btm);         \
  } while (0)

  IMG_LOAD(step0 * 32);
  IMG_WRITE(0);
  __syncthreads();

  for (int s = 0; s < STEPS_PER; ++s) {
    const int cur = s & 1;
    const bool more = (s + 1) < STEPS_PER;
    if (more) IMG_LOAD((step0 + s + 1) * 32);
    bf16x8 af[4], bfr[2];
#pragma unroll
    for (int i = 0; i < 4; ++i)
      af[i] =
          *reinterpret_cast<const bf16x8*>(&As[cur][(wr + i * 16 + fr) * 40 + fk]);
#pragma unroll
    for (int j = 0; j < 2; ++j)
      bfr[j] =
          *reinterpret_cast<const bf16x8*>(&Bs[cur][(wc + j * 16 + fr) * 40 + fk]);
#pragma unroll
    for (int i = 0; i < 4; ++i)
#pragma unroll
      for (int j = 0; j < 2; ++j) acc[i][j] = mfma16(af[i], bfr[j], acc[i][j]);
    if (more) IMG_WRITE(cur ^ 1);
    __syncthreads();
  }
#undef IMG_LOAD
#undef IMG_WRITE

  float* P = partials + (size_t)blockIdx.z * (512 * 512);
  const int rq = (lane >> 4) * 4;
#pragma unroll
  for (int i = 0; i < 4; ++i)
#pragma unroll
    for (int j = 0; j < 2; ++j)
#pragma unroll
      for (int r = 0; r < 4; ++r)
        P[(size_t)(m0 + wr + i * 16 + rq + r) * 512 + (n0 + wc + j * 16 + fr)] =
            acc[i][j][r];
}

// low[idx] = kp_feat(already there) + b_img + sum_z partials[z][idx];
// also writes bf16 copy into fusedbf[:, 0:512] (row stride 1024).
__global__ __launch_bounds__(256) void reduce_add_kernel(
    const float* __restrict__ partials, const float* __restrict__ b_img,
    float* __restrict__ low, __bf16* __restrict__ fusedbf) {
  const int idx = blockIdx.x * 256 + threadIdx.x;
  float acc = low[idx] + b_img[idx & 511];
#pragma unroll
  for (int z = 0; z < SPLITK; ++z) acc += partials[(size_t)z * 262144 + idx];
  low[idx] = acc;
  fusedbf[(size_t)(idx >> 9) * 1024 + (idx & 511)] = (__bf16)acc;
}

// =====================================================================
// kp_feat = LN(relu(keypoints @ W_kp + b_kp)); one block per row (512)
// =====================================================================
__global__ __launch_bounds__(256) void kp_kernel(
    const float* __restrict__ kp, const float* __restrict__ W,
    const float* __restrict__ bias, const float* __restrict__ g,
    const float* __restrict__ bt, float* __restrict__ low) {
  __shared__ float rowv[242];
  __shared__ float red[8];
  const int t = threadIdx.x;
  const size_t roff = (size_t)blockIdx.x * 242;
  if (t < 242) rowv[t] = kp[roff + t];
  __syncthreads();
  const int d0 = t, d1 = t + 256;
  float p0 = bias[d0], p1 = bias[d1];
  for (int kk = 0; kk < 242; ++kk) {
    const float x = rowv[kk];
    p0 = fmaf(x, W[kk * 512 + d0], p0);
    p1 = fmaf(x, W[kk * 512 + d1], p1);
  }
  p0 = fmaxf(p0, 0.f);
  p1 = fmaxf(p1, 0.f);
  float s = p0 + p1, sq = p0 * p0 + p1 * p1;
  blockRed2(s, sq, red);
  const float m = s * (1.f / 512.f);
  const float var = sq * (1.f / 512.f) - m * m;
  const float rs = rsqrtf(var + 1e-5f);
  const size_t off = (size_t)blockIdx.x * 512;
  low[off + d0] = (p0 - m) * rs * g[d0] + bt[d0];
  low[off + d1] = (p1 - m) * rs * g[d1] + bt[d1];
}

// =====================================================================
// W_qp transpose+convert: Wt[col][k] bf16, k padded 242 -> 256 (zeros).
// =====================================================================
__global__ __launch_bounds__(256) void wqp_transpose_kernel(
    const float* __restrict__ W, __bf16* __restrict__ Wt) {
  const int c = blockIdx.x;   // 512 output columns
  const int t = threadIdx.x;  // 256 k slots
  Wt[(size_t)c * 256 + t] = (t < 242) ? (__bf16)W[(size_t)t * 512 + c] : (__bf16)0.f;
}

// =====================================================================
// W_ctc transpose+convert: Wt[c][k] bf16 for c<1296, k<1024.
// =====================================================================
__global__ __launch_bounds__(256) void wctc_transpose_kernel(
    const float* __restrict__ W, __bf16* __restrict__ Wt) {
  const int c = blockIdx.x;  // 1296 columns
  const int t = threadIdx.x;
#pragma unroll
  for (int r = 0; r < 4; ++r) {
    const int k = r * 256 + t;
    Wt[(size_t)c * 1024 + k] = (__bf16)W[(size_t)k * 1296 + c];
  }
}

// =====================================================================
// Fused MFMA pooling: pooled = pool_mean(LN(qgrids @ W_qp + b_qp)).
// =====================================================================
__global__ __launch_bounds__(512) void pool_mfma_kernel(
    const float* __restrict__ qgrids, const int* __restrict__ lens,
    const __bf16* __restrict__ Wt, const float* __restrict__ bias,
    const float* __restrict__ g, const float* __restrict__ bt,
    float* __restrict__ pooled) {
  __shared__ float red[8][16][2];
  const int t = threadIdx.x, lane = t & 63, w = t >> 6;
  const int b = blockIdx.x >> 5;          // 8 batches
  const int j0 = (blockIdx.x & 31) * 16;  // pooled-row block
  const int L = lens[b];
  int S = (L + 511) >> 9;
  if (S < 1) S = 1;
  const int new_len = (L + S - 1) / S;
  const float* qg_b = qgrids + (size_t)b * 4096 * 242;
  float* pooled_b = pooled + (size_t)b * 512 * 512;

  const int fr = lane & 15;
  const int fq = lane >> 4;
  const int fkq = fq * 8;
  const int colbase = w * 64;

  float biasv[4], gv[4], btv[4];
#pragma unroll
  for (int nt = 0; nt < 4; ++nt) {
    const int col = colbase + nt * 16 + fr;
    biasv[nt] = bias[col];
    gv[nt] = g[col];
    btv[nt] = bt[col];
  }

  f32x4 pool[4];
#pragma unroll
  for (int nt = 0; nt < 4; ++nt) pool[nt] = f32x4{0.f, 0.f, 0.f, 0.f};

  for (int i = 0; i < S; ++i) {
    const int arow = (j0 + fr) * S + i;
    const float* asrc = qg_b + (size_t)arow * 242;
    f32x4 acc[4];
#pragma unroll
    for (int nt = 0; nt < 4; ++nt) acc[nt] = f32x4{0.f, 0.f, 0.f, 0.f};
#pragma unroll
    for (int ks = 0; ks < 8; ++ks) {
      bf16x8 af;
      if (ks < 7) {
        float tmp[8];
#pragma unroll
        for (int p2 = 0; p2 < 4; ++p2) {
          f32x2 v = *reinterpret_cast<const f32x2*>(asrc + ks * 32 + fkq + p2 * 2);
          tmp[p2 * 2] = v[0];
          tmp[p2 * 2 + 1] = v[1];
        }
        af = cvt8(tmp);
      } else {
        float tmp[8];
#pragma unroll
        for (int jj = 0; jj < 8; ++jj) {
          const int kk = 224 + fkq + jj;
          tmp[jj] = (kk < 242) ? asrc[kk] : 0.f;
        }
        af = cvt8(tmp);
      }
      const __bf16* wt = Wt + ks * 32 + fkq;
#pragma unroll
      for (int nt = 0; nt < 4; ++nt) {
        bf16x8 bfv = *reinterpret_cast<const bf16x8*>(
            wt + (size_t)(colbase + nt * 16 + fr) * 256);
        acc[nt] = mfma16(af, bfv, acc[nt]);
      }
    }
    float s[4] = {0.f, 0.f, 0.f, 0.f}, sq[4] = {0.f, 0.f, 0.f, 0.f};
#pragma unroll
    for (int nt = 0; nt < 4; ++nt) {
#pragma unroll
      for (int r = 0; r < 4; ++r) {
        const float v = acc[nt][r] + biasv[nt];
        acc[nt][r] = v;
        s[r] += v;
        sq[r] += v * v;
      }
    }
#pragma unroll
    for (int off = 1; off < 16; off <<= 1) {
#pragma unroll
      for (int r = 0; r < 4; ++r) {
        s[r] += __shfl_xor(s[r], off, 64);
        sq[r] += __shfl_xor(sq[r], off, 64);
      }
    }
    if (fr == 0) {
#pragma unroll
      for (int r = 0; r < 4; ++r) {
        red[w][fq * 4 + r][0] = s[r];
        red[w][fq * 4 + r][1] = sq[r];
      }
    }
    __syncthreads();
    float mean[4], rsig[4];
#pragma unroll
    for (int r = 0; r < 4; ++r) {
      const int p = fq * 4 + r;
      float ss = 0.f, qq = 0.f;
#pragma unroll
      for (int ww = 0; ww < 8; ++ww) {
        ss += red[ww][p][0];
        qq += red[ww][p][1];
      }
      const float m = ss * (1.f / 512.f);
      mean[r] = m;
      rsig[r] = rsqrtf(qq * (1.f / 512.f) - m * m + 1e-5f);
    }
    __syncthreads();
#pragma unroll
    for (int r = 0; r < 4; ++r) {
      const int srow = (j0 + fq * 4 + r) * S + i;
      const bool ok = srow < L;
#pragma unroll
      for (int nt = 0; nt < 4; ++nt) {
        const float nv = (acc[nt][r] - mean[r]) * rsig[r] * gv[nt] + btv[nt];
        pool[nt][r] += ok ? nv : 0.f;
      }
    }
  }
  const float inv = 1.f / (float)S;
#pragma unroll
  for (int r = 0; r < 4; ++r) {
    const int j = j0 + fq * 4 + r;
    const bool ok = j < new_len;
#pragma unroll
    for (int nt = 0; nt < 4; ++nt)
      pooled_b[(size_t)j * 512 + colbase + nt * 16 + fr] =
          ok ? pool[nt][r] * inv : 0.f;
  }
}

// =====================================================================
// Generic bf16-MFMA GEMM: C[M,N] = A[M,K]@B[K,N] (+bias if flags&1,
// += existing C if flags&2). M%64==0, K%32==0; N arbitrary (guarded).
// =====================================================================
__global__ __launch_bounds__(256) void gemm_kernel(
    const float* __restrict__ A, const float* __restrict__ B,
    const float* __restrict__ bias, float* __restrict__ C, int M, int N,
    int K, int flags) {
  __shared__ __bf16 As[64 * 40];
  __shared__ __bf16 Bs[64 * 40];
  const int t = threadIdx.x, lane = t & 63, w = t >> 6;
  const int m0 = blockIdx.y * 64, n0 = blockIdx.x * 64;
  f32x4 acc[4];
#pragma unroll
  for (int j = 0; j < 4; ++j) acc[j] = f32x4{0.f, 0.f, 0.f, 0.f};
  const int ar = t >> 2, ak = (t & 3) * 8;
  const int bn = t & 63, bk = (t >> 6) * 8;
  const int fr = lane & 15, fk = (lane >> 4) * 8;
  const int col = n0 + bn;
  const bool colok = col < N;
  const int nst = K >> 5;
  for (int s = 0; s < nst; ++s) {
    const int k0 = s * 32;
    {
      const float* src = A + (size_t)(m0 + ar) * K + k0 + ak;
      f32x4 v0 = *reinterpret_cast<const f32x4*>(src);
      f32x4 v1 = *reinterpret_cast<const f32x4*>(src + 4);
      float tmp[8] = {v0[0], v0[1], v0[2], v0[3], v1[0], v1[1], v1[2], v1[3]};
      *reinterpret_cast<bf16x8*>(&As[ar * 40 + ak]) = cvt8(tmp);
    }
    {
      float tmp[8];
#pragma unroll
      for (int j = 0; j < 8; ++j)
        tmp[j] = colok ? B[(size_t)(k0 + bk + j) * N + col] : 0.f;
      *reinterpret_cast<bf16x8*>(&Bs[bn * 40 + bk]) = cvt8(tmp);
    }
    __syncthreads();
    bf16x8 a = *reinterpret_cast<const bf16x8*>(&As[(w * 16 + fr) * 40 + fk]);
#pragma unroll
    for (int j = 0; j < 4; ++j) {
      bf16x8 b = *reinterpret_cast<const bf16x8*>(&Bs[(j * 16 + fr) * 40 + fk]);
      acc[j] = mfma16(a, b, acc[j]);
    }
    __syncthreads();
  }
  const int rq = (lane >> 4) * 4;
#pragma unroll
  for (int j = 0; j < 4; ++j) {
    const int c = n0 + j * 16 + fr;
    if (c < N) {
#pragma unroll
      for (int r = 0; r < 4; ++r) {
        const size_t idx = (size_t)(m0 + w * 16 + rq + r) * N + c;
        float v = acc[j][r];
        if (flags & 1) v += bias[c];
        if (flags & 2) v += C[idx];
        C[idx] = v;
      }
    }
  }
}

// =====================================================================
// Fused K+V GEMM: blockIdx.z picks (Wk,bk,kout) vs (Wv,bv,vout).
// =====================================================================
__global__ __launch_bounds__(256) void kv_gemm_kernel(
    const float* __restrict__ A, const float* __restrict__ Wk,
    const float* __restrict__ bk, const float* __restrict__ Wv,
    const float* __restrict__ bv, float* __restrict__ kout,
    float* __restrict__ vout) {
  __shared__ __bf16 As[64 * 40];
  __shared__ __bf16 Bs[64 * 40];
  const float* B = blockIdx.z ? Wv : Wk;
  const float* bias = blockIdx.z ? bv : bk;
  float* C = blockIdx.z ? vout : kout;
  const int t = threadIdx.x, lane = t & 63, w = t >> 6;
  const int m0 = blockIdx.y * 64, n0 = blockIdx.x * 64;
  f32x4 acc[4];
#pragma unroll
  for (int j = 0; j < 4; ++j) acc[j] = f32x4{0.f, 0.f, 0.f, 0.f};
  const int ar = t >> 2, ak = (t & 3) * 8;
  const int bn = t & 63, bk2 = (t >> 6) * 8;
  const int fr = lane & 15, fk = (lane >> 4) * 8;
  const int col = n0 + bn;
  for (int s = 0; s < 16; ++s) {
    const int k0 = s * 32;
    {
      const float* src = A + (size_t)(m0 + ar) * 512 + k0 + ak;
      f32x4 v0 = *reinterpret_cast<const f32x4*>(src);
      f32x4 v1 = *reinterpret_cast<const f32x4*>(src + 4);
      float tmp[8] = {v0[0], v0[1], v0[2], v0[3], v1[0], v1[1], v1[2], v1[3]};
      *reinterpret_cast<bf16x8*>(&As[ar * 40 + ak]) = cvt8(tmp);
    }
    {
      float tmp[8];
#pragma unroll
      for (int j = 0; j < 8; ++j)
        tmp[j] = B[(size_t)(k0 + bk2 + j) * 512 + col];
      *reinterpret_cast<bf16x8*>(&Bs[bn * 40 + bk2]) = cvt8(tmp);
    }
    __syncthreads();
    bf16x8 a = *reinterpret_cast<const bf16x8*>(&As[(w * 16 + fr) * 40 + fk]);
#pragma unroll
    for (int j = 0; j < 4; ++j) {
      bf16x8 b2 = *reinterpret_cast<const bf16x8*>(&Bs[(j * 16 + fr) * 40 + fk]);
      acc[j] = mfma16(a, b2, acc[j]);
    }
    __syncthreads();
  }
  const int rq = (lane >> 4) * 4;
#pragma unroll
  for (int j = 0; j < 4; ++j) {
    const int c = n0 + j * 16 + fr;
#pragma unroll
    for (int r = 0; r < 4; ++r)
      C[(size_t)(m0 + w * 16 + rq + r) * 512 + c] = acc[j][r] + bias[c];
  }
}

// =====================================================================
// CTC head, no-LDS register GEMM: out[512,1296] = fusedbf @ Wt^T + bias.
// fusedbf: [512][1024] bf16 (cols 0-511 = low, 512-1023 = ctxln).
// Wt: [1296][1024] bf16. One 16x16 tile per wave, fragments loaded
// directly from global (L2-resident), 32 unrolled k-steps, no barriers.
// =====================================================================
__global__ __launch_bounds__(256) void ctc_gemm_kernel(
    const __bf16* __restrict__ A, const __bf16* __restrict__ Wt,
    const float* __restrict__ bias, float* __restrict__ out) {
  const int t = threadIdx.x, lane = t & 63, w = t >> 6;
  const int n0 = blockIdx.x * 16;
  const int m0 = blockIdx.y * 64 + w * 16;
  const int fr = lane & 15, fq = lane >> 4;
  const __bf16* arow = A + (size_t)(m0 + fr) * 1024 + fq * 8;
  const __bf16* brow = Wt + (size_t)(n0 + fr) * 1024 + fq * 8;
  f32x4 acc = f32x4{0.f, 0.f, 0.f, 0.f};
#pragma unroll
  for (int ks = 0; ks < 32; ++ks) {
    bf16x8 a = *reinterpret_cast<const bf16x8*>(arow + ks * 32);
    bf16x8 b = *reinterpret_cast<const bf16x8*>(brow + ks * 32);
    acc = mfma16(a, b, acc);
  }
  const int col = n0 + fr;
  const float bv = bias[col];
  const int r0 = m0 + fq * 4;
#pragma unroll
  for (int r = 0; r < 4; ++r)
    out[(size_t)(r0 + r) * 1296 + col] = acc[r] + bv;
}

// =====================================================================
// Attention stage 1: P = softmax(mask(Q_h @ K_h^T / 8)) as bf16.
// =====================================================================
__global__ __launch_bounds__(256) void attn_scores_kernel(
    const float* __restrict__ q, const float* __restrict__ k,
    const int* __restrict__ lens, __bf16* __restrict__ P) {
  __shared__ __bf16 Qs[64 * 72];
  __shared__ __bf16 Bs[512 * 40];
  const int t = threadIdx.x, lane = t & 63, w = t >> 6;
  const int bh = blockIdx.x, b = bh >> 3, h = bh & 7;
  const int L = lens[b];
  const int sdiv = (L + 511) >> 9;
  const int new_len = (L + sdiv - 1) / sdiv;
  const size_t qbase = (size_t)b * 64 * 512 + h * 64;
  const size_t kbase = (size_t)b * 512 * 512 + h * 64;
#pragma unroll
  for (int rep = 0; rep < 4; ++rep) {
    const int gidx = rep * 256 + t;
    const int row = gidx >> 4, c = (gidx & 15) * 4;
    f32x4 v = *reinterpret_cast<const f32x4*>(&q[qbase + (size_t)row * 512 + c]);
    *reinterpret_cast<bf16x4*>(&Qs[row * 72 + c]) = cvt4(v);
  }
  f32x4 acc[32];
#pragma unroll
  for (int nt = 0; nt < 32; ++nt) acc[nt] = f32x4{0.f, 0.f, 0.f, 0.f};
  const int fr = lane & 15, fkq = (lane >> 4) * 8;
  for (int ks = 0; ks < 2; ++ks) {
    const int k0 = ks * 32;
#pragma unroll
    for (int rep = 0; rep < 16; ++rep) {
      const int gidx = rep * 256 + t;
      const int row = gidx >> 3, c = (gidx & 7) * 4;
      f32x4 v =
          *reinterpret_cast<const f32x4*>(&k[kbase + (size_t)row * 512 + k0 + c]);
      *reinterpret_cast<bf16x4*>(&Bs[row * 40 + c]) = cvt4(v);
    }
    __syncthreads();
    const bf16x8 af =
        *reinterpret_cast<const bf16x8*>(&Qs[(w * 16 + fr) * 72 + k0 + fkq]);
#pragma unroll
    for (int nt = 0; nt < 32; ++nt) {
      bf16x8 bf = *reinterpret_cast<const bf16x8*>(&Bs[(nt * 16 + fr) * 40 + fkq]);
      acc[nt] = mfma16(af, bf, acc[nt]);
    }
    __syncthreads();
  }
  const float scale = 0.125f;
  const size_t pb = (size_t)bh * 64 * 512;
#pragma unroll
  for (int r = 0; r < 4; ++r) {
    float mx = -3.0e38f;
#pragma unroll
    for (int nt = 0; nt < 32; ++nt) {
      const int col = nt * 16 + fr;
      const float sv = acc[nt][r] * scale;
      if (col < new_len) mx = fmaxf(mx, sv);
    }
#pragma unroll
    for (int off = 1; off < 16; off <<= 1) mx = fmaxf(mx, __shfl_xor(mx, off, 64));
    float sum = 0.f;
#pragma unroll
    for (int nt = 0; nt < 32; ++nt) {
      const int col = nt * 16 + fr;
      const float e = (col < new_len) ? __expf(acc[nt][r] * scale - mx) : 0.f;
      acc[nt][r] = e;
      sum += e;
    }
#pragma unroll
    for (int off = 1; off < 16; off <<= 1) sum += __shfl_xor(sum, off, 64);
    const float inv = 1.f / sum;
    const int row = w * 16 + ((lane >> 4) << 2) + r;
    __bf16* dst = P + pb + (size_t)row * 512 + fr;
#pragma unroll
    for (int nt = 0; nt < 32; ++nt) dst[nt * 16] = (__bf16)(acc[nt][r] * inv);
  }
}

// =====================================================================
// Attention stage 2: ctx = P_h(64x512 bf16) @ V_h(512x64).
// =====================================================================
__global__ __launch_bounds__(256) void attn_pv_kernel(
    const __bf16* __restrict__ P, const float* __restrict__ v,
    float* __restrict__ ctx) {
  __shared__ __bf16 As[64 * 40];
  __shared__ __bf16 Bs[64 * 40];
  const int t = threadIdx.x, lane = t & 63, w = t >> 6;
  const int bh = blockIdx.x, b = bh >> 3, h = bh & 7;
  const size_t pbase = (size_t)bh * 64 * 512;
  const size_t vbase = (size_t)b * 512 * 512 + h * 64;
  f32x4 acc[4];
#pragma unroll
  for (int j = 0; j < 4; ++j) acc[j] = f32x4{0.f, 0.f, 0.f, 0.f};
  const int fr = lane & 15, fk = (lane >> 4) * 8;
  const int arow = t >> 2, ac = (t & 3) * 8;
  const int bn = t & 63, bk = (t >> 6) * 8;
  for (int s = 0; s < 16; ++s) {
    const int k0 = s * 32;
    *reinterpret_cast<bf16x8*>(&As[arow * 40 + ac]) =
        *reinterpret_cast<const bf16x8*>(&P[pbase + (size_t)arow * 512 + k0 + ac]);
    {
      float tmp[8];
#pragma unroll
      for (int j = 0; j < 8; ++j)
        tmp[j] = v[vbase + (size_t)(k0 + bk + j) * 512 + bn];
      *reinterpret_cast<bf16x8*>(&Bs[bn * 40 + bk]) = cvt8(tmp);
    }
    __syncthreads();
    const bf16x8 a = *reinterpret_cast<const bf16x8*>(&As[(w * 16 + fr) * 40 + fk]);
#pragma unroll
    for (int j = 0; j < 4; ++j) {
      bf16x8 bfrag = *reinterpret_cast<const bf16x8*>(&Bs[(j * 16 + fr) * 40 + fk]);
      acc[j] = mfma16(a, bfrag, acc[j]);
    }
    __syncthreads();
  }
  const int rq = (lane >> 4) * 4;
  const size_t cbase = (size_t)b * 64 * 512 + h * 64;
#pragma unroll
  for (int j = 0; j < 4; ++j)
#pragma unroll
    for (int r = 0; r < 4; ++r)
      ctx[cbase + (size_t)(w * 16 + rq + r) * 512 + j * 16 + fr] = acc[j][r];
}

// LayerNorm over rows of 512, bf16 output into fusedbf[:, 512:1024]
// (pass ybf = fusedbf + 512, row stride 1024).
__global__ __launch_bounds__(256) void ln_bf16_kernel(
    const float* __restrict__ x, const float* __restrict__ g,
    const float* __restrict__ bt, __bf16* __restrict__ ybf) {
  __shared__ float red[8];
  const int t = threadIdx.x;
  const size_t off = (size_t)blockIdx.x * 512;
  const float a = x[off + t], b2 = x[off + t + 256];
  float s = a + b2, sq = a * a + b2 * b2;
  blockRed2(s, sq, red);
  const float m = s * (1.f / 512.f);
  const float var = sq * (1.f / 512.f) - m * m;
  const float rs = rsqrtf(var + 1e-5f);
  __bf16* yrow = ybf + (size_t)blockIdx.x * 1024;
  yrow[t] = (__bf16)((a - m) * rs * g[t] + bt[t]);
  yrow[t + 256] = (__bf16)((b2 - m) * rs * g[t + 256] + bt[t + 256]);
}

// =====================================================================
// Workspace layout (live ranges; pbuf is 4 MB — bh(64) x 64 x 512 bf16):
//   ws+ 0.. 1 MB  low      (steps 2-6)
//   ws+ 1.. 2 MB  qbuf     (steps 6-7)
//   ws+ 2.. 3 MB  wtq (0-4) then ctxo (8)
//   ws+ 3.. 4 MB  fusedbf  (3-9)   <- must NOT alias pbuf!
//   ws+ 4..12 MB  pooled (4-5) then pbuf 4MB (7a-7b)
//   ws+12..36 MB  partials (1-3) then kbuf(12-20)/vbuf(20-28, 5-7),
//                 ctx(28-29, 7-8), wtc(29-31.6, 3b-9)
// =====================================================================
extern "C" void kernel_launch(void* const* d_in, const int* in_sizes, int n_in,
                              void* d_out, int out_size, void* d_ws,
                              size_t ws_size, hipStream_t stream) {
  const float* images = (const float*)d_in[0];
  const float* qgrids = (const float*)d_in[1];
  const float* keypoints = (const float*)d_in[2];
  const int* qlens = (const int*)d_in[3];
  const float* W_img = (const float*)d_in[4];
  const float* b_img = (const float*)d_in[5];
  const float* W_kp = (const float*)d_in[6];
  const float* b_kp = (const float*)d_in[7];
  const float* g_kp = (const float*)d_in[8];
  const float* bt_kp = (const float*)d_in[9];
  const float* W_qp = (const float*)d_in[10];
  const float* b_qp = (const float*)d_in[11];
  const float* g_qln = (const float*)d_in[12];
  const float* bt_qln = (const float*)d_in[13];
  const float* Wq = (const float*)d_in[14];
  const float* bq = (const float*)d_in[15];
  const float* Wk = (const float*)d_in[16];
  const float* bk = (const float*)d_in[17];
  const float* Wv = (const float*)d_in[18];
  const float* bv = (const float*)d_in[19];
  const float* Wo = (const float*)d_in[20];
  const float* bo = (const float*)d_in[21];
  const float* g_attn = (const float*)d_in[22];
  const float* bt_attn = (const float*)d_in[23];
  const float* W_ctc = (const float*)d_in[24];
  const float* b_ctc = (const float*)d_in[25];
  float* out = (float*)d_out;

  const size_t MB = 1u << 20;
  if (ws_size < 29 * MB) return;
  char* ws = (char*)d_ws;
  float* low = (float*)(ws);                 // 1 MB
  float* qbuf = (float*)(ws + 1 * MB);       // 1 MB
  __bf16* wtq = (__bf16*)(ws + 2 * MB);      // 256 KB (dead after step 4)
  float* ctxo = (float*)(ws + 2 * MB);       // 1 MB   (written step 8)
  __bf16* fusedbf = (__bf16*)(ws + 3 * MB);  // 1 MB (512x1024 bf16)
  float* pooled = (float*)(ws + 4 * MB);     // 8 MB (dead after step 5)
  __bf16* pbuf = (__bf16*)(ws + 4 * MB);     // 4 MB (P; steps 7a-7b only)
  float* partials = (float*)(ws + 12 * MB);  // 24 MB (dead after step 3)
  float* kbuf = partials;                    // 8 MB  (ws+12..20)
  float* vbuf = (float*)(ws + 20 * MB);      // 8 MB  (ws+20..28)
  float* ctx = (float*)(ws + 28 * MB);       // 1 MB
  __bf16* wtc = (__bf16*)(ws + 29 * MB);     // 2.6 MB Wt_ctc

  // 0) Wt_qp = transpose(W_qp) bf16, K padded to 256
  wqp_transpose_kernel<<<512, 256, 0, stream>>>(W_qp, wtq);
  // 1) img GEMM partials (split-K=24, dbuf pipeline)
  img_gemm_kernel<<<dim3(4, 4, SPLITK), 512, 0, stream>>>(images, W_img, partials);
  // 2) kp_feat -> low
  kp_kernel<<<512, 256, 0, stream>>>(keypoints, W_kp, b_kp, g_kp, bt_kp, low);
  // 3) low += b_img + sum(partials); also fusedbf[:, :512] = bf16(low)
  reduce_add_kernel<<<1024, 256, 0, stream>>>(partials, b_img, low, fusedbf);
  // 3b) Wt_ctc = transpose(W_ctc) bf16 (partials region is dead now)
  wctc_transpose_kernel<<<1296, 256, 0, stream>>>(W_ctc, wtc);
  // 4) pooled qgrid tokens (MFMA proj + LN + ragged mean-pool)
  pool_mfma_kernel<<<256, 512, 0, stream>>>(qgrids, qlens, wtq, b_qp, g_qln,
                                            bt_qln, pooled);
  // 5) k + v from pooled, fused launch
  kv_gemm_kernel<<<dim3(8, 64, 2), 256, 0, stream>>>(pooled, Wk, bk, Wv, bv,
                                                     kbuf, vbuf);
  // 6) q from low
  gemm_kernel<<<dim3(8, 8), 256, 0, stream>>>(low, Wq, bq, qbuf, 512, 512, 512, 1);
  // 7) fused attention: batched MFMA scores+softmax, then MFMA PV
  attn_scores_kernel<<<64, 256, 0, stream>>>(qbuf, kbuf, qlens, pbuf);
  attn_pv_kernel<<<64, 256, 0, stream>>>(pbuf, vbuf, ctx);
  // 8) ctx @ Wo + bo, then LN -> fusedbf[:, 512:] (bf16)
  gemm_kernel<<<dim3(8, 8), 256, 0, stream>>>(ctx, Wo, bo, ctxo, 512, 512, 512, 1);
  ln_bf16_kernel<<<512, 256, 0, stream>>>(ctxo, g_attn, bt_attn, fusedbf + 512);
  // 9) out = fusedbf @ Wt_ctc^T + b_ctc (register GEMM, no LDS/barriers)
  ctc_gemm_kernel<<<dim3(81, 8), 256, 0, stream>>>(fusedbf, wtc, b_ctc, out);
}

// Round 7
// 343.738 us; speedup vs baseline: 1.9348x; 1.0235x over previous
//
#include <hip/hip_runtime.h>
#include <hip/hip_bf16.h>

typedef __bf16 bf16x8 __attribute__((ext_vector_type(8)));
typedef __bf16 bf16x4 __attribute__((ext_vector_type(4)));
typedef float f32x4 __attribute__((ext_vector_type(4)));
typedef float f32x2 __attribute__((ext_vector_type(2)));

__device__ __forceinline__ f32x4 mfma16(bf16x8 a, bf16x8 b, f32x4 c) {
  return __builtin_amdgcn_mfma_f32_16x16x32_bf16(a, b, c, 0, 0, 0);
}

__device__ __forceinline__ bf16x8 cvt8(const float* f) {
  bf16x8 r;
#pragma unroll
  for (int i = 0; i < 8; ++i) r[i] = (__bf16)f[i];
  return r;
}

__device__ __forceinline__ bf16x4 cvt4(f32x4 v) {
  bf16x4 r;
#pragma unroll
  for (int i = 0; i < 4; ++i) r[i] = (__bf16)v[i];
  return r;
}

// ---- block reduction helpers (blockDim.x == 256 assumed, 4 waves) ----
__device__ __forceinline__ void blockRed2(float& a, float& b, float* red) {
#pragma unroll
  for (int off = 1; off < 64; off <<= 1) {
    a += __shfl_xor(a, off, 64);
    b += __shfl_xor(b, off, 64);
  }
  const int w = threadIdx.x >> 6;
  if ((threadIdx.x & 63) == 0) { red[w] = a; red[4 + w] = b; }
  __syncthreads();
  a = red[0] + red[1] + red[2] + red[3];
  b = red[4] + red[5] + red[6] + red[7];
  __syncthreads();
}

// =====================================================================
// Stage A: img_feat partials = images_flat(512x37632) @ W_img(37632x512)
// split-K=49 (784 blocks = ~3/CU, 24 waves/CU), tile 128x128, 8 waves
// (wave tile 64x32), double-buffered LDS, 1 barrier / K-step.
// Partials stored bf16 (std~0.2, rounding ~8e-4/slice -> negligible).
// =====================================================================
#define IMG_K 37632
#define SPLITK 49
#define STEPS_PER 24  // 1176 k-steps of 32 / 49

__global__ __launch_bounds__(512) void img_gemm_kernel(
    const float* __restrict__ A, const float* __restrict__ B,
    __bf16* __restrict__ partials) {
  __shared__ __bf16 As[2][128 * 40];
  __shared__ __bf16 Bs[2][128 * 40];
  const int t = threadIdx.x;
  const int lane = t & 63;
  const int w = t >> 6;
  const int wr = (w >> 2) * 64;  // wave row base: 0 / 64
  const int wc = (w & 3) * 32;   // wave col base: 0/32/64/96
  const int m0 = blockIdx.y * 128, n0 = blockIdx.x * 128;
  const int step0 = blockIdx.z * STEPS_PER;

  f32x4 acc[4][2];
#pragma unroll
  for (int i = 0; i < 4; ++i)
#pragma unroll
    for (int j = 0; j < 2; ++j) acc[i][j] = f32x4{0.f, 0.f, 0.f, 0.f};

  const int ar = t >> 2, ak = (t & 3) * 8;
  const int bn = t & 127, bk = (t >> 7) * 8;
  const int fr = lane & 15, fk = (lane >> 4) * 8;

  float atm[8], btm[8];
#define IMG_LOAD(K0)                                                        \
  do {                                                                      \
    const float* asrc = A + (size_t)(m0 + ar) * IMG_K + (K0) + ak;          \
    f32x4 v0 = *reinterpret_cast<const f32x4*>(asrc);                       \
    f32x4 v1 = *reinterpret_cast<const f32x4*>(asrc + 4);                   \
    atm[0] = v0[0]; atm[1] = v0[1]; atm[2] = v0[2]; atm[3] = v0[3];         \
    atm[4] = v1[0]; atm[5] = v1[1]; atm[6] = v1[2]; atm[7] = v1[3];         \
    const float* bsrc = B + (size_t)((K0) + bk) * 512 + n0 + bn;            \
    _Pragma("unroll") for (int j = 0; j < 8; ++j) btm[j] =                  \
        bsrc[(size_t)j * 512];                                              \
  } while (0)
#define IMG_WRITE(BUF)                                                      \
  do {                                                                      \
    *reinterpret_cast<bf16x8*>(&As[BUF][ar * 40 + ak]) = cvt8(atm);         \
    *reinterpret_cast<bf16x8*>(&Bs[BUF][bn * 40 + bk]) = cvt8(btm);         \
  } while (0)

  IMG_LOAD(step0 * 32);
  IMG_WRITE(0);
  __syncthreads();

  for (int s = 0; s < STEPS_PER; ++s) {
    const int cur = s & 1;
    const bool more = (s + 1) < STEPS_PER;
    if (more) IMG_LOAD((step0 + s + 1) * 32);
    bf16x8 af[4], bfr[2];
#pragma unroll
    for (int i = 0; i < 4; ++i)
      af[i] =
          *reinterpret_cast<const bf16x8*>(&As[cur][(wr + i * 16 + fr) * 40 + fk]);
#pragma unroll
    for (int j = 0; j < 2; ++j)
      bfr[j] =
          *reinterpret_cast<const bf16x8*>(&Bs[cur][(wc + j * 16 + fr) * 40 + fk]);
#pragma unroll
    for (int i = 0; i < 4; ++i)
#pragma unroll
      for (int j = 0; j < 2; ++j) acc[i][j] = mfma16(af[i], bfr[j], acc[i][j]);
    if (more) IMG_WRITE(cur ^ 1);
    __syncthreads();
  }
#undef IMG_LOAD
#undef IMG_WRITE

  __bf16* P = partials + (size_t)blockIdx.z * (512 * 512);
  const int rq = (lane >> 4) * 4;
#pragma unroll
  for (int i = 0; i < 4; ++i)
#pragma unroll
    for (int j = 0; j < 2; ++j)
#pragma unroll
      for (int r = 0; r < 4; ++r)
        P[(size_t)(m0 + wr + i * 16 + rq + r) * 512 + (n0 + wc + j * 16 + fr)] =
            (__bf16)acc[i][j][r];
}

// low[idx] = kp_feat(already there) + b_img + sum_z partials[z][idx];
// also writes bf16 copy into fusedbf[:, 0:512] (row stride 1024).
__global__ __launch_bounds__(256) void reduce_add_kernel(
    const __bf16* __restrict__ partials, const float* __restrict__ b_img,
    float* __restrict__ low, __bf16* __restrict__ fusedbf) {
  const int idx = blockIdx.x * 256 + threadIdx.x;
  float acc = low[idx] + b_img[idx & 511];
#pragma unroll
  for (int z = 0; z < SPLITK; ++z)
    acc += (float)partials[(size_t)z * 262144 + idx];
  low[idx] = acc;
  fusedbf[(size_t)(idx >> 9) * 1024 + (idx & 511)] = (__bf16)acc;
}

// =====================================================================
// kp_feat = LN(relu(keypoints @ W_kp + b_kp)); one block per row (512)
// =====================================================================
__global__ __launch_bounds__(256) void kp_kernel(
    const float* __restrict__ kp, const float* __restrict__ W,
    const float* __restrict__ bias, const float* __restrict__ g,
    const float* __restrict__ bt, float* __restrict__ low) {
  __shared__ float rowv[242];
  __shared__ float red[8];
  const int t = threadIdx.x;
  const size_t roff = (size_t)blockIdx.x * 242;
  if (t < 242) rowv[t] = kp[roff + t];
  __syncthreads();
  const int d0 = t, d1 = t + 256;
  float p0 = bias[d0], p1 = bias[d1];
  for (int kk = 0; kk < 242; ++kk) {
    const float x = rowv[kk];
    p0 = fmaf(x, W[kk * 512 + d0], p0);
    p1 = fmaf(x, W[kk * 512 + d1], p1);
  }
  p0 = fmaxf(p0, 0.f);
  p1 = fmaxf(p1, 0.f);
  float s = p0 + p1, sq = p0 * p0 + p1 * p1;
  blockRed2(s, sq, red);
  const float m = s * (1.f / 512.f);
  const float var = sq * (1.f / 512.f) - m * m;
  const float rs = rsqrtf(var + 1e-5f);
  const size_t off = (size_t)blockIdx.x * 512;
  low[off + d0] = (p0 - m) * rs * g[d0] + bt[d0];
  low[off + d1] = (p1 - m) * rs * g[d1] + bt[d1];
}

// =====================================================================
// W_qp transpose+convert: Wt[col][k] bf16, k padded 242 -> 256 (zeros).
// =====================================================================
__global__ __launch_bounds__(256) void wqp_transpose_kernel(
    const float* __restrict__ W, __bf16* __restrict__ Wt) {
  const int c = blockIdx.x;   // 512 output columns
  const int t = threadIdx.x;  // 256 k slots
  Wt[(size_t)c * 256 + t] = (t < 242) ? (__bf16)W[(size_t)t * 512 + c] : (__bf16)0.f;
}

// =====================================================================
// W_ctc transpose+convert: Wt[c][k] bf16 for c<1296, k<1024.
// =====================================================================
__global__ __launch_bounds__(256) void wctc_transpose_kernel(
    const float* __restrict__ W, __bf16* __restrict__ Wt) {
  const int c = blockIdx.x;  // 1296 columns
  const int t = threadIdx.x;
#pragma unroll
  for (int r = 0; r < 4; ++r) {
    const int k = r * 256 + t;
    Wt[(size_t)c * 1024 + k] = (__bf16)W[(size_t)k * 1296 + c];
  }
}

// =====================================================================
// Fused MFMA pooling: pooled = pool_mean(LN(qgrids @ W_qp + b_qp)).
// =====================================================================
__global__ __launch_bounds__(512) void pool_mfma_kernel(
    const float* __restrict__ qgrids, const int* __restrict__ lens,
    const __bf16* __restrict__ Wt, const float* __restrict__ bias,
    const float* __restrict__ g, const float* __restrict__ bt,
    float* __restrict__ pooled) {
  __shared__ float red[8][16][2];
  const int t = threadIdx.x, lane = t & 63, w = t >> 6;
  const int b = blockIdx.x >> 5;          // 8 batches
  const int j0 = (blockIdx.x & 31) * 16;  // pooled-row block
  const int L = lens[b];
  int S = (L + 511) >> 9;
  if (S < 1) S = 1;
  const int new_len = (L + S - 1) / S;
  const float* qg_b = qgrids + (size_t)b * 4096 * 242;
  float* pooled_b = pooled + (size_t)b * 512 * 512;

  const int fr = lane & 15;
  const int fq = lane >> 4;
  const int fkq = fq * 8;
  const int colbase = w * 64;

  float biasv[4], gv[4], btv[4];
#pragma unroll
  for (int nt = 0; nt < 4; ++nt) {
    const int col = colbase + nt * 16 + fr;
    biasv[nt] = bias[col];
    gv[nt] = g[col];
    btv[nt] = bt[col];
  }

  f32x4 pool[4];
#pragma unroll
  for (int nt = 0; nt < 4; ++nt) pool[nt] = f32x4{0.f, 0.f, 0.f, 0.f};

  for (int i = 0; i < S; ++i) {
    const int arow = (j0 + fr) * S + i;
    const float* asrc = qg_b + (size_t)arow * 242;
    f32x4 acc[4];
#pragma unroll
    for (int nt = 0; nt < 4; ++nt) acc[nt] = f32x4{0.f, 0.f, 0.f, 0.f};
#pragma unroll
    for (int ks = 0; ks < 8; ++ks) {
      bf16x8 af;
      if (ks < 7) {
        float tmp[8];
#pragma unroll
        for (int p2 = 0; p2 < 4; ++p2) {
          f32x2 v = *reinterpret_cast<const f32x2*>(asrc + ks * 32 + fkq + p2 * 2);
          tmp[p2 * 2] = v[0];
          tmp[p2 * 2 + 1] = v[1];
        }
        af = cvt8(tmp);
      } else {
        float tmp[8];
#pragma unroll
        for (int jj = 0; jj < 8; ++jj) {
          const int kk = 224 + fkq + jj;
          tmp[jj] = (kk < 242) ? asrc[kk] : 0.f;
        }
        af = cvt8(tmp);
      }
      const __bf16* wt = Wt + ks * 32 + fkq;
#pragma unroll
      for (int nt = 0; nt < 4; ++nt) {
        bf16x8 bfv = *reinterpret_cast<const bf16x8*>(
            wt + (size_t)(colbase + nt * 16 + fr) * 256);
        acc[nt] = mfma16(af, bfv, acc[nt]);
      }
    }
    float s[4] = {0.f, 0.f, 0.f, 0.f}, sq[4] = {0.f, 0.f, 0.f, 0.f};
#pragma unroll
    for (int nt = 0; nt < 4; ++nt) {
#pragma unroll
      for (int r = 0; r < 4; ++r) {
        const float v = acc[nt][r] + biasv[nt];
        acc[nt][r] = v;
        s[r] += v;
        sq[r] += v * v;
      }
    }
#pragma unroll
    for (int off = 1; off < 16; off <<= 1) {
#pragma unroll
      for (int r = 0; r < 4; ++r) {
        s[r] += __shfl_xor(s[r], off, 64);
        sq[r] += __shfl_xor(sq[r], off, 64);
      }
    }
    if (fr == 0) {
#pragma unroll
      for (int r = 0; r < 4; ++r) {
        red[w][fq * 4 + r][0] = s[r];
        red[w][fq * 4 + r][1] = sq[r];
      }
    }
    __syncthreads();
    float mean[4], rsig[4];
#pragma unroll
    for (int r = 0; r < 4; ++r) {
      const int p = fq * 4 + r;
      float ss = 0.f, qq = 0.f;
#pragma unroll
      for (int ww = 0; ww < 8; ++ww) {
        ss += red[ww][p][0];
        qq += red[ww][p][1];
      }
      const float m = ss * (1.f / 512.f);
      mean[r] = m;
      rsig[r] = rsqrtf(qq * (1.f / 512.f) - m * m + 1e-5f);
    }
    __syncthreads();
#pragma unroll
    for (int r = 0; r < 4; ++r) {
      const int srow = (j0 + fq * 4 + r) * S + i;
      const bool ok = srow < L;
#pragma unroll
      for (int nt = 0; nt < 4; ++nt) {
        const float nv = (acc[nt][r] - mean[r]) * rsig[r] * gv[nt] + btv[nt];
        pool[nt][r] += ok ? nv : 0.f;
      }
    }
  }
  const float inv = 1.f / (float)S;
#pragma unroll
  for (int r = 0; r < 4; ++r) {
    const int j = j0 + fq * 4 + r;
    const bool ok = j < new_len;
#pragma unroll
    for (int nt = 0; nt < 4; ++nt)
      pooled_b[(size_t)j * 512 + colbase + nt * 16 + fr] =
          ok ? pool[nt][r] * inv : 0.f;
  }
}

// =====================================================================
// Generic bf16-MFMA GEMM: C[M,N] = A[M,K]@B[K,N] (+bias if flags&1,
// += existing C if flags&2). M%64==0, K%32==0; N arbitrary (guarded).
// =====================================================================
__global__ __launch_bounds__(256) void gemm_kernel(
    const float* __restrict__ A, const float* __restrict__ B,
    const float* __restrict__ bias, float* __restrict__ C, int M, int N,
    int K, int flags) {
  __shared__ __bf16 As[64 * 40];
  __shared__ __bf16 Bs[64 * 40];
  const int t = threadIdx.x, lane = t & 63, w = t >> 6;
  const int m0 = blockIdx.y * 64, n0 = blockIdx.x * 64;
  f32x4 acc[4];
#pragma unroll
  for (int j = 0; j < 4; ++j) acc[j] = f32x4{0.f, 0.f, 0.f, 0.f};
  const int ar = t >> 2, ak = (t & 3) * 8;
  const int bn = t & 63, bk = (t >> 6) * 8;
  const int fr = lane & 15, fk = (lane >> 4) * 8;
  const int col = n0 + bn;
  const bool colok = col < N;
  const int nst = K >> 5;
  for (int s = 0; s < nst; ++s) {
    const int k0 = s * 32;
    {
      const float* src = A + (size_t)(m0 + ar) * K + k0 + ak;
      f32x4 v0 = *reinterpret_cast<const f32x4*>(src);
      f32x4 v1 = *reinterpret_cast<const f32x4*>(src + 4);
      float tmp[8] = {v0[0], v0[1], v0[2], v0[3], v1[0], v1[1], v1[2], v1[3]};
      *reinterpret_cast<bf16x8*>(&As[ar * 40 + ak]) = cvt8(tmp);
    }
    {
      float tmp[8];
#pragma unroll
      for (int j = 0; j < 8; ++j)
        tmp[j] = colok ? B[(size_t)(k0 + bk + j) * N + col] : 0.f;
      *reinterpret_cast<bf16x8*>(&Bs[bn * 40 + bk]) = cvt8(tmp);
    }
    __syncthreads();
    bf16x8 a = *reinterpret_cast<const bf16x8*>(&As[(w * 16 + fr) * 40 + fk]);
#pragma unroll
    for (int j = 0; j < 4; ++j) {
      bf16x8 b = *reinterpret_cast<const bf16x8*>(&Bs[(j * 16 + fr) * 40 + fk]);
      acc[j] = mfma16(a, b, acc[j]);
    }
    __syncthreads();
  }
  const int rq = (lane >> 4) * 4;
#pragma unroll
  for (int j = 0; j < 4; ++j) {
    const int c = n0 + j * 16 + fr;
    if (c < N) {
#pragma unroll
      for (int r = 0; r < 4; ++r) {
        const size_t idx = (size_t)(m0 + w * 16 + rq + r) * N + c;
        float v = acc[j][r];
        if (flags & 1) v += bias[c];
        if (flags & 2) v += C[idx];
        C[idx] = v;
      }
    }
  }
}

// =====================================================================
// Fused K+V GEMM: blockIdx.z picks (Wk,bk,kout) vs (Wv,bv,vout).
// =====================================================================
__global__ __launch_bounds__(256) void kv_gemm_kernel(
    const float* __restrict__ A, const float* __restrict__ Wk,
    const float* __restrict__ bk, const float* __restrict__ Wv,
    const float* __restrict__ bv, float* __restrict__ kout,
    float* __restrict__ vout) {
  __shared__ __bf16 As[64 * 40];
  __shared__ __bf16 Bs[64 * 40];
  const float* B = blockIdx.z ? Wv : Wk;
  const float* bias = blockIdx.z ? bv : bk;
  float* C = blockIdx.z ? vout : kout;
  const int t = threadIdx.x, lane = t & 63, w = t >> 6;
  const int m0 = blockIdx.y * 64, n0 = blockIdx.x * 64;
  f32x4 acc[4];
#pragma unroll
  for (int j = 0; j < 4; ++j) acc[j] = f32x4{0.f, 0.f, 0.f, 0.f};
  const int ar = t >> 2, ak = (t & 3) * 8;
  const int bn = t & 63, bk2 = (t >> 6) * 8;
  const int fr = lane & 15, fk = (lane >> 4) * 8;
  const int col = n0 + bn;
  for (int s = 0; s < 16; ++s) {
    const int k0 = s * 32;
    {
      const float* src = A + (size_t)(m0 + ar) * 512 + k0 + ak;
      f32x4 v0 = *reinterpret_cast<const f32x4*>(src);
      f32x4 v1 = *reinterpret_cast<const f32x4*>(src + 4);
      float tmp[8] = {v0[0], v0[1], v0[2], v0[3], v1[0], v1[1], v1[2], v1[3]};
      *reinterpret_cast<bf16x8*>(&As[ar * 40 + ak]) = cvt8(tmp);
    }
    {
      float tmp[8];
#pragma unroll
      for (int j = 0; j < 8; ++j)
        tmp[j] = B[(size_t)(k0 + bk2 + j) * 512 + col];
      *reinterpret_cast<bf16x8*>(&Bs[bn * 40 + bk2]) = cvt8(tmp);
    }
    __syncthreads();
    bf16x8 a = *reinterpret_cast<const bf16x8*>(&As[(w * 16 + fr) * 40 + fk]);
#pragma unroll
    for (int j = 0; j < 4; ++j) {
      bf16x8 b2 = *reinterpret_cast<const bf16x8*>(&Bs[(j * 16 + fr) * 40 + fk]);
      acc[j] = mfma16(a, b2, acc[j]);
    }
    __syncthreads();
  }
  const int rq = (lane >> 4) * 4;
#pragma unroll
  for (int j = 0; j < 4; ++j) {
    const int c = n0 + j * 16 + fr;
#pragma unroll
    for (int r = 0; r < 4; ++r)
      C[(size_t)(m0 + w * 16 + rq + r) * 512 + c] = acc[j][r] + bias[c];
  }
}

// =====================================================================
// CTC head, no-LDS register GEMM: out[512,1296] = fusedbf @ Wt^T + bias.
// =====================================================================
__global__ __launch_bounds__(256) void ctc_gemm_kernel(
    const __bf16* __restrict__ A, const __bf16* __restrict__ Wt,
    const float* __restrict__ bias, float* __restrict__ out) {
  const int t = threadIdx.x, lane = t & 63, w = t >> 6;
  const int n0 = blockIdx.x * 16;
  const int m0 = blockIdx.y * 64 + w * 16;
  const int fr = lane & 15, fq = lane >> 4;
  const __bf16* arow = A + (size_t)(m0 + fr) * 1024 + fq * 8;
  const __bf16* brow = Wt + (size_t)(n0 + fr) * 1024 + fq * 8;
  f32x4 acc = f32x4{0.f, 0.f, 0.f, 0.f};
#pragma unroll
  for (int ks = 0; ks < 32; ++ks) {
    bf16x8 a = *reinterpret_cast<const bf16x8*>(arow + ks * 32);
    bf16x8 b = *reinterpret_cast<const bf16x8*>(brow + ks * 32);
    acc = mfma16(a, b, acc);
  }
  const int col = n0 + fr;
  const float bv = bias[col];
  const int r0 = m0 + fq * 4;
#pragma unroll
  for (int r = 0; r < 4; ++r)
    out[(size_t)(r0 + r) * 1296 + col] = acc[r] + bv;
}

// =====================================================================
// Attention stage 1: P = softmax(mask(Q_h @ K_h^T / 8)) as bf16.
// =====================================================================
__global__ __launch_bounds__(256) void attn_scores_kernel(
    const float* __restrict__ q, const float* __restrict__ k,
    const int* __restrict__ lens, __bf16* __restrict__ P) {
  __shared__ __bf16 Qs[64 * 72];
  __shared__ __bf16 Bs[512 * 40];
  const int t = threadIdx.x, lane = t & 63, w = t >> 6;
  const int bh = blockIdx.x, b = bh >> 3, h = bh & 7;
  const int L = lens[b];
  const int sdiv = (L + 511) >> 9;
  const int new_len = (L + sdiv - 1) / sdiv;
  const size_t qbase = (size_t)b * 64 * 512 + h * 64;
  const size_t kbase = (size_t)b * 512 * 512 + h * 64;
#pragma unroll
  for (int rep = 0; rep < 4; ++rep) {
    const int gidx = rep * 256 + t;
    const int row = gidx >> 4, c = (gidx & 15) * 4;
    f32x4 v = *reinterpret_cast<const f32x4*>(&q[qbase + (size_t)row * 512 + c]);
    *reinterpret_cast<bf16x4*>(&Qs[row * 72 + c]) = cvt4(v);
  }
  f32x4 acc[32];
#pragma unroll
  for (int nt = 0; nt < 32; ++nt) acc[nt] = f32x4{0.f, 0.f, 0.f, 0.f};
  const int fr = lane & 15, fkq = (lane >> 4) * 8;
  for (int ks = 0; ks < 2; ++ks) {
    const int k0 = ks * 32;
#pragma unroll
    for (int rep = 0; rep < 16; ++rep) {
      const int gidx = rep * 256 + t;
      const int row = gidx >> 3, c = (gidx & 7) * 4;
      f32x4 v =
          *reinterpret_cast<const f32x4*>(&k[kbase + (size_t)row * 512 + k0 + c]);
      *reinterpret_cast<bf16x4*>(&Bs[row * 40 + c]) = cvt4(v);
    }
    __syncthreads();
    const bf16x8 af =
        *reinterpret_cast<const bf16x8*>(&Qs[(w * 16 + fr) * 72 + k0 + fkq]);
#pragma unroll
    for (int nt = 0; nt < 32; ++nt) {
      bf16x8 bf = *reinterpret_cast<const bf16x8*>(&Bs[(nt * 16 + fr) * 40 + fkq]);
      acc[nt] = mfma16(af, bf, acc[nt]);
    }
    __syncthreads();
  }
  const float scale = 0.125f;
  const size_t pb = (size_t)bh * 64 * 512;
#pragma unroll
  for (int r = 0; r < 4; ++r) {
    float mx = -3.0e38f;
#pragma unroll
    for (int nt = 0; nt < 32; ++nt) {
      const int col = nt * 16 + fr;
      const float sv = acc[nt][r] * scale;
      if (col < new_len) mx = fmaxf(mx, sv);
    }
#pragma unroll
    for (int off = 1; off < 16; off <<= 1) mx = fmaxf(mx, __shfl_xor(mx, off, 64));
    float sum = 0.f;
#pragma unroll
    for (int nt = 0; nt < 32; ++nt) {
      const int col = nt * 16 + fr;
      const float e = (col < new_len) ? __expf(acc[nt][r] * scale - mx) : 0.f;
      acc[nt][r] = e;
      sum += e;
    }
#pragma unroll
    for (int off = 1; off < 16; off <<= 1) sum += __shfl_xor(sum, off, 64);
    const float inv = 1.f / sum;
    const int row = w * 16 + ((lane >> 4) << 2) + r;
    __bf16* dst = P + pb + (size_t)row * 512 + fr;
#pragma unroll
    for (int nt = 0; nt < 32; ++nt) dst[nt * 16] = (__bf16)(acc[nt][r] * inv);
  }
}

// =====================================================================
// Attention stage 2: ctx = P_h(64x512 bf16) @ V_h(512x64).
// =====================================================================
__global__ __launch_bounds__(256) void attn_pv_kernel(
    const __bf16* __restrict__ P, const float* __restrict__ v,
    float* __restrict__ ctx) {
  __shared__ __bf16 As[64 * 40];
  __shared__ __bf16 Bs[64 * 40];
  const int t = threadIdx.x, lane = t & 63, w = t >> 6;
  const int bh = blockIdx.x, b = bh >> 3, h = bh & 7;
  const size_t pbase = (size_t)bh * 64 * 512;
  const size_t vbase = (size_t)b * 512 * 512 + h * 64;
  f32x4 acc[4];
#pragma unroll
  for (int j = 0; j < 4; ++j) acc[j] = f32x4{0.f, 0.f, 0.f, 0.f};
  const int fr = lane & 15, fk = (lane >> 4) * 8;
  const int arow = t >> 2, ac = (t & 3) * 8;
  const int bn = t & 63, bk = (t >> 6) * 8;
  for (int s = 0; s < 16; ++s) {
    const int k0 = s * 32;
    *reinterpret_cast<bf16x8*>(&As[arow * 40 + ac]) =
        *reinterpret_cast<const bf16x8*>(&P[pbase + (size_t)arow * 512 + k0 + ac]);
    {
      float tmp[8];
#pragma unroll
      for (int j = 0; j < 8; ++j)
        tmp[j] = v[vbase + (size_t)(k0 + bk + j) * 512 + bn];
      *reinterpret_cast<bf16x8*>(&Bs[bn * 40 + bk]) = cvt8(tmp);
    }
    __syncthreads();
    const bf16x8 a = *reinterpret_cast<const bf16x8*>(&As[(w * 16 + fr) * 40 + fk]);
#pragma unroll
    for (int j = 0; j < 4; ++j) {
      bf16x8 bfrag = *reinterpret_cast<const bf16x8*>(&Bs[(j * 16 + fr) * 40 + fk]);
      acc[j] = mfma16(a, bfrag, acc[j]);
    }
    __syncthreads();
  }
  const int rq = (lane >> 4) * 4;
  const size_t cbase = (size_t)b * 64 * 512 + h * 64;
#pragma unroll
  for (int j = 0; j < 4; ++j)
#pragma unroll
    for (int r = 0; r < 4; ++r)
      ctx[cbase + (size_t)(w * 16 + rq + r) * 512 + j * 16 + fr] = acc[j][r];
}

// LayerNorm over rows of 512, bf16 output into fusedbf[:, 512:1024]
__global__ __launch_bounds__(256) void ln_bf16_kernel(
    const float* __restrict__ x, const float* __restrict__ g,
    const float* __restrict__ bt, __bf16* __restrict__ ybf) {
  __shared__ float red[8];
  const int t = threadIdx.x;
  const size_t off = (size_t)blockIdx.x * 512;
  const float a = x[off + t], b2 = x[off + t + 256];
  float s = a + b2, sq = a * a + b2 * b2;
  blockRed2(s, sq, red);
  const float m = s * (1.f / 512.f);
  const float var = sq * (1.f / 512.f) - m * m;
  const float rs = rsqrtf(var + 1e-5f);
  __bf16* yrow = ybf + (size_t)blockIdx.x * 1024;
  yrow[t] = (__bf16)((a - m) * rs * g[t] + bt[t]);
  yrow[t + 256] = (__bf16)((b2 - m) * rs * g[t + 256] + bt[t + 256]);
}

// =====================================================================
// Workspace layout (live ranges by step; ws >= 36 MB, proven by round
// 1-6 partials usage at ws+12..36):
//   ws+ 0.. 1 MB  low      (2-6)
//   ws+ 1.. 2 MB  qbuf     (6-7)
//   ws+ 2.. 3 MB  wtq (0-4) then ctxo (8)
//   ws+ 3.. 4 MB  fusedbf  (3-9)      <- never alias pbuf!
//   ws+ 4..28.5   partials bf16, 49 x 512KB (1-3, dead after 3)
//     overlaps:   pooled   ws+4..12   (4-5)
//                 pbuf 4MB ws+4..8    (7a-7b)
//                 kbuf     ws+12..20  (5-7)
//                 vbuf     ws+20..28  (5-7)
//   ws+28..29 MB  ctx      (7b-8)
//   ws+29..31.6   wtc      (3b-9)
// =====================================================================
extern "C" void kernel_launch(void* const* d_in, const int* in_sizes, int n_in,
                              void* d_out, int out_size, void* d_ws,
                              size_t ws_size, hipStream_t stream) {
  const float* images = (const float*)d_in[0];
  const float* qgrids = (const float*)d_in[1];
  const float* keypoints = (const float*)d_in[2];
  const int* qlens = (const int*)d_in[3];
  const float* W_img = (const float*)d_in[4];
  const float* b_img = (const float*)d_in[5];
  const float* W_kp = (const float*)d_in[6];
  const float* b_kp = (const float*)d_in[7];
  const float* g_kp = (const float*)d_in[8];
  const float* bt_kp = (const float*)d_in[9];
  const float* W_qp = (const float*)d_in[10];
  const float* b_qp = (const float*)d_in[11];
  const float* g_qln = (const float*)d_in[12];
  const float* bt_qln = (const float*)d_in[13];
  const float* Wq = (const float*)d_in[14];
  const float* bq = (const float*)d_in[15];
  const float* Wk = (const float*)d_in[16];
  const float* bk = (const float*)d_in[17];
  const float* Wv = (const float*)d_in[18];
  const float* bv = (const float*)d_in[19];
  const float* Wo = (const float*)d_in[20];
  const float* bo = (const float*)d_in[21];
  const float* g_attn = (const float*)d_in[22];
  const float* bt_attn = (const float*)d_in[23];
  const float* W_ctc = (const float*)d_in[24];
  const float* b_ctc = (const float*)d_in[25];
  float* out = (float*)d_out;

  const size_t MB = 1u << 20;
  if (ws_size < 32 * MB) return;
  char* ws = (char*)d_ws;
  float* low = (float*)(ws);                 // 1 MB
  float* qbuf = (float*)(ws + 1 * MB);       // 1 MB
  __bf16* wtq = (__bf16*)(ws + 2 * MB);      // 256 KB (dead after step 4)
  float* ctxo = (float*)(ws + 2 * MB);       // 1 MB (written step 8)
  __bf16* fusedbf = (__bf16*)(ws + 3 * MB);  // 1 MB (512x1024 bf16)
  __bf16* partials = (__bf16*)(ws + 4 * MB); // 24.5 MB bf16 (dead after 3)
  float* pooled = (float*)(ws + 4 * MB);     // 8 MB (steps 4-5)
  __bf16* pbuf = (__bf16*)(ws + 4 * MB);     // 4 MB (P; steps 7a-7b)
  float* kbuf = (float*)(ws + 12 * MB);      // 8 MB (5-7)
  float* vbuf = (float*)(ws + 20 * MB);      // 8 MB (5-7)
  float* ctx = (float*)(ws + 28 * MB);       // 1 MB (7b-8)
  __bf16* wtc = (__bf16*)(ws + 29 * MB);     // 2.6 MB Wt_ctc (3b-9)

  // 0) Wt_qp = transpose(W_qp) bf16, K padded to 256
  wqp_transpose_kernel<<<512, 256, 0, stream>>>(W_qp, wtq);
  // 1) img GEMM partials (split-K=49, bf16 partials, dbuf pipeline)
  img_gemm_kernel<<<dim3(4, 4, SPLITK), 512, 0, stream>>>(images, W_img, partials);
  // 2) kp_feat -> low
  kp_kernel<<<512, 256, 0, stream>>>(keypoints, W_kp, b_kp, g_kp, bt_kp, low);
  // 3) low += b_img + sum(partials); also fusedbf[:, :512] = bf16(low)
  reduce_add_kernel<<<1024, 256, 0, stream>>>(partials, b_img, low, fusedbf);
  // 3b) Wt_ctc = transpose(W_ctc) bf16
  wctc_transpose_kernel<<<1296, 256, 0, stream>>>(W_ctc, wtc);
  // 4) pooled qgrid tokens (MFMA proj + LN + ragged mean-pool)
  pool_mfma_kernel<<<256, 512, 0, stream>>>(qgrids, qlens, wtq, b_qp, g_qln,
                                            bt_qln, pooled);
  // 5) k + v from pooled, fused launch
  kv_gemm_kernel<<<dim3(8, 64, 2), 256, 0, stream>>>(pooled, Wk, bk, Wv, bv,
                                                     kbuf, vbuf);
  // 6) q from low
  gemm_kernel<<<dim3(8, 8), 256, 0, stream>>>(low, Wq, bq, qbuf, 512, 512, 512, 1);
  // 7) fused attention: batched MFMA scores+softmax, then MFMA PV
  attn_scores_kernel<<<64, 256, 0, stream>>>(qbuf, kbuf, qlens, pbuf);
  attn_pv_kernel<<<64, 256, 0, stream>>>(pbuf, vbuf, ctx);
  // 8) ctx @ Wo + bo, then LN -> fusedbf[:, 512:] (bf16)
  gemm_kernel<<<dim3(8, 8), 256, 0, stream>>>(ctx, Wo, bo, ctxo, 512, 512, 512, 1);
  ln_bf16_kernel<<<512, 256, 0, stream>>>(ctxo, g_attn, bt_attn, fusedbf + 512);
  // 9) out = fusedbf @ Wt_ctc^T + b_ctc (register GEMM, no LDS/barriers)
  ctc_gemm_kernel<<<dim3(81, 8), 256, 0, stream>>>(fusedbf, wtc, b_ctc, out);
}

// Round 8
// 326.667 us; speedup vs baseline: 2.0359x; 1.0523x over previous
//
#include <hip/hip_runtime.h>
#include <hip/hip_bf16.h>

typedef __bf16 bf16x8 __attribute__((ext_vector_type(8)));
typedef __bf16 bf16x4 __attribute__((ext_vector_type(4)));
typedef float f32x4 __attribute__((ext_vector_type(4)));
typedef float f32x2 __attribute__((ext_vector_type(2)));

__device__ __forceinline__ f32x4 mfma16(bf16x8 a, bf16x8 b, f32x4 c) {
  return __builtin_amdgcn_mfma_f32_16x16x32_bf16(a, b, c, 0, 0, 0);
}

__device__ __forceinline__ bf16x8 cvt8(const float* f) {
  bf16x8 r;
#pragma unroll
  for (int i = 0; i < 8; ++i) r[i] = (__bf16)f[i];
  return r;
}

__device__ __forceinline__ bf16x4 cvt4(f32x4 v) {
  bf16x4 r;
#pragma unroll
  for (int i = 0; i < 4; ++i) r[i] = (__bf16)v[i];
  return r;
}

// ---- block reduction helpers (blockDim.x == 256 assumed, 4 waves) ----
__device__ __forceinline__ void blockRed2(float& a, float& b, float* red) {
#pragma unroll
  for (int off = 1; off < 64; off <<= 1) {
    a += __shfl_xor(a, off, 64);
    b += __shfl_xor(b, off, 64);
  }
  const int w = threadIdx.x >> 6;
  if ((threadIdx.x & 63) == 0) { red[w] = a; red[4 + w] = b; }
  __syncthreads();
  a = red[0] + red[1] + red[2] + red[3];
  b = red[4] + red[5] + red[6] + red[7];
  __syncthreads();
}

// =====================================================================
// Stage A: img_feat partials = images_flat(512x37632) @ W_img(37632x512)
// split-K=49, tile 128x128, 8 waves (wave tile 64x32), double-buffered
// LDS, DEPTH-2 register pipeline: loads for step s+2 issue at step s,
// land a full iteration later (2x in-flight bytes vs depth-1; the
// round-7 depth-1 version was latency-capped at 2.35 TB/s).
// Partials stored bf16 (std~0.2, rounding ~8e-4/slice -> negligible).
// =====================================================================
#define IMG_K 37632
#define SPLITK 49
#define STEPS_PER 24  // 1176 k-steps of 32 / 49 (even: 2x-unrolled loop)

__global__ __launch_bounds__(512) void img_gemm_kernel(
    const float* __restrict__ A, const float* __restrict__ B,
    __bf16* __restrict__ partials) {
  __shared__ __bf16 As[2][128 * 40];
  __shared__ __bf16 Bs[2][128 * 40];
  const int t = threadIdx.x;
  const int lane = t & 63;
  const int w = t >> 6;
  const int wr = (w >> 2) * 64;  // wave row base: 0 / 64
  const int wc = (w & 3) * 32;   // wave col base: 0/32/64/96
  const int m0 = blockIdx.y * 128, n0 = blockIdx.x * 128;
  const int step0 = blockIdx.z * STEPS_PER;

  f32x4 acc[4][2];
#pragma unroll
  for (int i = 0; i < 4; ++i)
#pragma unroll
    for (int j = 0; j < 2; ++j) acc[i][j] = f32x4{0.f, 0.f, 0.f, 0.f};

  const int ar = t >> 2, ak = (t & 3) * 8;
  const int bn = t & 127, bk = (t >> 7) * 8;
  const int fr = lane & 15, fk = (lane >> 4) * 8;

  float a0[8], b0[8], a1[8], b1[8];
#define IMG_LOAD(AT, BT, K0)                                                \
  do {                                                                      \
    const float* asrc = A + (size_t)(m0 + ar) * IMG_K + (K0) + ak;          \
    f32x4 v0 = *reinterpret_cast<const f32x4*>(asrc);                       \
    f32x4 v1 = *reinterpret_cast<const f32x4*>(asrc + 4);                   \
    AT[0] = v0[0]; AT[1] = v0[1]; AT[2] = v0[2]; AT[3] = v0[3];             \
    AT[4] = v1[0]; AT[5] = v1[1]; AT[6] = v1[2]; AT[7] = v1[3];             \
    const float* bsrc = B + (size_t)((K0) + bk) * 512 + n0 + bn;            \
    _Pragma("unroll") for (int j = 0; j < 8; ++j) BT[j] =                   \
        bsrc[(size_t)j * 512];                                              \
  } while (0)
#define IMG_WRITE(BUF, AT, BT)                                              \
  do {                                                                      \
    *reinterpret_cast<bf16x8*>(&As[BUF][ar * 40 + ak]) = cvt8(AT);          \
    *reinterpret_cast<bf16x8*>(&Bs[BUF][bn * 40 + bk]) = cvt8(BT);          \
  } while (0)
#define IMG_MFMA(BUF)                                                       \
  do {                                                                      \
    bf16x8 af[4], bfr[2];                                                   \
    _Pragma("unroll") for (int i = 0; i < 4; ++i) af[i] =                   \
        *reinterpret_cast<const bf16x8*>(                                   \
            &As[BUF][(wr + i * 16 + fr) * 40 + fk]);                        \
    _Pragma("unroll") for (int j = 0; j < 2; ++j) bfr[j] =                  \
        *reinterpret_cast<const bf16x8*>(                                   \
            &Bs[BUF][(wc + j * 16 + fr) * 40 + fk]);                        \
    _Pragma("unroll") for (int i = 0; i < 4; ++i)                           \
        _Pragma("unroll") for (int j = 0; j < 2; ++j) acc[i][j] =           \
            mfma16(af[i], bfr[j], acc[i][j]);                               \
  } while (0)

  // prologue: step0 -> buf0 (exposed once), step1 loads in flight
  IMG_LOAD(a0, b0, step0 * 32);
  IMG_WRITE(0, a0, b0);
  IMG_LOAD(a1, b1, (step0 + 1) * 32);
  __syncthreads();

  for (int s = 0; s < STEPS_PER; s += 2) {
    // even step s: compute buf0; issue s+2; commit s+1 (loaded 1 iter ago)
    if (s + 2 < STEPS_PER) IMG_LOAD(a0, b0, (step0 + s + 2) * 32);
    IMG_MFMA(0);
    IMG_WRITE(1, a1, b1);
    __syncthreads();
    // odd step s+1: compute buf1; issue s+3; commit s+2
    if (s + 3 < STEPS_PER) IMG_LOAD(a1, b1, (step0 + s + 3) * 32);
    IMG_MFMA(1);
    if (s + 2 < STEPS_PER) IMG_WRITE(0, a0, b0);
    __syncthreads();
  }
#undef IMG_LOAD
#undef IMG_WRITE
#undef IMG_MFMA

  __bf16* P = partials + (size_t)blockIdx.z * (512 * 512);
  const int rq = (lane >> 4) * 4;
#pragma unroll
  for (int i = 0; i < 4; ++i)
#pragma unroll
    for (int j = 0; j < 2; ++j)
#pragma unroll
      for (int r = 0; r < 4; ++r)
        P[(size_t)(m0 + wr + i * 16 + rq + r) * 512 + (n0 + wc + j * 16 + fr)] =
            (__bf16)acc[i][j][r];
}

// low[idx] = kp_feat(already there) + b_img + sum_z partials[z][idx];
// also writes bf16 copy into fusedbf[:, 0:512] (row stride 1024).
__global__ __launch_bounds__(256) void reduce_add_kernel(
    const __bf16* __restrict__ partials, const float* __restrict__ b_img,
    float* __restrict__ low, __bf16* __restrict__ fusedbf) {
  const int idx = blockIdx.x * 256 + threadIdx.x;
  float acc = low[idx] + b_img[idx & 511];
#pragma unroll
  for (int z = 0; z < SPLITK; ++z)
    acc += (float)partials[(size_t)z * 262144 + idx];
  low[idx] = acc;
  fusedbf[(size_t)(idx >> 9) * 1024 + (idx & 511)] = (__bf16)acc;
}

// =====================================================================
// kp_feat = LN(relu(keypoints @ W_kp + b_kp)); one block per row (512)
// =====================================================================
__global__ __launch_bounds__(256) void kp_kernel(
    const float* __restrict__ kp, const float* __restrict__ W,
    const float* __restrict__ bias, const float* __restrict__ g,
    const float* __restrict__ bt, float* __restrict__ low) {
  __shared__ float rowv[242];
  __shared__ float red[8];
  const int t = threadIdx.x;
  const size_t roff = (size_t)blockIdx.x * 242;
  if (t < 242) rowv[t] = kp[roff + t];
  __syncthreads();
  const int d0 = t, d1 = t + 256;
  float p0 = bias[d0], p1 = bias[d1];
  for (int kk = 0; kk < 242; ++kk) {
    const float x = rowv[kk];
    p0 = fmaf(x, W[kk * 512 + d0], p0);
    p1 = fmaf(x, W[kk * 512 + d1], p1);
  }
  p0 = fmaxf(p0, 0.f);
  p1 = fmaxf(p1, 0.f);
  float s = p0 + p1, sq = p0 * p0 + p1 * p1;
  blockRed2(s, sq, red);
  const float m = s * (1.f / 512.f);
  const float var = sq * (1.f / 512.f) - m * m;
  const float rs = rsqrtf(var + 1e-5f);
  const size_t off = (size_t)blockIdx.x * 512;
  low[off + d0] = (p0 - m) * rs * g[d0] + bt[d0];
  low[off + d1] = (p1 - m) * rs * g[d1] + bt[d1];
}

// =====================================================================
// W_qp transpose+convert: Wt[col][k] bf16, k padded 242 -> 256 (zeros).
// =====================================================================
__global__ __launch_bounds__(256) void wqp_transpose_kernel(
    const float* __restrict__ W, __bf16* __restrict__ Wt) {
  const int c = blockIdx.x;   // 512 output columns
  const int t = threadIdx.x;  // 256 k slots
  Wt[(size_t)c * 256 + t] = (t < 242) ? (__bf16)W[(size_t)t * 512 + c] : (__bf16)0.f;
}

// =====================================================================
// W_ctc transpose+convert: Wt[c][k] bf16 for c<1296, k<1024.
// =====================================================================
__global__ __launch_bounds__(256) void wctc_transpose_kernel(
    const float* __restrict__ W, __bf16* __restrict__ Wt) {
  const int c = blockIdx.x;  // 1296 columns
  const int t = threadIdx.x;
#pragma unroll
  for (int r = 0; r < 4; ++r) {
    const int k = r * 256 + t;
    Wt[(size_t)c * 1024 + k] = (__bf16)W[(size_t)k * 1296 + c];
  }
}

// =====================================================================
// Fused MFMA pooling: pooled = pool_mean(LN(qgrids @ W_qp + b_qp)).
// =====================================================================
__global__ __launch_bounds__(512) void pool_mfma_kernel(
    const float* __restrict__ qgrids, const int* __restrict__ lens,
    const __bf16* __restrict__ Wt, const float* __restrict__ bias,
    const float* __restrict__ g, const float* __restrict__ bt,
    float* __restrict__ pooled) {
  __shared__ float red[8][16][2];
  const int t = threadIdx.x, lane = t & 63, w = t >> 6;
  const int b = blockIdx.x >> 5;          // 8 batches
  const int j0 = (blockIdx.x & 31) * 16;  // pooled-row block
  const int L = lens[b];
  int S = (L + 511) >> 9;
  if (S < 1) S = 1;
  const int new_len = (L + S - 1) / S;
  const float* qg_b = qgrids + (size_t)b * 4096 * 242;
  float* pooled_b = pooled + (size_t)b * 512 * 512;

  const int fr = lane & 15;
  const int fq = lane >> 4;
  const int fkq = fq * 8;
  const int colbase = w * 64;

  float biasv[4], gv[4], btv[4];
#pragma unroll
  for (int nt = 0; nt < 4; ++nt) {
    const int col = colbase + nt * 16 + fr;
    biasv[nt] = bias[col];
    gv[nt] = g[col];
    btv[nt] = bt[col];
  }

  f32x4 pool[4];
#pragma unroll
  for (int nt = 0; nt < 4; ++nt) pool[nt] = f32x4{0.f, 0.f, 0.f, 0.f};

  for (int i = 0; i < S; ++i) {
    const int arow = (j0 + fr) * S + i;
    const float* asrc = qg_b + (size_t)arow * 242;
    f32x4 acc[4];
#pragma unroll
    for (int nt = 0; nt < 4; ++nt) acc[nt] = f32x4{0.f, 0.f, 0.f, 0.f};
#pragma unroll
    for (int ks = 0; ks < 8; ++ks) {
      bf16x8 af;
      if (ks < 7) {
        float tmp[8];
#pragma unroll
        for (int p2 = 0; p2 < 4; ++p2) {
          f32x2 v = *reinterpret_cast<const f32x2*>(asrc + ks * 32 + fkq + p2 * 2);
          tmp[p2 * 2] = v[0];
          tmp[p2 * 2 + 1] = v[1];
        }
        af = cvt8(tmp);
      } else {
        float tmp[8];
#pragma unroll
        for (int jj = 0; jj < 8; ++jj) {
          const int kk = 224 + fkq + jj;
          tmp[jj] = (kk < 242) ? asrc[kk] : 0.f;
        }
        af = cvt8(tmp);
      }
      const __bf16* wt = Wt + ks * 32 + fkq;
#pragma unroll
      for (int nt = 0; nt < 4; ++nt) {
        bf16x8 bfv = *reinterpret_cast<const bf16x8*>(
            wt + (size_t)(colbase + nt * 16 + fr) * 256);
        acc[nt] = mfma16(af, bfv, acc[nt]);
      }
    }
    float s[4] = {0.f, 0.f, 0.f, 0.f}, sq[4] = {0.f, 0.f, 0.f, 0.f};
#pragma unroll
    for (int nt = 0; nt < 4; ++nt) {
#pragma unroll
      for (int r = 0; r < 4; ++r) {
        const float v = acc[nt][r] + biasv[nt];
        acc[nt][r] = v;
        s[r] += v;
        sq[r] += v * v;
      }
    }
#pragma unroll
    for (int off = 1; off < 16; off <<= 1) {
#pragma unroll
      for (int r = 0; r < 4; ++r) {
        s[r] += __shfl_xor(s[r], off, 64);
        sq[r] += __shfl_xor(sq[r], off, 64);
      }
    }
    if (fr == 0) {
#pragma unroll
      for (int r = 0; r < 4; ++r) {
        red[w][fq * 4 + r][0] = s[r];
        red[w][fq * 4 + r][1] = sq[r];
      }
    }
    __syncthreads();
    float mean[4], rsig[4];
#pragma unroll
    for (int r = 0; r < 4; ++r) {
      const int p = fq * 4 + r;
      float ss = 0.f, qq = 0.f;
#pragma unroll
      for (int ww = 0; ww < 8; ++ww) {
        ss += red[ww][p][0];
        qq += red[ww][p][1];
      }
      const float m = ss * (1.f / 512.f);
      mean[r] = m;
      rsig[r] = rsqrtf(qq * (1.f / 512.f) - m * m + 1e-5f);
    }
    __syncthreads();
#pragma unroll
    for (int r = 0; r < 4; ++r) {
      const int srow = (j0 + fq * 4 + r) * S + i;
      const bool ok = srow < L;
#pragma unroll
      for (int nt = 0; nt < 4; ++nt) {
        const float nv = (acc[nt][r] - mean[r]) * rsig[r] * gv[nt] + btv[nt];
        pool[nt][r] += ok ? nv : 0.f;
      }
    }
  }
  const float inv = 1.f / (float)S;
#pragma unroll
  for (int r = 0; r < 4; ++r) {
    const int j = j0 + fq * 4 + r;
    const bool ok = j < new_len;
#pragma unroll
    for (int nt = 0; nt < 4; ++nt)
      pooled_b[(size_t)j * 512 + colbase + nt * 16 + fr] =
          ok ? pool[nt][r] * inv : 0.f;
  }
}

// =====================================================================
// Generic bf16-MFMA GEMM: C[M,N] = A[M,K]@B[K,N] (+bias if flags&1,
// += existing C if flags&2). M%64==0, K%32==0; N arbitrary (guarded).
// =====================================================================
__global__ __launch_bounds__(256) void gemm_kernel(
    const float* __restrict__ A, const float* __restrict__ B,
    const float* __restrict__ bias, float* __restrict__ C, int M, int N,
    int K, int flags) {
  __shared__ __bf16 As[64 * 40];
  __shared__ __bf16 Bs[64 * 40];
  const int t = threadIdx.x, lane = t & 63, w = t >> 6;
  const int m0 = blockIdx.y * 64, n0 = blockIdx.x * 64;
  f32x4 acc[4];
#pragma unroll
  for (int j = 0; j < 4; ++j) acc[j] = f32x4{0.f, 0.f, 0.f, 0.f};
  const int ar = t >> 2, ak = (t & 3) * 8;
  const int bn = t & 63, bk = (t >> 6) * 8;
  const int fr = lane & 15, fk = (lane >> 4) * 8;
  const int col = n0 + bn;
  const bool colok = col < N;
  const int nst = K >> 5;
  for (int s = 0; s < nst; ++s) {
    const int k0 = s * 32;
    {
      const float* src = A + (size_t)(m0 + ar) * K + k0 + ak;
      f32x4 v0 = *reinterpret_cast<const f32x4*>(src);
      f32x4 v1 = *reinterpret_cast<const f32x4*>(src + 4);
      float tmp[8] = {v0[0], v0[1], v0[2], v0[3], v1[0], v1[1], v1[2], v1[3]};
      *reinterpret_cast<bf16x8*>(&As[ar * 40 + ak]) = cvt8(tmp);
    }
    {
      float tmp[8];
#pragma unroll
      for (int j = 0; j < 8; ++j)
        tmp[j] = colok ? B[(size_t)(k0 + bk + j) * N + col] : 0.f;
      *reinterpret_cast<bf16x8*>(&Bs[bn * 40 + bk]) = cvt8(tmp);
    }
    __syncthreads();
    bf16x8 a = *reinterpret_cast<const bf16x8*>(&As[(w * 16 + fr) * 40 + fk]);
#pragma unroll
    for (int j = 0; j < 4; ++j) {
      bf16x8 b = *reinterpret_cast<const bf16x8*>(&Bs[(j * 16 + fr) * 40 + fk]);
      acc[j] = mfma16(a, b, acc[j]);
    }
    __syncthreads();
  }
  const int rq = (lane >> 4) * 4;
#pragma unroll
  for (int j = 0; j < 4; ++j) {
    const int c = n0 + j * 16 + fr;
    if (c < N) {
#pragma unroll
      for (int r = 0; r < 4; ++r) {
        const size_t idx = (size_t)(m0 + w * 16 + rq + r) * N + c;
        float v = acc[j][r];
        if (flags & 1) v += bias[c];
        if (flags & 2) v += C[idx];
        C[idx] = v;
      }
    }
  }
}

// =====================================================================
// Fused K+V GEMM: blockIdx.z picks (Wk,bk,kout) vs (Wv,bv,vout).
// =====================================================================
__global__ __launch_bounds__(256) void kv_gemm_kernel(
    const float* __restrict__ A, const float* __restrict__ Wk,
    const float* __restrict__ bk, const float* __restrict__ Wv,
    const float* __restrict__ bv, float* __restrict__ kout,
    float* __restrict__ vout) {
  __shared__ __bf16 As[64 * 40];
  __shared__ __bf16 Bs[64 * 40];
  const float* B = blockIdx.z ? Wv : Wk;
  const float* bias = blockIdx.z ? bv : bk;
  float* C = blockIdx.z ? vout : kout;
  const int t = threadIdx.x, lane = t & 63, w = t >> 6;
  const int m0 = blockIdx.y * 64, n0 = blockIdx.x * 64;
  f32x4 acc[4];
#pragma unroll
  for (int j = 0; j < 4; ++j) acc[j] = f32x4{0.f, 0.f, 0.f, 0.f};
  const int ar = t >> 2, ak = (t & 3) * 8;
  const int bn = t & 63, bk2 = (t >> 6) * 8;
  const int fr = lane & 15, fk = (lane >> 4) * 8;
  const int col = n0 + bn;
  for (int s = 0; s < 16; ++s) {
    const int k0 = s * 32;
    {
      const float* src = A + (size_t)(m0 + ar) * 512 + k0 + ak;
      f32x4 v0 = *reinterpret_cast<const f32x4*>(src);
      f32x4 v1 = *reinterpret_cast<const f32x4*>(src + 4);
      float tmp[8] = {v0[0], v0[1], v0[2], v0[3], v1[0], v1[1], v1[2], v1[3]};
      *reinterpret_cast<bf16x8*>(&As[ar * 40 + ak]) = cvt8(tmp);
    }
    {
      float tmp[8];
#pragma unroll
      for (int j = 0; j < 8; ++j)
        tmp[j] = B[(size_t)(k0 + bk2 + j) * 512 + col];
      *reinterpret_cast<bf16x8*>(&Bs[bn * 40 + bk2]) = cvt8(tmp);
    }
    __syncthreads();
    bf16x8 a = *reinterpret_cast<const bf16x8*>(&As[(w * 16 + fr) * 40 + fk]);
#pragma unroll
    for (int j = 0; j < 4; ++j) {
      bf16x8 b2 = *reinterpret_cast<const bf16x8*>(&Bs[(j * 16 + fr) * 40 + fk]);
      acc[j] = mfma16(a, b2, acc[j]);
    }
    __syncthreads();
  }
  const int rq = (lane >> 4) * 4;
#pragma unroll
  for (int j = 0; j < 4; ++j) {
    const int c = n0 + j * 16 + fr;
#pragma unroll
    for (int r = 0; r < 4; ++r)
      C[(size_t)(m0 + w * 16 + rq + r) * 512 + c] = acc[j][r] + bias[c];
  }
}

// =====================================================================
// CTC head, no-LDS register GEMM: out[512,1296] = fusedbf @ Wt^T + bias.
// =====================================================================
__global__ __launch_bounds__(256) void ctc_gemm_kernel(
    const __bf16* __restrict__ A, const __bf16* __restrict__ Wt,
    const float* __restrict__ bias, float* __restrict__ out) {
  const int t = threadIdx.x, lane = t & 63, w = t >> 6;
  const int n0 = blockIdx.x * 16;
  const int m0 = blockIdx.y * 64 + w * 16;
  const int fr = lane & 15, fq = lane >> 4;
  const __bf16* arow = A + (size_t)(m0 + fr) * 1024 + fq * 8;
  const __bf16* brow = Wt + (size_t)(n0 + fr) * 1024 + fq * 8;
  f32x4 acc = f32x4{0.f, 0.f, 0.f, 0.f};
#pragma unroll
  for (int ks = 0; ks < 32; ++ks) {
    bf16x8 a = *reinterpret_cast<const bf16x8*>(arow + ks * 32);
    bf16x8 b = *reinterpret_cast<const bf16x8*>(brow + ks * 32);
    acc = mfma16(a, b, acc);
  }
  const int col = n0 + fr;
  const float bv = bias[col];
  const int r0 = m0 + fq * 4;
#pragma unroll
  for (int r = 0; r < 4; ++r)
    out[(size_t)(r0 + r) * 1296 + col] = acc[r] + bv;
}

// =====================================================================
// Attention stage 1: P = softmax(mask(Q_h @ K_h^T / 8)) as bf16.
// =====================================================================
__global__ __launch_bounds__(256) void attn_scores_kernel(
    const float* __restrict__ q, const float* __restrict__ k,
    const int* __restrict__ lens, __bf16* __restrict__ P) {
  __shared__ __bf16 Qs[64 * 72];
  __shared__ __bf16 Bs[512 * 40];
  const int t = threadIdx.x, lane = t & 63, w = t >> 6;
  const int bh = blockIdx.x, b = bh >> 3, h = bh & 7;
  const int L = lens[b];
  const int sdiv = (L + 511) >> 9;
  const int new_len = (L + sdiv - 1) / sdiv;
  const size_t qbase = (size_t)b * 64 * 512 + h * 64;
  const size_t kbase = (size_t)b * 512 * 512 + h * 64;
#pragma unroll
  for (int rep = 0; rep < 4; ++rep) {
    const int gidx = rep * 256 + t;
    const int row = gidx >> 4, c = (gidx & 15) * 4;
    f32x4 v = *reinterpret_cast<const f32x4*>(&q[qbase + (size_t)row * 512 + c]);
    *reinterpret_cast<bf16x4*>(&Qs[row * 72 + c]) = cvt4(v);
  }
  f32x4 acc[32];
#pragma unroll
  for (int nt = 0; nt < 32; ++nt) acc[nt] = f32x4{0.f, 0.f, 0.f, 0.f};
  const int fr = lane & 15, fkq = (lane >> 4) * 8;
  for (int ks = 0; ks < 2; ++ks) {
    const int k0 = ks * 32;
#pragma unroll
    for (int rep = 0; rep < 16; ++rep) {
      const int gidx = rep * 256 + t;
      const int row = gidx >> 3, c = (gidx & 7) * 4;
      f32x4 v =
          *reinterpret_cast<const f32x4*>(&k[kbase + (size_t)row * 512 + k0 + c]);
      *reinterpret_cast<bf16x4*>(&Bs[row * 40 + c]) = cvt4(v);
    }
    __syncthreads();
    const bf16x8 af =
        *reinterpret_cast<const bf16x8*>(&Qs[(w * 16 + fr) * 72 + k0 + fkq]);
#pragma unroll
    for (int nt = 0; nt < 32; ++nt) {
      bf16x8 bf = *reinterpret_cast<const bf16x8*>(&Bs[(nt * 16 + fr) * 40 + fkq]);
      acc[nt] = mfma16(af, bf, acc[nt]);
    }
    __syncthreads();
  }
  const float scale = 0.125f;
  const size_t pb = (size_t)bh * 64 * 512;
#pragma unroll
  for (int r = 0; r < 4; ++r) {
    float mx = -3.0e38f;
#pragma unroll
    for (int nt = 0; nt < 32; ++nt) {
      const int col = nt * 16 + fr;
      const float sv = acc[nt][r] * scale;
      if (col < new_len) mx = fmaxf(mx, sv);
    }
#pragma unroll
    for (int off = 1; off < 16; off <<= 1) mx = fmaxf(mx, __shfl_xor(mx, off, 64));
    float sum = 0.f;
#pragma unroll
    for (int nt = 0; nt < 32; ++nt) {
      const int col = nt * 16 + fr;
      const float e = (col < new_len) ? __expf(acc[nt][r] * scale - mx) : 0.f;
      acc[nt][r] = e;
      sum += e;
    }
#pragma unroll
    for (int off = 1; off < 16; off <<= 1) sum += __shfl_xor(sum, off, 64);
    const float inv = 1.f / sum;
    const int row = w * 16 + ((lane >> 4) << 2) + r;
    __bf16* dst = P + pb + (size_t)row * 512 + fr;
#pragma unroll
    for (int nt = 0; nt < 32; ++nt) dst[nt * 16] = (__bf16)(acc[nt][r] * inv);
  }
}

// =====================================================================
// Attention stage 2: ctx = P_h(64x512 bf16) @ V_h(512x64).
// =====================================================================
__global__ __launch_bounds__(256) void attn_pv_kernel(
    const __bf16* __restrict__ P, const float* __restrict__ v,
    float* __restrict__ ctx) {
  __shared__ __bf16 As[64 * 40];
  __shared__ __bf16 Bs[64 * 40];
  const int t = threadIdx.x, lane = t & 63, w = t >> 6;
  const int bh = blockIdx.x, b = bh >> 3, h = bh & 7;
  const size_t pbase = (size_t)bh * 64 * 512;
  const size_t vbase = (size_t)b * 512 * 512 + h * 64;
  f32x4 acc[4];
#pragma unroll
  for (int j = 0; j < 4; ++j) acc[j] = f32x4{0.f, 0.f, 0.f, 0.f};
  const int fr = lane & 15, fk = (lane >> 4) * 8;
  const int arow = t >> 2, ac = (t & 3) * 8;
  const int bn = t & 63, bk = (t >> 6) * 8;
  for (int s = 0; s < 16; ++s) {
    const int k0 = s * 32;
    *reinterpret_cast<bf16x8*>(&As[arow * 40 + ac]) =
        *reinterpret_cast<const bf16x8*>(&P[pbase + (size_t)arow * 512 + k0 + ac]);
    {
      float tmp[8];
#pragma unroll
      for (int j = 0; j < 8; ++j)
        tmp[j] = v[vbase + (size_t)(k0 + bk + j) * 512 + bn];
      *reinterpret_cast<bf16x8*>(&Bs[bn * 40 + bk]) = cvt8(tmp);
    }
    __syncthreads();
    const bf16x8 a = *reinterpret_cast<const bf16x8*>(&As[(w * 16 + fr) * 40 + fk]);
#pragma unroll
    for (int j = 0; j < 4; ++j) {
      bf16x8 bfrag = *reinterpret_cast<const bf16x8*>(&Bs[(j * 16 + fr) * 40 + fk]);
      acc[j] = mfma16(a, bfrag, acc[j]);
    }
    __syncthreads();
  }
  const int rq = (lane >> 4) * 4;
  const size_t cbase = (size_t)b * 64 * 512 + h * 64;
#pragma unroll
  for (int j = 0; j < 4; ++j)
#pragma unroll
    for (int r = 0; r < 4; ++r)
      ctx[cbase + (size_t)(w * 16 + rq + r) * 512 + j * 16 + fr] = acc[j][r];
}

// LayerNorm over rows of 512, bf16 output into fusedbf[:, 512:1024]
__global__ __launch_bounds__(256) void ln_bf16_kernel(
    const float* __restrict__ x, const float* __restrict__ g,
    const float* __restrict__ bt, __bf16* __restrict__ ybf) {
  __shared__ float red[8];
  const int t = threadIdx.x;
  const size_t off = (size_t)blockIdx.x * 512;
  const float a = x[off + t], b2 = x[off + t + 256];
  float s = a + b2, sq = a * a + b2 * b2;
  blockRed2(s, sq, red);
  const float m = s * (1.f / 512.f);
  const float var = sq * (1.f / 512.f) - m * m;
  const float rs = rsqrtf(var + 1e-5f);
  __bf16* yrow = ybf + (size_t)blockIdx.x * 1024;
  yrow[t] = (__bf16)((a - m) * rs * g[t] + bt[t]);
  yrow[t + 256] = (__bf16)((b2 - m) * rs * g[t + 256] + bt[t + 256]);
}

// =====================================================================
// Workspace layout (live ranges by step):
//   ws+ 0.. 1 MB  low      (2-6)
//   ws+ 1.. 2 MB  qbuf     (6-7)
//   ws+ 2.. 3 MB  wtq (0-4) then ctxo (8)
//   ws+ 3.. 4 MB  fusedbf  (3-9)      <- never alias pbuf!
//   ws+ 4..28.5   partials bf16, 49 x 512KB (1-3, dead after 3)
//     overlaps:   pooled   ws+4..12   (4-5)
//                 pbuf 4MB ws+4..8    (7a-7b)
//                 kbuf     ws+12..20  (5-7)
//                 vbuf     ws+20..28  (5-7)
//   ws+28..29 MB  ctx      (7b-8)
//   ws+29..31.6   wtc      (3b-9)
// =====================================================================
extern "C" void kernel_launch(void* const* d_in, const int* in_sizes, int n_in,
                              void* d_out, int out_size, void* d_ws,
                              size_t ws_size, hipStream_t stream) {
  const float* images = (const float*)d_in[0];
  const float* qgrids = (const float*)d_in[1];
  const float* keypoints = (const float*)d_in[2];
  const int* qlens = (const int*)d_in[3];
  const float* W_img = (const float*)d_in[4];
  const float* b_img = (const float*)d_in[5];
  const float* W_kp = (const float*)d_in[6];
  const float* b_kp = (const float*)d_in[7];
  const float* g_kp = (const float*)d_in[8];
  const float* bt_kp = (const float*)d_in[9];
  const float* W_qp = (const float*)d_in[10];
  const float* b_qp = (const float*)d_in[11];
  const float* g_qln = (const float*)d_in[12];
  const float* bt_qln = (const float*)d_in[13];
  const float* Wq = (const float*)d_in[14];
  const float* bq = (const float*)d_in[15];
  const float* Wk = (const float*)d_in[16];
  const float* bk = (const float*)d_in[17];
  const float* Wv = (const float*)d_in[18];
  const float* bv = (const float*)d_in[19];
  const float* Wo = (const float*)d_in[20];
  const float* bo = (const float*)d_in[21];
  const float* g_attn = (const float*)d_in[22];
  const float* bt_attn = (const float*)d_in[23];
  const float* W_ctc = (const float*)d_in[24];
  const float* b_ctc = (const float*)d_in[25];
  float* out = (float*)d_out;

  const size_t MB = 1u << 20;
  if (ws_size < 32 * MB) return;
  char* ws = (char*)d_ws;
  float* low = (float*)(ws);                 // 1 MB
  float* qbuf = (float*)(ws + 1 * MB);       // 1 MB
  __bf16* wtq = (__bf16*)(ws + 2 * MB);      // 256 KB (dead after step 4)
  float* ctxo = (float*)(ws + 2 * MB);       // 1 MB (written step 8)
  __bf16* fusedbf = (__bf16*)(ws + 3 * MB);  // 1 MB (512x1024 bf16)
  __bf16* partials = (__bf16*)(ws + 4 * MB); // 24.5 MB bf16 (dead after 3)
  float* pooled = (float*)(ws + 4 * MB);     // 8 MB (steps 4-5)
  __bf16* pbuf = (__bf16*)(ws + 4 * MB);     // 4 MB (P; steps 7a-7b)
  float* kbuf = (float*)(ws + 12 * MB);      // 8 MB (5-7)
  float* vbuf = (float*)(ws + 20 * MB);      // 8 MB (5-7)
  float* ctx = (float*)(ws + 28 * MB);       // 1 MB (7b-8)
  __bf16* wtc = (__bf16*)(ws + 29 * MB);     // 2.6 MB Wt_ctc (3b-9)

  // 0) Wt_qp = transpose(W_qp) bf16, K padded to 256
  wqp_transpose_kernel<<<512, 256, 0, stream>>>(W_qp, wtq);
  // 1) img GEMM partials (split-K=49, bf16 partials, depth-2 pipeline)
  img_gemm_kernel<<<dim3(4, 4, SPLITK), 512, 0, stream>>>(images, W_img, partials);
  // 2) kp_feat -> low
  kp_kernel<<<512, 256, 0, stream>>>(keypoints, W_kp, b_kp, g_kp, bt_kp, low);
  // 3) low += b_img + sum(partials); also fusedbf[:, :512] = bf16(low)
  reduce_add_kernel<<<1024, 256, 0, stream>>>(partials, b_img, low, fusedbf);
  // 3b) Wt_ctc = transpose(W_ctc) bf16
  wctc_transpose_kernel<<<1296, 256, 0, stream>>>(W_ctc, wtc);
  // 4) pooled qgrid tokens (MFMA proj + LN + ragged mean-pool)
  pool_mfma_kernel<<<256, 512, 0, stream>>>(qgrids, qlens, wtq, b_qp, g_qln,
                                            bt_qln, pooled);
  // 5) k + v from pooled, fused launch
  kv_gemm_kernel<<<dim3(8, 64, 2), 256, 0, stream>>>(pooled, Wk, bk, Wv, bv,
                                                     kbuf, vbuf);
  // 6) q from low
  gemm_kernel<<<dim3(8, 8), 256, 0, stream>>>(low, Wq, bq, qbuf, 512, 512, 512, 1);
  // 7) fused attention: batched MFMA scores+softmax, then MFMA PV
  attn_scores_kernel<<<64, 256, 0, stream>>>(qbuf, kbuf, qlens, pbuf);
  attn_pv_kernel<<<64, 256, 0, stream>>>(pbuf, vbuf, ctx);
  // 8) ctx @ Wo + bo, then LN -> fusedbf[:, 512:] (bf16)
  gemm_kernel<<<dim3(8, 8), 256, 0, stream>>>(ctx, Wo, bo, ctxo, 512, 512, 512, 1);
  ln_bf16_kernel<<<512, 256, 0, stream>>>(ctxo, g_attn, bt_attn, fusedbf + 512);
  // 9) out = fusedbf @ Wt_ctc^T + b_ctc (register GEMM, no LDS/barriers)
  ctc_gemm_kernel<<<dim3(81, 8), 256, 0, stream>>>(fusedbf, wtc, b_ctc, out);
}

// Round 9
// 322.422 us; speedup vs baseline: 2.0627x; 1.0132x over previous
//
#include <hip/hip_runtime.h>
#include <hip/hip_bf16.h>

typedef __bf16 bf16x8 __attribute__((ext_vector_type(8)));
typedef __bf16 bf16x4 __attribute__((ext_vector_type(4)));
typedef float f32x4 __attribute__((ext_vector_type(4)));
typedef float f32x2 __attribute__((ext_vector_type(2)));

__device__ __forceinline__ f32x4 mfma16(bf16x8 a, bf16x8 b, f32x4 c) {
  return __builtin_amdgcn_mfma_f32_16x16x32_bf16(a, b, c, 0, 0, 0);
}

__device__ __forceinline__ bf16x8 cvt8(const float* f) {
  bf16x8 r;
#pragma unroll
  for (int i = 0; i < 8; ++i) r[i] = (__bf16)f[i];
  return r;
}

__device__ __forceinline__ bf16x4 cvt4(f32x4 v) {
  bf16x4 r;
#pragma unroll
  for (int i = 0; i < 4; ++i) r[i] = (__bf16)v[i];
  return r;
}

// ---- block reduction helpers (blockDim.x == 256 assumed, 4 waves) ----
__device__ __forceinline__ void blockRed2(float& a, float& b, float* red) {
#pragma unroll
  for (int off = 1; off < 64; off <<= 1) {
    a += __shfl_xor(a, off, 64);
    b += __shfl_xor(b, off, 64);
  }
  const int w = threadIdx.x >> 6;
  if ((threadIdx.x & 63) == 0) { red[w] = a; red[4 + w] = b; }
  __syncthreads();
  a = red[0] + red[1] + red[2] + red[3];
  b = red[4] + red[5] + red[6] + red[7];
  __syncthreads();
}

// =====================================================================
// Stage A: img_feat partials = images_flat(512x37632) @ W_img(37632x512)
// split-K=49, tile 128x128, 8 waves (wave tile 64x32), double-buffered
// LDS, DEPTH-3 register pipeline: loads issue 3 steps before use and
// commit to LDS 2 iterations after issue (depth-2 gave 2.35->2.81 TB/s;
// in-flight-bytes model says depth is the lever).
// =====================================================================
#define IMG_K 37632
#define SPLITK 49
#define STEPS_PER 24  // divisible by 6 (2-buf x 3-set unroll)

__global__ __launch_bounds__(512) void img_gemm_kernel(
    const float* __restrict__ A, const float* __restrict__ B,
    __bf16* __restrict__ partials) {
  __shared__ __bf16 As[2][128 * 40];
  __shared__ __bf16 Bs[2][128 * 40];
  const int t = threadIdx.x;
  const int lane = t & 63;
  const int w = t >> 6;
  const int wr = (w >> 2) * 64;
  const int wc = (w & 3) * 32;
  const int m0 = blockIdx.y * 128, n0 = blockIdx.x * 128;
  const int step0 = blockIdx.z * STEPS_PER;

  f32x4 acc[4][2];
#pragma unroll
  for (int i = 0; i < 4; ++i)
#pragma unroll
    for (int j = 0; j < 2; ++j) acc[i][j] = f32x4{0.f, 0.f, 0.f, 0.f};

  const int ar = t >> 2, ak = (t & 3) * 8;
  const int bn = t & 127, bk = (t >> 7) * 8;
  const int fr = lane & 15, fk = (lane >> 4) * 8;

  float r0a[8], r0b[8], r1a[8], r1b[8], r2a[8], r2b[8];
#define IMG_LOAD(AT, BT, K0)                                                \
  do {                                                                      \
    const float* asrc = A + (size_t)(m0 + ar) * IMG_K + (K0) + ak;          \
    f32x4 v0 = *reinterpret_cast<const f32x4*>(asrc);                       \
    f32x4 v1 = *reinterpret_cast<const f32x4*>(asrc + 4);                   \
    AT[0] = v0[0]; AT[1] = v0[1]; AT[2] = v0[2]; AT[3] = v0[3];             \
    AT[4] = v1[0]; AT[5] = v1[1]; AT[6] = v1[2]; AT[7] = v1[3];             \
    const float* bsrc = B + (size_t)((K0) + bk) * 512 + n0 + bn;            \
    _Pragma("unroll") for (int j = 0; j < 8; ++j) BT[j] =                   \
        bsrc[(size_t)j * 512];                                              \
  } while (0)
#define IMG_WRITE(BUF, AT, BT)                                              \
  do {                                                                      \
    *reinterpret_cast<bf16x8*>(&As[BUF][ar * 40 + ak]) = cvt8(AT);          \
    *reinterpret_cast<bf16x8*>(&Bs[BUF][bn * 40 + bk]) = cvt8(BT);          \
  } while (0)
#define IMG_MFMA(BUF)                                                       \
  do {                                                                      \
    bf16x8 af[4], bfr[2];                                                   \
    _Pragma("unroll") for (int i = 0; i < 4; ++i) af[i] =                   \
        *reinterpret_cast<const bf16x8*>(                                   \
            &As[BUF][(wr + i * 16 + fr) * 40 + fk]);                        \
    _Pragma("unroll") for (int j = 0; j < 2; ++j) bfr[j] =                  \
        *reinterpret_cast<const bf16x8*>(                                   \
            &Bs[BUF][(wc + j * 16 + fr) * 40 + fk]);                        \
    _Pragma("unroll") for (int i = 0; i < 4; ++i)                           \
        _Pragma("unroll") for (int j = 0; j < 2; ++j) acc[i][j] =           \
            mfma16(af[i], bfr[j], acc[i][j]);                               \
  } while (0)
  // step s: load set s%3 (data k_{s+3}); mfma buf s&1;
  //         write buf (s+1)&1 <- set (s+1)%3 (data k_{s+1}, issued s-2)
#define IMG_STEP(S, BUF, WBUF, LA, LB, WA, WB)                              \
  do {                                                                      \
    if ((S) + 3 < STEPS_PER) IMG_LOAD(LA, LB, (step0 + (S) + 3) * 32);      \
    IMG_MFMA(BUF);                                                          \
    if ((S) + 1 < STEPS_PER) IMG_WRITE(WBUF, WA, WB);                       \
    __syncthreads();                                                        \
  } while (0)

  // prologue: k0 committed to buf0; k1,k2 in registers/in flight
  IMG_LOAD(r0a, r0b, step0 * 32);
  IMG_WRITE(0, r0a, r0b);
  IMG_LOAD(r1a, r1b, (step0 + 1) * 32);
  IMG_LOAD(r2a, r2b, (step0 + 2) * 32);
  __syncthreads();

  for (int s6 = 0; s6 < STEPS_PER; s6 += 6) {
    IMG_STEP(s6 + 0, 0, 1, r0a, r0b, r1a, r1b);
    IMG_STEP(s6 + 1, 1, 0, r1a, r1b, r2a, r2b);
    IMG_STEP(s6 + 2, 0, 1, r2a, r2b, r0a, r0b);
    IMG_STEP(s6 + 3, 1, 0, r0a, r0b, r1a, r1b);
    IMG_STEP(s6 + 4, 0, 1, r1a, r1b, r2a, r2b);
    IMG_STEP(s6 + 5, 1, 0, r2a, r2b, r0a, r0b);
  }
#undef IMG_LOAD
#undef IMG_WRITE
#undef IMG_MFMA
#undef IMG_STEP

  __bf16* P = partials + (size_t)blockIdx.z * (512 * 512);
  const int rq = (lane >> 4) * 4;
#pragma unroll
  for (int i = 0; i < 4; ++i)
#pragma unroll
    for (int j = 0; j < 2; ++j)
#pragma unroll
      for (int r = 0; r < 4; ++r)
        P[(size_t)(m0 + wr + i * 16 + rq + r) * 512 + (n0 + wc + j * 16 + fr)] =
            (__bf16)acc[i][j][r];
}

// low[idx] = kp_feat(already there) + b_img + sum_z partials[z][idx];
// also writes bf16 copy into fusedbf[:, 0:512] (row stride 1024).
__global__ __launch_bounds__(256) void reduce_add_kernel(
    const __bf16* __restrict__ partials, const float* __restrict__ b_img,
    float* __restrict__ low, __bf16* __restrict__ fusedbf) {
  const int idx = blockIdx.x * 256 + threadIdx.x;
  float acc = low[idx] + b_img[idx & 511];
#pragma unroll
  for (int z = 0; z < SPLITK; ++z)
    acc += (float)partials[(size_t)z * 262144 + idx];
  low[idx] = acc;
  fusedbf[(size_t)(idx >> 9) * 1024 + (idx & 511)] = (__bf16)acc;
}

// =====================================================================
// kp_feat = LN(relu(keypoints @ W_kp + b_kp)); one block per row (512)
// =====================================================================
__global__ __launch_bounds__(256) void kp_kernel(
    const float* __restrict__ kp, const float* __restrict__ W,
    const float* __restrict__ bias, const float* __restrict__ g,
    const float* __restrict__ bt, float* __restrict__ low) {
  __shared__ float rowv[242];
  __shared__ float red[8];
  const int t = threadIdx.x;
  const size_t roff = (size_t)blockIdx.x * 242;
  if (t < 242) rowv[t] = kp[roff + t];
  __syncthreads();
  const int d0 = t, d1 = t + 256;
  float p0 = bias[d0], p1 = bias[d1];
  for (int kk = 0; kk < 242; ++kk) {
    const float x = rowv[kk];
    p0 = fmaf(x, W[kk * 512 + d0], p0);
    p1 = fmaf(x, W[kk * 512 + d1], p1);
  }
  p0 = fmaxf(p0, 0.f);
  p1 = fmaxf(p1, 0.f);
  float s = p0 + p1, sq = p0 * p0 + p1 * p1;
  blockRed2(s, sq, red);
  const float m = s * (1.f / 512.f);
  const float var = sq * (1.f / 512.f) - m * m;
  const float rs = rsqrtf(var + 1e-5f);
  const size_t off = (size_t)blockIdx.x * 512;
  low[off + d0] = (p0 - m) * rs * g[d0] + bt[d0];
  low[off + d1] = (p1 - m) * rs * g[d1] + bt[d1];
}

// =====================================================================
// W_qp transpose+convert: Wt[col][k] bf16, k padded 242 -> 256 (zeros).
// =====================================================================
__global__ __launch_bounds__(256) void wqp_transpose_kernel(
    const float* __restrict__ W, __bf16* __restrict__ Wt) {
  const int c = blockIdx.x;   // 512 output columns
  const int t = threadIdx.x;  // 256 k slots
  Wt[(size_t)c * 256 + t] = (t < 242) ? (__bf16)W[(size_t)t * 512 + c] : (__bf16)0.f;
}

// =====================================================================
// W_ctc transpose+convert (LDS-tiled, coalesced both sides):
// Wt[c][k] bf16 = W[k][c], W is [1024][1296] f32. 32x32 tiles.
// (Old version read dwords at 5184B stride -> ~85 MB effective fetch.)
// =====================================================================
__global__ __launch_bounds__(256) void wctc_transpose_kernel(
    const float* __restrict__ W, __bf16* __restrict__ Wt) {
  __shared__ float T[32][33];
  const int t = threadIdx.x;
  const int c0 = blockIdx.x * 32;  // 41 blocks over 1296 cols
  const int k0 = blockIdx.y * 32;  // 32 blocks over 1024 rows
#pragma unroll
  for (int r = 0; r < 4; ++r) {
    const int idx = r * 256 + t;
    const int i = idx >> 5, j = idx & 31;
    const int c = c0 + j;
    T[i][j] = (c < 1296) ? W[(size_t)(k0 + i) * 1296 + c] : 0.f;
  }
  __syncthreads();
#pragma unroll
  for (int r = 0; r < 4; ++r) {
    const int idx = r * 256 + t;
    const int i = idx >> 5, j = idx & 31;
    const int c = c0 + i;
    if (c < 1296) Wt[(size_t)c * 1024 + k0 + j] = (__bf16)T[j][i];
  }
}

// =====================================================================
// Fused MFMA pooling: pooled = pool_mean(LN(qgrids @ W_qp + b_qp)).
// Output bf16 (consumer kv_gemm casts to bf16 anyway -> same numerics).
// =====================================================================
__global__ __launch_bounds__(512) void pool_mfma_kernel(
    const float* __restrict__ qgrids, const int* __restrict__ lens,
    const __bf16* __restrict__ Wt, const float* __restrict__ bias,
    const float* __restrict__ g, const float* __restrict__ bt,
    __bf16* __restrict__ pooled) {
  __shared__ float red[8][16][2];
  const int t = threadIdx.x, lane = t & 63, w = t >> 6;
  const int b = blockIdx.x >> 5;          // 8 batches
  const int j0 = (blockIdx.x & 31) * 16;  // pooled-row block
  const int L = lens[b];
  int S = (L + 511) >> 9;
  if (S < 1) S = 1;
  const int new_len = (L + S - 1) / S;
  const float* qg_b = qgrids + (size_t)b * 4096 * 242;
  __bf16* pooled_b = pooled + (size_t)b * 512 * 512;

  const int fr = lane & 15;
  const int fq = lane >> 4;
  const int fkq = fq * 8;
  const int colbase = w * 64;

  float biasv[4], gv[4], btv[4];
#pragma unroll
  for (int nt = 0; nt < 4; ++nt) {
    const int col = colbase + nt * 16 + fr;
    biasv[nt] = bias[col];
    gv[nt] = g[col];
    btv[nt] = bt[col];
  }

  f32x4 pool[4];
#pragma unroll
  for (int nt = 0; nt < 4; ++nt) pool[nt] = f32x4{0.f, 0.f, 0.f, 0.f};

  for (int i = 0; i < S; ++i) {
    const int arow = (j0 + fr) * S + i;
    const float* asrc = qg_b + (size_t)arow * 242;
    f32x4 acc[4];
#pragma unroll
    for (int nt = 0; nt < 4; ++nt) acc[nt] = f32x4{0.f, 0.f, 0.f, 0.f};
#pragma unroll
    for (int ks = 0; ks < 8; ++ks) {
      bf16x8 af;
      if (ks < 7) {
        float tmp[8];
#pragma unroll
        for (int p2 = 0; p2 < 4; ++p2) {
          f32x2 v = *reinterpret_cast<const f32x2*>(asrc + ks * 32 + fkq + p2 * 2);
          tmp[p2 * 2] = v[0];
          tmp[p2 * 2 + 1] = v[1];
        }
        af = cvt8(tmp);
      } else {
        float tmp[8];
#pragma unroll
        for (int jj = 0; jj < 8; ++jj) {
          const int kk = 224 + fkq + jj;
          tmp[jj] = (kk < 242) ? asrc[kk] : 0.f;
        }
        af = cvt8(tmp);
      }
      const __bf16* wt = Wt + ks * 32 + fkq;
#pragma unroll
      for (int nt = 0; nt < 4; ++nt) {
        bf16x8 bfv = *reinterpret_cast<const bf16x8*>(
            wt + (size_t)(colbase + nt * 16 + fr) * 256);
        acc[nt] = mfma16(af, bfv, acc[nt]);
      }
    }
    float s[4] = {0.f, 0.f, 0.f, 0.f}, sq[4] = {0.f, 0.f, 0.f, 0.f};
#pragma unroll
    for (int nt = 0; nt < 4; ++nt) {
#pragma unroll
      for (int r = 0; r < 4; ++r) {
        const float v = acc[nt][r] + biasv[nt];
        acc[nt][r] = v;
        s[r] += v;
        sq[r] += v * v;
      }
    }
#pragma unroll
    for (int off = 1; off < 16; off <<= 1) {
#pragma unroll
      for (int r = 0; r < 4; ++r) {
        s[r] += __shfl_xor(s[r], off, 64);
        sq[r] += __shfl_xor(sq[r], off, 64);
      }
    }
    if (fr == 0) {
#pragma unroll
      for (int r = 0; r < 4; ++r) {
        red[w][fq * 4 + r][0] = s[r];
        red[w][fq * 4 + r][1] = sq[r];
      }
    }
    __syncthreads();
    float mean[4], rsig[4];
#pragma unroll
    for (int r = 0; r < 4; ++r) {
      const int p = fq * 4 + r;
      float ss = 0.f, qq = 0.f;
#pragma unroll
      for (int ww = 0; ww < 8; ++ww) {
        ss += red[ww][p][0];
        qq += red[ww][p][1];
      }
      const float m = ss * (1.f / 512.f);
      mean[r] = m;
      rsig[r] = rsqrtf(qq * (1.f / 512.f) - m * m + 1e-5f);
    }
    __syncthreads();
#pragma unroll
    for (int r = 0; r < 4; ++r) {
      const int srow = (j0 + fq * 4 + r) * S + i;
      const bool ok = srow < L;
#pragma unroll
      for (int nt = 0; nt < 4; ++nt) {
        const float nv = (acc[nt][r] - mean[r]) * rsig[r] * gv[nt] + btv[nt];
        pool[nt][r] += ok ? nv : 0.f;
      }
    }
  }
  const float inv = 1.f / (float)S;
#pragma unroll
  for (int r = 0; r < 4; ++r) {
    const int j = j0 + fq * 4 + r;
    const bool ok = j < new_len;
#pragma unroll
    for (int nt = 0; nt < 4; ++nt)
      pooled_b[(size_t)j * 512 + colbase + nt * 16 + fr] =
          (__bf16)(ok ? pool[nt][r] * inv : 0.f);
  }
}

// =====================================================================
// Generic bf16-MFMA GEMM (f32 in/out): C = A@B (+bias/accumulate).
// =====================================================================
__global__ __launch_bounds__(256) void gemm_kernel(
    const float* __restrict__ A, const float* __restrict__ B,
    const float* __restrict__ bias, float* __restrict__ C, int M, int N,
    int K, int flags) {
  __shared__ __bf16 As[64 * 40];
  __shared__ __bf16 Bs[64 * 40];
  const int t = threadIdx.x, lane = t & 63, w = t >> 6;
  const int m0 = blockIdx.y * 64, n0 = blockIdx.x * 64;
  f32x4 acc[4];
#pragma unroll
  for (int j = 0; j < 4; ++j) acc[j] = f32x4{0.f, 0.f, 0.f, 0.f};
  const int ar = t >> 2, ak = (t & 3) * 8;
  const int bn = t & 63, bk = (t >> 6) * 8;
  const int fr = lane & 15, fk = (lane >> 4) * 8;
  const int col = n0 + bn;
  const bool colok = col < N;
  const int nst = K >> 5;
  for (int s = 0; s < nst; ++s) {
    const int k0 = s * 32;
    {
      const float* src = A + (size_t)(m0 + ar) * K + k0 + ak;
      f32x4 v0 = *reinterpret_cast<const f32x4*>(src);
      f32x4 v1 = *reinterpret_cast<const f32x4*>(src + 4);
      float tmp[8] = {v0[0], v0[1], v0[2], v0[3], v1[0], v1[1], v1[2], v1[3]};
      *reinterpret_cast<bf16x8*>(&As[ar * 40 + ak]) = cvt8(tmp);
    }
    {
      float tmp[8];
#pragma unroll
      for (int j = 0; j < 8; ++j)
        tmp[j] = colok ? B[(size_t)(k0 + bk + j) * N + col] : 0.f;
      *reinterpret_cast<bf16x8*>(&Bs[bn * 40 + bk]) = cvt8(tmp);
    }
    __syncthreads();
    bf16x8 a = *reinterpret_cast<const bf16x8*>(&As[(w * 16 + fr) * 40 + fk]);
#pragma unroll
    for (int j = 0; j < 4; ++j) {
      bf16x8 b = *reinterpret_cast<const bf16x8*>(&Bs[(j * 16 + fr) * 40 + fk]);
      acc[j] = mfma16(a, b, acc[j]);
    }
    __syncthreads();
  }
  const int rq = (lane >> 4) * 4;
#pragma unroll
  for (int j = 0; j < 4; ++j) {
    const int c = n0 + j * 16 + fr;
    if (c < N) {
#pragma unroll
      for (int r = 0; r < 4; ++r) {
        const size_t idx = (size_t)(m0 + w * 16 + rq + r) * N + c;
        float v = acc[j][r];
        if (flags & 1) v += bias[c];
        if (flags & 2) v += C[idx];
        C[idx] = v;
      }
    }
  }
}

// =====================================================================
// Fused K+V GEMM: A is bf16 [4096][512]; outputs bf16 (consumers cast
// to bf16 anyway -> identical numerics, half the traffic).
// =====================================================================
__global__ __launch_bounds__(256) void kv_gemm_kernel(
    const __bf16* __restrict__ A, const float* __restrict__ Wk,
    const float* __restrict__ bk, const float* __restrict__ Wv,
    const float* __restrict__ bv, __bf16* __restrict__ kout,
    __bf16* __restrict__ vout) {
  __shared__ __bf16 As[64 * 40];
  __shared__ __bf16 Bs[64 * 40];
  const float* B = blockIdx.z ? Wv : Wk;
  const float* bias = blockIdx.z ? bv : bk;
  __bf16* C = blockIdx.z ? vout : kout;
  const int t = threadIdx.x, lane = t & 63, w = t >> 6;
  const int m0 = blockIdx.y * 64, n0 = blockIdx.x * 64;
  f32x4 acc[4];
#pragma unroll
  for (int j = 0; j < 4; ++j) acc[j] = f32x4{0.f, 0.f, 0.f, 0.f};
  const int ar = t >> 2, ak = (t & 3) * 8;
  const int bn = t & 63, bk2 = (t >> 6) * 8;
  const int fr = lane & 15, fk = (lane >> 4) * 8;
  const int col = n0 + bn;
  for (int s = 0; s < 16; ++s) {
    const int k0 = s * 32;
    *reinterpret_cast<bf16x8*>(&As[ar * 40 + ak]) =
        *reinterpret_cast<const bf16x8*>(A + (size_t)(m0 + ar) * 512 + k0 + ak);
    {
      float tmp[8];
#pragma unroll
      for (int j = 0; j < 8; ++j)
        tmp[j] = B[(size_t)(k0 + bk2 + j) * 512 + col];
      *reinterpret_cast<bf16x8*>(&Bs[bn * 40 + bk2]) = cvt8(tmp);
    }
    __syncthreads();
    bf16x8 a = *reinterpret_cast<const bf16x8*>(&As[(w * 16 + fr) * 40 + fk]);
#pragma unroll
    for (int j = 0; j < 4; ++j) {
      bf16x8 b2 = *reinterpret_cast<const bf16x8*>(&Bs[(j * 16 + fr) * 40 + fk]);
      acc[j] = mfma16(a, b2, acc[j]);
    }
    __syncthreads();
  }
  const int rq = (lane >> 4) * 4;
#pragma unroll
  for (int j = 0; j < 4; ++j) {
    const int c = n0 + j * 16 + fr;
#pragma unroll
    for (int r = 0; r < 4; ++r)
      C[(size_t)(m0 + w * 16 + rq + r) * 512 + c] = (__bf16)(acc[j][r] + bias[c]);
  }
}

// =====================================================================
// CTC head, no-LDS register GEMM: out[512,1296] = fusedbf @ Wt^T + bias.
// =====================================================================
__global__ __launch_bounds__(256) void ctc_gemm_kernel(
    const __bf16* __restrict__ A, const __bf16* __restrict__ Wt,
    const float* __restrict__ bias, float* __restrict__ out) {
  const int t = threadIdx.x, lane = t & 63, w = t >> 6;
  const int n0 = blockIdx.x * 16;
  const int m0 = blockIdx.y * 64 + w * 16;
  const int fr = lane & 15, fq = lane >> 4;
  const __bf16* arow = A + (size_t)(m0 + fr) * 1024 + fq * 8;
  const __bf16* brow = Wt + (size_t)(n0 + fr) * 1024 + fq * 8;
  f32x4 acc = f32x4{0.f, 0.f, 0.f, 0.f};
#pragma unroll
  for (int ks = 0; ks < 32; ++ks) {
    bf16x8 a = *reinterpret_cast<const bf16x8*>(arow + ks * 32);
    bf16x8 b = *reinterpret_cast<const bf16x8*>(brow + ks * 32);
    acc = mfma16(a, b, acc);
  }
  const int col = n0 + fr;
  const float bv = bias[col];
  const int r0 = m0 + fq * 4;
#pragma unroll
  for (int r = 0; r < 4; ++r)
    out[(size_t)(r0 + r) * 1296 + col] = acc[r] + bv;
}

// =====================================================================
// Attention stage 1: P = softmax(mask(Q_h @ K_h^T / 8)) as bf16.
// K is bf16 (written by kv_gemm) -> staging is a straight copy.
// =====================================================================
__global__ __launch_bounds__(256) void attn_scores_kernel(
    const float* __restrict__ q, const __bf16* __restrict__ k,
    const int* __restrict__ lens, __bf16* __restrict__ P) {
  __shared__ __bf16 Qs[64 * 72];
  __shared__ __bf16 Bs[512 * 40];
  const int t = threadIdx.x, lane = t & 63, w = t >> 6;
  const int bh = blockIdx.x, b = bh >> 3, h = bh & 7;
  const int L = lens[b];
  const int sdiv = (L + 511) >> 9;
  const int new_len = (L + sdiv - 1) / sdiv;
  const size_t qbase = (size_t)b * 64 * 512 + h * 64;
  const size_t kbase = (size_t)b * 512 * 512 + h * 64;
#pragma unroll
  for (int rep = 0; rep < 4; ++rep) {
    const int gidx = rep * 256 + t;
    const int row = gidx >> 4, c = (gidx & 15) * 4;
    f32x4 v = *reinterpret_cast<const f32x4*>(&q[qbase + (size_t)row * 512 + c]);
    *reinterpret_cast<bf16x4*>(&Qs[row * 72 + c]) = cvt4(v);
  }
  f32x4 acc[32];
#pragma unroll
  for (int nt = 0; nt < 32; ++nt) acc[nt] = f32x4{0.f, 0.f, 0.f, 0.f};
  const int fr = lane & 15, fkq = (lane >> 4) * 8;
  for (int ks = 0; ks < 2; ++ks) {
    const int k0 = ks * 32;
#pragma unroll
    for (int rep = 0; rep < 16; ++rep) {
      const int gidx = rep * 256 + t;
      const int row = gidx >> 3, c = (gidx & 7) * 4;
      *reinterpret_cast<bf16x4*>(&Bs[row * 40 + c]) =
          *reinterpret_cast<const bf16x4*>(&k[kbase + (size_t)row * 512 + k0 + c]);
    }
    __syncthreads();
    const bf16x8 af =
        *reinterpret_cast<const bf16x8*>(&Qs[(w * 16 + fr) * 72 + k0 + fkq]);
#pragma unroll
    for (int nt = 0; nt < 32; ++nt) {
      bf16x8 bf = *reinterpret_cast<const bf16x8*>(&Bs[(nt * 16 + fr) * 40 + fkq]);
      acc[nt] = mfma16(af, bf, acc[nt]);
    }
    __syncthreads();
  }
  const float scale = 0.125f;
  const size_t pb = (size_t)bh * 64 * 512;
#pragma unroll
  for (int r = 0; r < 4; ++r) {
    float mx = -3.0e38f;
#pragma unroll
    for (int nt = 0; nt < 32; ++nt) {
      const int col = nt * 16 + fr;
      const float sv = acc[nt][r] * scale;
      if (col < new_len) mx = fmaxf(mx, sv);
    }
#pragma unroll
    for (int off = 1; off < 16; off <<= 1) mx = fmaxf(mx, __shfl_xor(mx, off, 64));
    float sum = 0.f;
#pragma unroll
    for (int nt = 0; nt < 32; ++nt) {
      const int col = nt * 16 + fr;
      const float e = (col < new_len) ? __expf(acc[nt][r] * scale - mx) : 0.f;
      acc[nt][r] = e;
      sum += e;
    }
#pragma unroll
    for (int off = 1; off < 16; off <<= 1) sum += __shfl_xor(sum, off, 64);
    const float inv = 1.f / sum;
    const int row = w * 16 + ((lane >> 4) << 2) + r;
    __bf16* dst = P + pb + (size_t)row * 512 + fr;
#pragma unroll
    for (int nt = 0; nt < 32; ++nt) dst[nt * 16] = (__bf16)(acc[nt][r] * inv);
  }
}

// =====================================================================
// Attention stage 2: ctx = P_h(64x512 bf16) @ V_h(512x64 bf16).
// =====================================================================
__global__ __launch_bounds__(256) void attn_pv_kernel(
    const __bf16* __restrict__ P, const __bf16* __restrict__ v,
    float* __restrict__ ctx) {
  __shared__ __bf16 As[64 * 40];
  __shared__ __bf16 Bs[64 * 40];
  const int t = threadIdx.x, lane = t & 63, w = t >> 6;
  const int bh = blockIdx.x, b = bh >> 3, h = bh & 7;
  const size_t pbase = (size_t)bh * 64 * 512;
  const size_t vbase = (size_t)b * 512 * 512 + h * 64;
  f32x4 acc[4];
#pragma unroll
  for (int j = 0; j < 4; ++j) acc[j] = f32x4{0.f, 0.f, 0.f, 0.f};
  const int fr = lane & 15, fk = (lane >> 4) * 8;
  const int arow = t >> 2, ac = (t & 3) * 8;
  const int bn = t & 63, bk = (t >> 6) * 8;
  for (int s = 0; s < 16; ++s) {
    const int k0 = s * 32;
    *reinterpret_cast<bf16x8*>(&As[arow * 40 + ac]) =
        *reinterpret_cast<const bf16x8*>(&P[pbase + (size_t)arow * 512 + k0 + ac]);
    {
      bf16x8 tmp;
#pragma unroll
      for (int j = 0; j < 8; ++j)
        tmp[j] = v[vbase + (size_t)(k0 + bk + j) * 512 + bn];
      *reinterpret_cast<bf16x8*>(&Bs[bn * 40 + bk]) = tmp;
    }
    __syncthreads();
    const bf16x8 a = *reinterpret_cast<const bf16x8*>(&As[(w * 16 + fr) * 40 + fk]);
#pragma unroll
    for (int j = 0; j < 4; ++j) {
      bf16x8 bfrag = *reinterpret_cast<const bf16x8*>(&Bs[(j * 16 + fr) * 40 + fk]);
      acc[j] = mfma16(a, bfrag, acc[j]);
    }
    __syncthreads();
  }
  const int rq = (lane >> 4) * 4;
  const size_t cbase = (size_t)b * 64 * 512 + h * 64;
#pragma unroll
  for (int j = 0; j < 4; ++j)
#pragma unroll
    for (int r = 0; r < 4; ++r)
      ctx[cbase + (size_t)(w * 16 + rq + r) * 512 + j * 16 + fr] = acc[j][r];
}

// LayerNorm over rows of 512, bf16 output into fusedbf[:, 512:1024]
__global__ __launch_bounds__(256) void ln_bf16_kernel(
    const float* __restrict__ x, const float* __restrict__ g,
    const float* __restrict__ bt, __bf16* __restrict__ ybf) {
  __shared__ float red[8];
  const int t = threadIdx.x;
  const size_t off = (size_t)blockIdx.x * 512;
  const float a = x[off + t], b2 = x[off + t + 256];
  float s = a + b2, sq = a * a + b2 * b2;
  blockRed2(s, sq, red);
  const float m = s * (1.f / 512.f);
  const float var = sq * (1.f / 512.f) - m * m;
  const float rs = rsqrtf(var + 1e-5f);
  __bf16* yrow = ybf + (size_t)blockIdx.x * 1024;
  yrow[t] = (__bf16)((a - m) * rs * g[t] + bt[t]);
  yrow[t + 256] = (__bf16)((b2 - m) * rs * g[t + 256] + bt[t + 256]);
}

// =====================================================================
// Workspace layout (live ranges by step):
//   ws+ 0.. 1 MB  low      (2-6)
//   ws+ 1.. 2 MB  qbuf     (6-7)
//   ws+ 2.. 3 MB  wtq (0-4) then ctxo (8)
//   ws+ 3.. 4 MB  fusedbf  (3-9)      <- never alias pbuf!
//   ws+ 4..28.5   partials bf16 49x512KB (1-3, dead after 3)
//     overlaps:   pooled bf16 ws+4..8   (4-5)
//                 pbuf   4MB  ws+4..8   (7a-7b, after pooled dead)
//                 kbuf   bf16 ws+12..16 (5-7)
//                 vbuf   bf16 ws+16..20 (5-7)
//   ws+28..29 MB  ctx      (7b-8, partials dead)
//   ws+29..31.6   wtc      (3b-9)
// =====================================================================
extern "C" void kernel_launch(void* const* d_in, const int* in_sizes, int n_in,
                              void* d_out, int out_size, void* d_ws,
                              size_t ws_size, hipStream_t stream) {
  const float* images = (const float*)d_in[0];
  const float* qgrids = (const float*)d_in[1];
  const float* keypoints = (const float*)d_in[2];
  const int* qlens = (const int*)d_in[3];
  const float* W_img = (const float*)d_in[4];
  const float* b_img = (const float*)d_in[5];
  const float* W_kp = (const float*)d_in[6];
  const float* b_kp = (const float*)d_in[7];
  const float* g_kp = (const float*)d_in[8];
  const float* bt_kp = (const float*)d_in[9];
  const float* W_qp = (const float*)d_in[10];
  const float* b_qp = (const float*)d_in[11];
  const float* g_qln = (const float*)d_in[12];
  const float* bt_qln = (const float*)d_in[13];
  const float* Wq = (const float*)d_in[14];
  const float* bq = (const float*)d_in[15];
  const float* Wk = (const float*)d_in[16];
  const float* bk = (const float*)d_in[17];
  const float* Wv = (const float*)d_in[18];
  const float* bv = (const float*)d_in[19];
  const float* Wo = (const float*)d_in[20];
  const float* bo = (const float*)d_in[21];
  const float* g_attn = (const float*)d_in[22];
  const float* bt_attn = (const float*)d_in[23];
  const float* W_ctc = (const float*)d_in[24];
  const float* b_ctc = (const float*)d_in[25];
  float* out = (float*)d_out;

  const size_t MB = 1u << 20;
  if (ws_size < 32 * MB) return;
  char* ws = (char*)d_ws;
  float* low = (float*)(ws);                 // 1 MB
  float* qbuf = (float*)(ws + 1 * MB);       // 1 MB
  __bf16* wtq = (__bf16*)(ws + 2 * MB);      // 256 KB (dead after step 4)
  float* ctxo = (float*)(ws + 2 * MB);       // 1 MB (written step 8)
  __bf16* fusedbf = (__bf16*)(ws + 3 * MB);  // 1 MB (512x1024 bf16)
  __bf16* partials = (__bf16*)(ws + 4 * MB); // 24.5 MB bf16 (dead after 3)
  __bf16* pooled = (__bf16*)(ws + 4 * MB);   // 4 MB bf16 (steps 4-5)
  __bf16* pbuf = (__bf16*)(ws + 4 * MB);     // 4 MB (P; steps 7a-7b)
  __bf16* kbuf = (__bf16*)(ws + 12 * MB);    // 4 MB bf16 (5-7)
  __bf16* vbuf = (__bf16*)(ws + 16 * MB);    // 4 MB bf16 (5-7)
  float* ctx = (float*)(ws + 28 * MB);       // 1 MB (7b-8)
  __bf16* wtc = (__bf16*)(ws + 29 * MB);     // 2.6 MB Wt_ctc (3b-9)

  // 0) Wt_qp = transpose(W_qp) bf16, K padded to 256
  wqp_transpose_kernel<<<512, 256, 0, stream>>>(W_qp, wtq);
  // 1) img GEMM partials (split-K=49, bf16 partials, depth-3 pipeline)
  img_gemm_kernel<<<dim3(4, 4, SPLITK), 512, 0, stream>>>(images, W_img, partials);
  // 2) kp_feat -> low
  kp_kernel<<<512, 256, 0, stream>>>(keypoints, W_kp, b_kp, g_kp, bt_kp, low);
  // 3) low += b_img + sum(partials); also fusedbf[:, :512] = bf16(low)
  reduce_add_kernel<<<1024, 256, 0, stream>>>(partials, b_img, low, fusedbf);
  // 3b) Wt_ctc = transpose(W_ctc) bf16 (tiled, coalesced)
  wctc_transpose_kernel<<<dim3(41, 32), 256, 0, stream>>>(W_ctc, wtc);
  // 4) pooled qgrid tokens (MFMA proj + LN + ragged mean-pool) -> bf16
  pool_mfma_kernel<<<256, 512, 0, stream>>>(qgrids, qlens, wtq, b_qp, g_qln,
                                            bt_qln, pooled);
  // 5) k + v from pooled (bf16 in, bf16 out), fused launch
  kv_gemm_kernel<<<dim3(8, 64, 2), 256, 0, stream>>>(pooled, Wk, bk, Wv, bv,
                                                     kbuf, vbuf);
  // 6) q from low
  gemm_kernel<<<dim3(8, 8), 256, 0, stream>>>(low, Wq, bq, qbuf, 512, 512, 512, 1);
  // 7) fused attention: batched MFMA scores+softmax, then MFMA PV
  attn_scores_kernel<<<64, 256, 0, stream>>>(qbuf, kbuf, qlens, pbuf);
  attn_pv_kernel<<<64, 256, 0, stream>>>(pbuf, vbuf, ctx);
  // 8) ctx @ Wo + bo, then LN -> fusedbf[:, 512:] (bf16)
  gemm_kernel<<<dim3(8, 8), 256, 0, stream>>>(ctx, Wo, bo, ctxo, 512, 512, 512, 1);
  ln_bf16_kernel<<<512, 256, 0, stream>>>(ctxo, g_attn, bt_attn, fusedbf + 512);
  // 9) out = fusedbf @ Wt_ctc^T + b_ctc (register GEMM, no LDS/barriers)
  ctc_gemm_kernel<<<dim3(81, 8), 256, 0, stream>>>(fusedbf, wtc, b_ctc, out);
}

// Round 10
// 263.427 us; speedup vs baseline: 2.5246x; 1.2239x over previous
//
#include <hip/hip_runtime.h>
#include <hip/hip_bf16.h>

typedef __bf16 bf16x8 __attribute__((ext_vector_type(8)));
typedef __bf16 bf16x4 __attribute__((ext_vector_type(4)));
typedef float f32x4 __attribute__((ext_vector_type(4)));
typedef float f32x2 __attribute__((ext_vector_type(2)));

__device__ __forceinline__ f32x4 mfma16(bf16x8 a, bf16x8 b, f32x4 c) {
  return __builtin_amdgcn_mfma_f32_16x16x32_bf16(a, b, c, 0, 0, 0);
}

__device__ __forceinline__ bf16x8 cvt8(const float* f) {
  bf16x8 r;
#pragma unroll
  for (int i = 0; i < 8; ++i) r[i] = (__bf16)f[i];
  return r;
}

// ---- block reduction helpers (blockDim.x == 256 assumed, 4 waves) ----
__device__ __forceinline__ void blockRed2(float& a, float& b, float* red) {
#pragma unroll
  for (int off = 1; off < 64; off <<= 1) {
    a += __shfl_xor(a, off, 64);
    b += __shfl_xor(b, off, 64);
  }
  const int w = threadIdx.x >> 6;
  if ((threadIdx.x & 63) == 0) { red[w] = a; red[4 + w] = b; }
  __syncthreads();
  a = red[0] + red[1] + red[2] + red[3];
  b = red[4] + red[5] + red[6] + red[7];
  __syncthreads();
}

// =====================================================================
// Stage A: img_feat partials = images_flat(512x37632) @ W_img(37632x512)
// split-K=49, tile 128x128, 8 waves, dbuf LDS, depth-3 reg pipeline.
// XCD-chunked swizzle: blocks sharing A/B slices land on one XCD's L2.
// =====================================================================
#define IMG_K 37632
#define SPLITK 49
#define STEPS_PER 24  // divisible by 6 (2-buf x 3-set unroll)

__global__ __launch_bounds__(512) void img_gemm_kernel(
    const float* __restrict__ A, const float* __restrict__ B,
    __bf16* __restrict__ partials) {
  __shared__ __bf16 As[2][128 * 40];
  __shared__ __bf16 Bs[2][128 * 40];
  const int t = threadIdx.x;
  const int lane = t & 63;
  const int w = t >> 6;
  const int wr = (w >> 2) * 64;
  const int wc = (w & 3) * 32;
  // XCD-chunked bijective swizzle: 784 blocks = 8 XCDs x 98.
  const int orig = blockIdx.x + (blockIdx.y << 2) + (blockIdx.z << 4);
  const int swz = (orig & 7) * 98 + (orig >> 3);
  const int m0 = ((swz >> 2) & 3) * 128;
  const int n0 = (swz & 3) * 128;
  const int zz = swz >> 4;
  const int step0 = zz * STEPS_PER;

  f32x4 acc[4][2];
#pragma unroll
  for (int i = 0; i < 4; ++i)
#pragma unroll
    for (int j = 0; j < 2; ++j) acc[i][j] = f32x4{0.f, 0.f, 0.f, 0.f};

  const int ar = t >> 2, ak = (t & 3) * 8;
  const int bn = t & 127, bk = (t >> 7) * 8;
  const int fr = lane & 15, fk = (lane >> 4) * 8;

  float r0a[8], r0b[8], r1a[8], r1b[8], r2a[8], r2b[8];
#define IMG_LOAD(AT, BT, K0)                                                \
  do {                                                                      \
    const float* asrc = A + (size_t)(m0 + ar) * IMG_K + (K0) + ak;          \
    f32x4 v0 = *reinterpret_cast<const f32x4*>(asrc);                       \
    f32x4 v1 = *reinterpret_cast<const f32x4*>(asrc + 4);                   \
    AT[0] = v0[0]; AT[1] = v0[1]; AT[2] = v0[2]; AT[3] = v0[3];             \
    AT[4] = v1[0]; AT[5] = v1[1]; AT[6] = v1[2]; AT[7] = v1[3];             \
    const float* bsrc = B + (size_t)((K0) + bk) * 512 + n0 + bn;            \
    _Pragma("unroll") for (int j = 0; j < 8; ++j) BT[j] =                   \
        bsrc[(size_t)j * 512];                                              \
  } while (0)
#define IMG_WRITE(BUF, AT, BT)                                              \
  do {                                                                      \
    *reinterpret_cast<bf16x8*>(&As[BUF][ar * 40 + ak]) = cvt8(AT);          \
    *reinterpret_cast<bf16x8*>(&Bs[BUF][bn * 40 + bk]) = cvt8(BT);          \
  } while (0)
#define IMG_MFMA(BUF)                                                       \
  do {                                                                      \
    bf16x8 af[4], bfr[2];                                                   \
    _Pragma("unroll") for (int i = 0; i < 4; ++i) af[i] =                   \
        *reinterpret_cast<const bf16x8*>(                                   \
            &As[BUF][(wr + i * 16 + fr) * 40 + fk]);                        \
    _Pragma("unroll") for (int j = 0; j < 2; ++j) bfr[j] =                  \
        *reinterpret_cast<const bf16x8*>(                                   \
            &Bs[BUF][(wc + j * 16 + fr) * 40 + fk]);                        \
    _Pragma("unroll") for (int i = 0; i < 4; ++i)                           \
        _Pragma("unroll") for (int j = 0; j < 2; ++j) acc[i][j] =           \
            mfma16(af[i], bfr[j], acc[i][j]);                               \
  } while (0)
#define IMG_STEP(S, BUF, WBUF, LA, LB, WA, WB)                              \
  do {                                                                      \
    if ((S) + 3 < STEPS_PER) IMG_LOAD(LA, LB, (step0 + (S) + 3) * 32);      \
    IMG_MFMA(BUF);                                                          \
    if ((S) + 1 < STEPS_PER) IMG_WRITE(WBUF, WA, WB);                       \
    __syncthreads();                                                        \
  } while (0)

  IMG_LOAD(r0a, r0b, step0 * 32);
  IMG_WRITE(0, r0a, r0b);
  IMG_LOAD(r1a, r1b, (step0 + 1) * 32);
  IMG_LOAD(r2a, r2b, (step0 + 2) * 32);
  __syncthreads();

  for (int s6 = 0; s6 < STEPS_PER; s6 += 6) {
    IMG_STEP(s6 + 0, 0, 1, r0a, r0b, r1a, r1b);
    IMG_STEP(s6 + 1, 1, 0, r1a, r1b, r2a, r2b);
    IMG_STEP(s6 + 2, 0, 1, r2a, r2b, r0a, r0b);
    IMG_STEP(s6 + 3, 1, 0, r0a, r0b, r1a, r1b);
    IMG_STEP(s6 + 4, 0, 1, r1a, r1b, r2a, r2b);
    IMG_STEP(s6 + 5, 1, 0, r2a, r2b, r0a, r0b);
  }
#undef IMG_LOAD
#undef IMG_WRITE
#undef IMG_MFMA
#undef IMG_STEP

  __bf16* P = partials + (size_t)zz * (512 * 512);
  const int rq = (lane >> 4) * 4;
#pragma unroll
  for (int i = 0; i < 4; ++i)
#pragma unroll
    for (int j = 0; j < 2; ++j)
#pragma unroll
      for (int r = 0; r < 4; ++r)
        P[(size_t)(m0 + wr + i * 16 + rq + r) * 512 + (n0 + wc + j * 16 + fr)] =
            (__bf16)acc[i][j][r];
}

// low[idx] = kp_feat(already there) + b_img + sum_z partials[z][idx];
// also writes bf16 copy into fusedbf[:, 0:512] (row stride 1024).
__global__ __launch_bounds__(256) void reduce_add_kernel(
    const __bf16* __restrict__ partials, const float* __restrict__ b_img,
    float* __restrict__ low, __bf16* __restrict__ fusedbf) {
  const int idx = blockIdx.x * 256 + threadIdx.x;
  float acc = low[idx] + b_img[idx & 511];
#pragma unroll
  for (int z = 0; z < SPLITK; ++z)
    acc += (float)partials[(size_t)z * 262144 + idx];
  low[idx] = acc;
  fusedbf[(size_t)(idx >> 9) * 1024 + (idx & 511)] = (__bf16)acc;
}

// =====================================================================
// kp_feat = LN(relu(keypoints @ W_kp + b_kp)); one block per row (512)
// =====================================================================
__global__ __launch_bounds__(256) void kp_kernel(
    const float* __restrict__ kp, const float* __restrict__ W,
    const float* __restrict__ bias, const float* __restrict__ g,
    const float* __restrict__ bt, float* __restrict__ low) {
  __shared__ float rowv[242];
  __shared__ float red[8];
  const int t = threadIdx.x;
  const size_t roff = (size_t)blockIdx.x * 242;
  if (t < 242) rowv[t] = kp[roff + t];
  __syncthreads();
  const int d0 = t, d1 = t + 256;
  float p0 = bias[d0], p1 = bias[d1];
  for (int kk = 0; kk < 242; ++kk) {
    const float x = rowv[kk];
    p0 = fmaf(x, W[kk * 512 + d0], p0);
    p1 = fmaf(x, W[kk * 512 + d1], p1);
  }
  p0 = fmaxf(p0, 0.f);
  p1 = fmaxf(p1, 0.f);
  float s = p0 + p1, sq = p0 * p0 + p1 * p1;
  blockRed2(s, sq, red);
  const float m = s * (1.f / 512.f);
  const float var = sq * (1.f / 512.f) - m * m;
  const float rs = rsqrtf(var + 1e-5f);
  const size_t off = (size_t)blockIdx.x * 512;
  low[off + d0] = (p0 - m) * rs * g[d0] + bt[d0];
  low[off + d1] = (p1 - m) * rs * g[d1] + bt[d1];
}

// =====================================================================
// W_qp transpose+convert: Wt[col][k] bf16, k padded 242 -> 256 (zeros).
// =====================================================================
__global__ __launch_bounds__(256) void wqp_transpose_kernel(
    const float* __restrict__ W, __bf16* __restrict__ Wt) {
  const int c = blockIdx.x;   // 512 output columns
  const int t = threadIdx.x;  // 256 k slots
  Wt[(size_t)c * 256 + t] = (t < 242) ? (__bf16)W[(size_t)t * 512 + c] : (__bf16)0.f;
}

// =====================================================================
// Generic transpose+convert (LDS-tiled, coalesced both sides):
// W [NK][NC] f32 -> Wt [NC][NK] bf16. 32x32 tiles; NC guarded, NK%32==0.
// =====================================================================
__global__ __launch_bounds__(256) void wtrans_kernel(
    const float* __restrict__ W, __bf16* __restrict__ Wt, int NC, int NK) {
  __shared__ float T[32][33];
  const int t = threadIdx.x;
  const int c0 = blockIdx.x * 32;
  const int k0 = blockIdx.y * 32;
#pragma unroll
  for (int r = 0; r < 4; ++r) {
    const int idx = r * 256 + t;
    const int i = idx >> 5, j = idx & 31;
    const int c = c0 + j;
    T[i][j] = (c < NC) ? W[(size_t)(k0 + i) * NC + c] : 0.f;
  }
  __syncthreads();
#pragma unroll
  for (int r = 0; r < 4; ++r) {
    const int idx = r * 256 + t;
    const int i = idx >> 5, j = idx & 31;
    const int c = c0 + i;
    if (c < NC) Wt[(size_t)c * NK + k0 + j] = (__bf16)T[j][i];
  }
}

// =====================================================================
// Fused MFMA pooling: pooled = pool_mean(LN(qgrids @ W_qp + b_qp)).
// Output bf16 (consumers cast anyway -> same numerics).
// =====================================================================
__global__ __launch_bounds__(512) void pool_mfma_kernel(
    const float* __restrict__ qgrids, const int* __restrict__ lens,
    const __bf16* __restrict__ Wt, const float* __restrict__ bias,
    const float* __restrict__ g, const float* __restrict__ bt,
    __bf16* __restrict__ pooled) {
  __shared__ float red[8][16][2];
  const int t = threadIdx.x, lane = t & 63, w = t >> 6;
  const int b = blockIdx.x >> 5;
  const int j0 = (blockIdx.x & 31) * 16;
  const int L = lens[b];
  int S = (L + 511) >> 9;
  if (S < 1) S = 1;
  const int new_len = (L + S - 1) / S;
  const float* qg_b = qgrids + (size_t)b * 4096 * 242;
  __bf16* pooled_b = pooled + (size_t)b * 512 * 512;

  const int fr = lane & 15;
  const int fq = lane >> 4;
  const int fkq = fq * 8;
  const int colbase = w * 64;

  float biasv[4], gv[4], btv[4];
#pragma unroll
  for (int nt = 0; nt < 4; ++nt) {
    const int col = colbase + nt * 16 + fr;
    biasv[nt] = bias[col];
    gv[nt] = g[col];
    btv[nt] = bt[col];
  }

  f32x4 pool[4];
#pragma unroll
  for (int nt = 0; nt < 4; ++nt) pool[nt] = f32x4{0.f, 0.f, 0.f, 0.f};

  for (int i = 0; i < S; ++i) {
    const int arow = (j0 + fr) * S + i;
    const float* asrc = qg_b + (size_t)arow * 242;
    f32x4 acc[4];
#pragma unroll
    for (int nt = 0; nt < 4; ++nt) acc[nt] = f32x4{0.f, 0.f, 0.f, 0.f};
#pragma unroll
    for (int ks = 0; ks < 8; ++ks) {
      bf16x8 af;
      if (ks < 7) {
        float tmp[8];
#pragma unroll
        for (int p2 = 0; p2 < 4; ++p2) {
          f32x2 v = *reinterpret_cast<const f32x2*>(asrc + ks * 32 + fkq + p2 * 2);
          tmp[p2 * 2] = v[0];
          tmp[p2 * 2 + 1] = v[1];
        }
        af = cvt8(tmp);
      } else {
        float tmp[8];
#pragma unroll
        for (int jj = 0; jj < 8; ++jj) {
          const int kk = 224 + fkq + jj;
          tmp[jj] = (kk < 242) ? asrc[kk] : 0.f;
        }
        af = cvt8(tmp);
      }
      const __bf16* wt = Wt + ks * 32 + fkq;
#pragma unroll
      for (int nt = 0; nt < 4; ++nt) {
        bf16x8 bfv = *reinterpret_cast<const bf16x8*>(
            wt + (size_t)(colbase + nt * 16 + fr) * 256);
        acc[nt] = mfma16(af, bfv, acc[nt]);
      }
    }
    float s[4] = {0.f, 0.f, 0.f, 0.f}, sq[4] = {0.f, 0.f, 0.f, 0.f};
#pragma unroll
    for (int nt = 0; nt < 4; ++nt) {
#pragma unroll
      for (int r = 0; r < 4; ++r) {
        const float v = acc[nt][r] + biasv[nt];
        acc[nt][r] = v;
        s[r] += v;
        sq[r] += v * v;
      }
    }
#pragma unroll
    for (int off = 1; off < 16; off <<= 1) {
#pragma unroll
      for (int r = 0; r < 4; ++r) {
        s[r] += __shfl_xor(s[r], off, 64);
        sq[r] += __shfl_xor(sq[r], off, 64);
      }
    }
    if (fr == 0) {
#pragma unroll
      for (int r = 0; r < 4; ++r) {
        red[w][fq * 4 + r][0] = s[r];
        red[w][fq * 4 + r][1] = sq[r];
      }
    }
    __syncthreads();
    float mean[4], rsig[4];
#pragma unroll
    for (int r = 0; r < 4; ++r) {
      const int p = fq * 4 + r;
      float ss = 0.f, qq = 0.f;
#pragma unroll
      for (int ww = 0; ww < 8; ++ww) {
        ss += red[ww][p][0];
        qq += red[ww][p][1];
      }
      const float m = ss * (1.f / 512.f);
      mean[r] = m;
      rsig[r] = rsqrtf(qq * (1.f / 512.f) - m * m + 1e-5f);
    }
    __syncthreads();
#pragma unroll
    for (int r = 0; r < 4; ++r) {
      const int srow = (j0 + fq * 4 + r) * S + i;
      const bool ok = srow < L;
#pragma unroll
      for (int nt = 0; nt < 4; ++nt) {
        const float nv = (acc[nt][r] - mean[r]) * rsig[r] * gv[nt] + btv[nt];
        pool[nt][r] += ok ? nv : 0.f;
      }
    }
  }
  const float inv = 1.f / (float)S;
#pragma unroll
  for (int r = 0; r < 4; ++r) {
    const int j = j0 + fq * 4 + r;
    const bool ok = j < new_len;
#pragma unroll
    for (int nt = 0; nt < 4; ++nt)
      pooled_b[(size_t)j * 512 + colbase + nt * 16 + fr] =
          (__bf16)(ok ? pool[nt][r] * inv : 0.f);
  }
}

// =====================================================================
// Register GEMM, K=512: C[M][ldc] = A_bf16[M][lda cols, first 512 used]
// @ Wt^T + bias. One 16x16 tile per wave, fragments direct from global
// (L2-resident), 16 unrolled k-steps, no LDS, no barriers.
// Grid: (ldc/16, M/64). Same structure as the proven ctc register GEMM.
// =====================================================================
template <typename OutT>
__global__ __launch_bounds__(256) void reg_gemm512_kernel(
    const __bf16* __restrict__ A, int lda, const __bf16* __restrict__ Wt,
    const float* __restrict__ bias, OutT* __restrict__ C, int ldc) {
  const int t = threadIdx.x, lane = t & 63, w = t >> 6;
  const int n0 = blockIdx.x * 16;
  const int m0 = blockIdx.y * 64 + w * 16;
  const int fr = lane & 15, fq = lane >> 4;
  const __bf16* arow = A + (size_t)(m0 + fr) * lda + fq * 8;
  const __bf16* brow = Wt + (size_t)(n0 + fr) * 512 + fq * 8;
  f32x4 acc = f32x4{0.f, 0.f, 0.f, 0.f};
#pragma unroll
  for (int ks = 0; ks < 16; ++ks) {
    bf16x8 a = *reinterpret_cast<const bf16x8*>(arow + ks * 32);
    bf16x8 b = *reinterpret_cast<const bf16x8*>(brow + ks * 32);
    acc = mfma16(a, b, acc);
  }
  const int col = n0 + fr;
  const float bv = bias[col];
  const int r0 = m0 + fq * 4;
#pragma unroll
  for (int r = 0; r < 4; ++r)
    C[(size_t)(r0 + r) * ldc + col] = (OutT)(acc[r] + bv);
}

// =====================================================================
// CTC head register GEMM: out[512,1296] = fusedbf @ Wt^T + bias (K=1024)
// =====================================================================
__global__ __launch_bounds__(256) void ctc_gemm_kernel(
    const __bf16* __restrict__ A, const __bf16* __restrict__ Wt,
    const float* __restrict__ bias, float* __restrict__ out) {
  const int t = threadIdx.x, lane = t & 63, w = t >> 6;
  const int n0 = blockIdx.x * 16;
  const int m0 = blockIdx.y * 64 + w * 16;
  const int fr = lane & 15, fq = lane >> 4;
  const __bf16* arow = A + (size_t)(m0 + fr) * 1024 + fq * 8;
  const __bf16* brow = Wt + (size_t)(n0 + fr) * 1024 + fq * 8;
  f32x4 acc = f32x4{0.f, 0.f, 0.f, 0.f};
#pragma unroll
  for (int ks = 0; ks < 32; ++ks) {
    bf16x8 a = *reinterpret_cast<const bf16x8*>(arow + ks * 32);
    bf16x8 b = *reinterpret_cast<const bf16x8*>(brow + ks * 32);
    acc = mfma16(a, b, acc);
  }
  const int col = n0 + fr;
  const float bv = bias[col];
  const int r0 = m0 + fq * 4;
#pragma unroll
  for (int r = 0; r < 4; ++r)
    out[(size_t)(r0 + r) * 1296 + col] = acc[r] + bv;
}

// =====================================================================
// Attention stage 1: P = softmax(mask(Q_h @ K_h^T / 8)) as bf16.
// Q and K are bf16 -> staging is a straight copy.
// =====================================================================
__global__ __launch_bounds__(256) void attn_scores_kernel(
    const __bf16* __restrict__ q, const __bf16* __restrict__ k,
    const int* __restrict__ lens, __bf16* __restrict__ P) {
  __shared__ __bf16 Qs[64 * 72];
  __shared__ __bf16 Bs[512 * 40];
  const int t = threadIdx.x, lane = t & 63, w = t >> 6;
  const int bh = blockIdx.x, b = bh >> 3, h = bh & 7;
  const int L = lens[b];
  const int sdiv = (L + 511) >> 9;
  const int new_len = (L + sdiv - 1) / sdiv;
  const size_t qbase = (size_t)b * 64 * 512 + h * 64;
  const size_t kbase = (size_t)b * 512 * 512 + h * 64;
#pragma unroll
  for (int rep = 0; rep < 4; ++rep) {
    const int gidx = rep * 256 + t;
    const int row = gidx >> 4, c = (gidx & 15) * 4;
    *reinterpret_cast<bf16x4*>(&Qs[row * 72 + c]) =
        *reinterpret_cast<const bf16x4*>(&q[qbase + (size_t)row * 512 + c]);
  }
  f32x4 acc[32];
#pragma unroll
  for (int nt = 0; nt < 32; ++nt) acc[nt] = f32x4{0.f, 0.f, 0.f, 0.f};
  const int fr = lane & 15, fkq = (lane >> 4) * 8;
  for (int ks = 0; ks < 2; ++ks) {
    const int k0 = ks * 32;
#pragma unroll
    for (int rep = 0; rep < 16; ++rep) {
      const int gidx = rep * 256 + t;
      const int row = gidx >> 3, c = (gidx & 7) * 4;
      *reinterpret_cast<bf16x4*>(&Bs[row * 40 + c]) =
          *reinterpret_cast<const bf16x4*>(&k[kbase + (size_t)row * 512 + k0 + c]);
    }
    __syncthreads();
    const bf16x8 af =
        *reinterpret_cast<const bf16x8*>(&Qs[(w * 16 + fr) * 72 + k0 + fkq]);
#pragma unroll
    for (int nt = 0; nt < 32; ++nt) {
      bf16x8 bf = *reinterpret_cast<const bf16x8*>(&Bs[(nt * 16 + fr) * 40 + fkq]);
      acc[nt] = mfma16(af, bf, acc[nt]);
    }
    __syncthreads();
  }
  const float scale = 0.125f;
  const size_t pb = (size_t)bh * 64 * 512;
#pragma unroll
  for (int r = 0; r < 4; ++r) {
    float mx = -3.0e38f;
#pragma unroll
    for (int nt = 0; nt < 32; ++nt) {
      const int col = nt * 16 + fr;
      const float sv = acc[nt][r] * scale;
      if (col < new_len) mx = fmaxf(mx, sv);
    }
#pragma unroll
    for (int off = 1; off < 16; off <<= 1) mx = fmaxf(mx, __shfl_xor(mx, off, 64));
    float sum = 0.f;
#pragma unroll
    for (int nt = 0; nt < 32; ++nt) {
      const int col = nt * 16 + fr;
      const float e = (col < new_len) ? __expf(acc[nt][r] * scale - mx) : 0.f;
      acc[nt][r] = e;
      sum += e;
    }
#pragma unroll
    for (int off = 1; off < 16; off <<= 1) sum += __shfl_xor(sum, off, 64);
    const float inv = 1.f / sum;
    const int row = w * 16 + ((lane >> 4) << 2) + r;
    __bf16* dst = P + pb + (size_t)row * 512 + fr;
#pragma unroll
    for (int nt = 0; nt < 32; ++nt) dst[nt * 16] = (__bf16)(acc[nt][r] * inv);
  }
}

// =====================================================================
// Attention stage 2: ctx = P_h(64x512 bf16) @ V_h(512x64 bf16) -> bf16.
// =====================================================================
__global__ __launch_bounds__(256) void attn_pv_kernel(
    const __bf16* __restrict__ P, const __bf16* __restrict__ v,
    __bf16* __restrict__ ctx) {
  __shared__ __bf16 As[64 * 40];
  __shared__ __bf16 Bs[64 * 40];
  const int t = threadIdx.x, lane = t & 63, w = t >> 6;
  const int bh = blockIdx.x, b = bh >> 3, h = bh & 7;
  const size_t pbase = (size_t)bh * 64 * 512;
  const size_t vbase = (size_t)b * 512 * 512 + h * 64;
  f32x4 acc[4];
#pragma unroll
  for (int j = 0; j < 4; ++j) acc[j] = f32x4{0.f, 0.f, 0.f, 0.f};
  const int fr = lane & 15, fk = (lane >> 4) * 8;
  const int arow = t >> 2, ac = (t & 3) * 8;
  const int bn = t & 63, bk = (t >> 6) * 8;
  for (int s = 0; s < 16; ++s) {
    const int k0 = s * 32;
    *reinterpret_cast<bf16x8*>(&As[arow * 40 + ac]) =
        *reinterpret_cast<const bf16x8*>(&P[pbase + (size_t)arow * 512 + k0 + ac]);
    {
      bf16x8 tmp;
#pragma unroll
      for (int j = 0; j < 8; ++j)
        tmp[j] = v[vbase + (size_t)(k0 + bk + j) * 512 + bn];
      *reinterpret_cast<bf16x8*>(&Bs[bn * 40 + bk]) = tmp;
    }
    __syncthreads();
    const bf16x8 a = *reinterpret_cast<const bf16x8*>(&As[(w * 16 + fr) * 40 + fk]);
#pragma unroll
    for (int j = 0; j < 4; ++j) {
      bf16x8 bfrag = *reinterpret_cast<const bf16x8*>(&Bs[(j * 16 + fr) * 40 + fk]);
      acc[j] = mfma16(a, bfrag, acc[j]);
    }
    __syncthreads();
  }
  const int rq = (lane >> 4) * 4;
  const size_t cbase = (size_t)b * 64 * 512 + h * 64;
#pragma unroll
  for (int j = 0; j < 4; ++j)
#pragma unroll
    for (int r = 0; r < 4; ++r)
      ctx[cbase + (size_t)(w * 16 + rq + r) * 512 + j * 16 + fr] =
          (__bf16)acc[j][r];
}

// LayerNorm over rows of 512, bf16 output into fusedbf[:, 512:1024]
__global__ __launch_bounds__(256) void ln_bf16_kernel(
    const float* __restrict__ x, const float* __restrict__ g,
    const float* __restrict__ bt, __bf16* __restrict__ ybf) {
  __shared__ float red[8];
  const int t = threadIdx.x;
  const size_t off = (size_t)blockIdx.x * 512;
  const float a = x[off + t], b2 = x[off + t + 256];
  float s = a + b2, sq = a * a + b2 * b2;
  blockRed2(s, sq, red);
  const float m = s * (1.f / 512.f);
  const float var = sq * (1.f / 512.f) - m * m;
  const float rs = rsqrtf(var + 1e-5f);
  __bf16* yrow = ybf + (size_t)blockIdx.x * 1024;
  yrow[t] = (__bf16)((a - m) * rs * g[t] + bt[t]);
  yrow[t + 256] = (__bf16)((b2 - m) * rs * g[t + 256] + bt[t + 256]);
}

// =====================================================================
// Workspace layout (live ranges by step):
//   ws+ 0.. 1 MB  low      (2-6)
//   ws+ 1.. 2 MB  qbuf bf16 512KB (6-7)
//   ws+ 2.. 3 MB  wtq (0-4) then ctxo f32 (8)
//   ws+ 3.. 4 MB  fusedbf  (3-9)      <- never alias pbuf!
//   ws+ 4..28.5   partials bf16 49x512KB (1-3, dead after 3)
//     overlaps:   pooled bf16 ws+4..8   (4-5)
//                 pbuf   4MB  ws+4..8   (7a-7b, after pooled dead)
//                 kbuf   bf16 ws+12..16 (5-7)
//                 vbuf   bf16 ws+16..20 (5-7)
//   ws+28..29 MB  ctxbf bf16 512KB (7b-8, partials dead)
//   ws+29..31.6   wtc (0-9; clear of partials: 28.5 MB end < 29 MB)
//   ws+32..34 MB  wq_t/wk_t/wv_t/wo_t bf16 512KB each (0-8)
// =====================================================================
extern "C" void kernel_launch(void* const* d_in, const int* in_sizes, int n_in,
                              void* d_out, int out_size, void* d_ws,
                              size_t ws_size, hipStream_t stream) {
  const float* images = (const float*)d_in[0];
  const float* qgrids = (const float*)d_in[1];
  const float* keypoints = (const float*)d_in[2];
  const int* qlens = (const int*)d_in[3];
  const float* W_img = (const float*)d_in[4];
  const float* b_img = (const float*)d_in[5];
  const float* W_kp = (const float*)d_in[6];
  const float* b_kp = (const float*)d_in[7];
  const float* g_kp = (const float*)d_in[8];
  const float* bt_kp = (const float*)d_in[9];
  const float* W_qp = (const float*)d_in[10];
  const float* b_qp = (const float*)d_in[11];
  const float* g_qln = (const float*)d_in[12];
  const float* bt_qln = (const float*)d_in[13];
  const float* Wq = (const float*)d_in[14];
  const float* bq = (const float*)d_in[15];
  const float* Wk = (const float*)d_in[16];
  const float* bk = (const float*)d_in[17];
  const float* Wv = (const float*)d_in[18];
  const float* bv = (const float*)d_in[19];
  const float* Wo = (const float*)d_in[20];
  const float* bo = (const float*)d_in[21];
  const float* g_attn = (const float*)d_in[22];
  const float* bt_attn = (const float*)d_in[23];
  const float* W_ctc = (const float*)d_in[24];
  const float* b_ctc = (const float*)d_in[25];
  float* out = (float*)d_out;

  const size_t MB = 1u << 20;
  if (ws_size < 34 * MB) return;
  char* ws = (char*)d_ws;
  float* low = (float*)(ws);                 // 1 MB
  __bf16* qbuf = (__bf16*)(ws + 1 * MB);     // 512 KB bf16
  __bf16* wtq = (__bf16*)(ws + 2 * MB);      // 256 KB (dead after step 4)
  float* ctxo = (float*)(ws + 2 * MB);       // 1 MB (written step 8)
  __bf16* fusedbf = (__bf16*)(ws + 3 * MB);  // 1 MB (512x1024 bf16)
  __bf16* partials = (__bf16*)(ws + 4 * MB); // 24.5 MB bf16 (dead after 3)
  __bf16* pooled = (__bf16*)(ws + 4 * MB);   // 4 MB bf16 (steps 4-5)
  __bf16* pbuf = (__bf16*)(ws + 4 * MB);     // 4 MB (P; steps 7a-7b)
  __bf16* kbuf = (__bf16*)(ws + 12 * MB);    // 4 MB bf16 (5-7)
  __bf16* vbuf = (__bf16*)(ws + 16 * MB);    // 4 MB bf16 (5-7)
  __bf16* ctxbf = (__bf16*)(ws + 28 * MB);   // 512 KB bf16 (7b-8)
  __bf16* wtc = (__bf16*)(ws + 29 * MB);     // 2.53 MB Wt_ctc
  __bf16* wq_t = (__bf16*)(ws + 32 * MB);    // 512 KB
  __bf16* wk_t = (__bf16*)(ws + 32 * MB + 512 * 1024);
  __bf16* wv_t = (__bf16*)(ws + 33 * MB);
  __bf16* wo_t = (__bf16*)(ws + 33 * MB + 512 * 1024);

  // 0) weight transposes (inputs only; partials region untouched)
  wqp_transpose_kernel<<<512, 256, 0, stream>>>(W_qp, wtq);
  wtrans_kernel<<<dim3(16, 16), 256, 0, stream>>>(Wq, wq_t, 512, 512);
  wtrans_kernel<<<dim3(16, 16), 256, 0, stream>>>(Wk, wk_t, 512, 512);
  wtrans_kernel<<<dim3(16, 16), 256, 0, stream>>>(Wv, wv_t, 512, 512);
  wtrans_kernel<<<dim3(16, 16), 256, 0, stream>>>(Wo, wo_t, 512, 512);
  wtrans_kernel<<<dim3(41, 32), 256, 0, stream>>>(W_ctc, wtc, 1296, 1024);
  // 1) img GEMM partials (split-K=49, bf16 partials, depth-3, XCD swz)
  img_gemm_kernel<<<dim3(4, 4, SPLITK), 512, 0, stream>>>(images, W_img, partials);
  // 2) kp_feat -> low
  kp_kernel<<<512, 256, 0, stream>>>(keypoints, W_kp, b_kp, g_kp, bt_kp, low);
  // 3) low += b_img + sum(partials); also fusedbf[:, :512] = bf16(low)
  reduce_add_kernel<<<1024, 256, 0, stream>>>(partials, b_img, low, fusedbf);
  // 4) pooled qgrid tokens (MFMA proj + LN + ragged mean-pool) -> bf16
  pool_mfma_kernel<<<256, 512, 0, stream>>>(qgrids, qlens, wtq, b_qp, g_qln,
                                            bt_qln, pooled);
  // 5) k, v via register GEMM (M=4096)
  reg_gemm512_kernel<__bf16><<<dim3(32, 64), 256, 0, stream>>>(
      pooled, 512, wk_t, bk, kbuf, 512);
  reg_gemm512_kernel<__bf16><<<dim3(32, 64), 256, 0, stream>>>(
      pooled, 512, wv_t, bv, vbuf, 512);
  // 6) q via register GEMM (A = fusedbf low-half, lda=1024)
  reg_gemm512_kernel<__bf16><<<dim3(32, 8), 256, 0, stream>>>(
      fusedbf, 1024, wq_t, bq, qbuf, 512);
  // 7) fused attention: batched MFMA scores+softmax, then MFMA PV
  attn_scores_kernel<<<64, 256, 0, stream>>>(qbuf, kbuf, qlens, pbuf);
  attn_pv_kernel<<<64, 256, 0, stream>>>(pbuf, vbuf, ctxbf);
  // 8) ctx @ Wo + bo via register GEMM (f32 out), then LN -> fusedbf[:,512:]
  reg_gemm512_kernel<float><<<dim3(32, 8), 256, 0, stream>>>(
      ctxbf, 512, wo_t, bo, ctxo, 512);
  ln_bf16_kernel<<<512, 256, 0, stream>>>(ctxo, g_attn, bt_attn, fusedbf + 512);
  // 9) out = fusedbf @ Wt_ctc^T + b_ctc (register GEMM, K=1024)
  ctc_gemm_kernel<<<dim3(81, 8), 256, 0, stream>>>(fusedbf, wtc, b_ctc, out);
}